// Round 2
// baseline (300.188 us; speedup 1.0000x reference)
//
#include <hip/hip_runtime.h>
#include <hip/hip_bf16.h>
#include <stdint.h>

// ---------------------------------------------------------------------------
// EquivariantAttention on MI355X.  Dtype-adaptive (bf16 or fp32 inputs).
// R11: consolidated pipeline; kB = 99us, VALU-bound (VALUBusy 46%, MfmaUtil 0).
// R12: kB layers 2+3 (64x64 and 64x8 GEMMs, ~half the per-thread VALU work and
//   the whole s_load stall chain) moved to MFMA 16x16x32 bf16.  Phase 1
//   (sh + ea + tanh) unchanged per-thread; h packed bf16 into XOR-swizzled LDS
//   reusing ArecS/AsndS space (LDS stays 37376B -> occupancy unchanged).
//   W2T/W3T B-fragments live in registers (loaded once per block).  Only ONE
//   extra barrier: all post-pack LDS traffic is intra-wave (each wave reads
//   exactly the rows its own threads wrote).
// R13: resubmit of R12 — previous round was an infra failure (container
//   acquire), no kernel signal.  Source unchanged after a bounds/barrier/
//   layout re-audit.
// ---------------------------------------------------------------------------

#define NNODES 512
#define NDIM   480

// ws layout (4-byte word offsets)
#define QS_OFF    0u         // 512*480 f32 q, per-head layout, folds applied
#define KT_OFF    245760u    // k packed: [h(8)][j4(15)][n(512)][4] f32
#define VB_OFF    491520u    // 512*480 f32 v, output-irrep (final) layout
#define ARE_OFF   737280u    // 512*288 u32 (bf16 pairs over o): [n][mi(9)][oc(32)]
#define ASN_OFF   884736u    // 512*288 u32
#define WF_OFF    1032192u   // 8192 f32: W1a[32][64]@0, W2T[64][64]@2048, W3[64][8]@6144, b1@6656, b2@6720, b3@6784
#define FLAG_OFF  1040384u   // flag[0] = 1 if inputs fp32, 0 if bf16
#define L_OFF     1040448u   // L SoA: [h(8)][r(512)][s(512)] f32 (8MB)
#define WTQ_OFF   3137600u   // q weights transposed [o][i] f32 + folds
#define WTK_OFF   3159104u
#define WTV_OFF   3180608u
#define W1T_OFF   3202112u   // mW1 transposed [o(64)][row(480)] f32, cg folded

typedef float f32x4 __attribute__((ext_vector_type(4)));
typedef short s16x8 __attribute__((ext_vector_type(8)));

__device__ __forceinline__ float bf2f(uint16_t u) {
    return __uint_as_float(((uint32_t)u) << 16);
}
__device__ __forceinline__ uint16_t f2bf(float f) {
    union { __hip_bfloat16 h; uint16_t u; } cv;
    cv.h = __float2bfloat16(f);
    return cv.u;
}
__device__ __forceinline__ uint32_t packbf(float lo, float hi) {
    return ((uint32_t)f2bf(hi) << 16) | (uint32_t)f2bf(lo);
}
__device__ __forceinline__ float ldin(const void* p, size_t i, int f32) {
    return f32 ? ((const float*)p)[i] : bf2f(((const uint16_t*)p)[i]);
}
// tanh(x) = 1 - 2/(exp(2x)+1)
__device__ __forceinline__ float ftanh(float x) {
    float e = __builtin_amdgcn_exp2f(x * 2.885390081777927f);
    return 1.0f - 2.0f * __builtin_amdgcn_rcpf(e + 1.0f);
}

// ------------------------------------------------- dtype detector
__global__ __launch_bounds__(64) void kDet(const uint32_t* __restrict__ nf,
                                           int* __restrict__ flag)
{
    int t = threadIdx.x;
    uint32_t x = nf[64 + t];
    int e = (x >> 7) & 0xff;
    int good = (x != 0u) && (e >= 100) && (e <= 140);
    unsigned long long m = __ballot(good);
    if (t == 0) flag[0] = (__popcll(m) < 32) ? 1 : 0;
}

// ---------------------------------------------------------------- weights prep
#define NS 16384
__global__ __launch_bounds__(256) void kW(
    const void* __restrict__ mW1, const void* __restrict__ mb1,
    const void* __restrict__ mW2, const void* __restrict__ mb2,
    const void* __restrict__ mW3, const void* __restrict__ mb3,
    const void* __restrict__ Wq0, const void* __restrict__ Wq1, const void* __restrict__ Wq2,
    const void* __restrict__ Wk0, const void* __restrict__ Wk1, const void* __restrict__ Wk2,
    const void* __restrict__ Wv0, const void* __restrict__ Wv1, const void* __restrict__ Wv2,
    float* __restrict__ ws, const int* __restrict__ flagp)
{
    const int f32 = flagp[0];
    const int gt = blockIdx.x * 256 + threadIdx.x;
    float* Wf = ws + WF_OFF;

    for (int i = gt; i < 2048; i += NS) Wf[i] = ldin(mW1, i, f32);
    for (int i = gt; i < 4096; i += NS) {
        int o2 = i >> 6, ii = i & 63;
        Wf[2048 + i] = ldin(mW2, ii * 64 + o2, f32);
    }
    for (int i = gt; i < 512; i += NS) Wf[6144 + i] = ldin(mW3, i, f32);
    for (int i = gt; i < 64; i += NS) Wf[6656 + i] = ldin(mb1, i, f32);
    for (int i = gt; i < 64; i += NS) Wf[6720 + i] = ldin(mb2, i, f32);
    for (int i = gt; i < 8; i += NS)  Wf[6784 + i] = ldin(mb3, i, f32);

    const float e3n0 = 0.08838834764831845f, e3n1 = 0.125f, e3n2 = 0.17677669529663687f;
    const float cg1 = 0.5773502691896258f, cg2 = 0.4472135954999579f;
    const float attn = 0.1889822365046136f;

    const void* Wsrc[9] = {Wq0, Wq1, Wq2, Wk0, Wk1, Wk2, Wv0, Wv1, Wv2};
    float* Wdst[3] = {ws + WTQ_OFF, ws + WTK_OFF, ws + WTV_OFF};
    for (int kind = 0; kind < 3; ++kind) {
        const float f0 = (kind == 0) ? e3n0 * attn : e3n0;
        const float f1 = (kind == 0) ? e3n1 * cg1 * attn : e3n1;
        const float f2 = (kind == 0) ? e3n2 * cg2 * attn : e3n2;
        for (int i = gt; i < 16384; i += NS) {
            int o = i >> 7, ii = i & 127;
            Wdst[kind][i] = ldin(Wsrc[kind * 3], (size_t)ii * 128 + o, f32) * f0;
        }
        for (int i = gt; i < 4096; i += NS) {
            int o = i >> 6, ii = i & 63;
            Wdst[kind][16384 + i] = ldin(Wsrc[kind * 3 + 1], (size_t)ii * 64 + o, f32) * f1;
        }
        for (int i = gt; i < 1024; i += NS) {
            int o = i >> 5, ii = i & 31;
            Wdst[kind][20480 + i] = ldin(Wsrc[kind * 3 + 2], (size_t)ii * 32 + o, f32) * f2;
        }
    }
    float* W1T = ws + W1T_OFF;
    for (int i = gt; i < 30720; i += NS) {
        int o = i / 480, row = i - o * 480;
        float cgv;
        if (row < 160)      cgv = 1.0f;
        else if (row < 224) cgv = cg1;
        else if (row < 256) cgv = cg2;
        else if (row < 384) cgv = 1.0f;
        else if (row < 448) cgv = cg1;
        else                cgv = cg2;
        W1T[i] = ldin(mW1, (size_t)row * 64 + o, f32) * cgv;
    }
}

// ------------------------------------------------- per-node precompute
__global__ __launch_bounds__(256) void kA(
    const void* __restrict__ nfu,
    const float* __restrict__ WtQ, const float* __restrict__ WtK,
    const float* __restrict__ WtV, const float* __restrict__ W1T,
    float* __restrict__ qS, float* __restrict__ kT4, float* __restrict__ vB,
    uint32_t* __restrict__ ArecG, uint32_t* __restrict__ AsndG,
    const int* __restrict__ flagp)
{
    const int f32 = flagp[0];
    const int n = blockIdx.x, t = threadIdx.x;
    __shared__ float nfs[480];
    for (int i = t; i < 480; i += 256) nfs[i] = ldin(nfu, (size_t)n * 480 + i, f32);
    __syncthreads();

    for (int idx = t; idx < 1440; idx += 256) {
        int kind = idx / 480, rem = idx - kind * 480;
        int o, m, mul, d, off, am, qoff, sub;
        if (rem < 128)      { o = rem;           m = 0;          mul = 128; d = 1; off = 0;   am = 16; qoff = 0;  sub = 0; }
        else if (rem < 320) { int x = rem - 128; o = x / 3; m = x - o * 3; mul = 64;  d = 3; off = 128; am = 8;  qoff = 16; sub = 16384; }
        else                { int x = rem - 320; o = x / 5; m = x - o * 5; mul = 32;  d = 5; off = 320; am = 4;  qoff = 40; sub = 20480; }
        const float* base = (kind == 0) ? WtQ : (kind == 1) ? WtK : WtV;
        const float4* W4 = reinterpret_cast<const float4*>(base + sub + o * mul);
        const float* nf0 = nfs + off + m;
        float ax = 0.f, ay = 0.f, az = 0.f, aw = 0.f;
        const int n4 = mul >> 2;
        for (int i4 = 0; i4 < n4; ++i4) {
            float4 w = W4[i4];
            int ib = 4 * i4 * d;
            ax += nf0[ib]         * w.x;
            ay += nf0[ib + d]     * w.y;
            az += nf0[ib + 2 * d] * w.z;
            aw += nf0[ib + 3 * d] * w.w;
        }
        float acc = (ax + ay) + (az + aw);
        if (kind == 2) {
            vB[(size_t)n * 480 + rem] = acc;
        } else {
            int hh = o / am, a = o - hh * am;
            int j = qoff + a * d + m;
            if (kind == 0) qS[(size_t)n * 480 + hh * 60 + j] = acc;
            else           kT4[((size_t)(hh * 15 + (j >> 2)) * 512 + n) * 4 + (j & 3)] = acc;
        }
    }

    if (t < 128) {
        const int src = t >> 6, o = t & 63;
        float a[9];
        #pragma unroll
        for (int mi = 0; mi < 9; ++mi) {
            const int l = (mi == 0) ? 0 : (mi < 4 ? 1 : 2);
            const int m = (mi == 0) ? 0 : (mi < 4 ? mi - 1 : mi - 4);
            const int mul = (l == 0 ? 128 : l == 1 ? 64 : 32);
            const int d = 2 * l + 1;
            const int off = (l == 0 ? 0 : l == 1 ? 128 : 320);
            const int base = (src == 0) ? (l == 0 ? 32 : l == 1 ? 160 : 224)
                                        : (l == 0 ? 256 : l == 1 ? 384 : 448);
            const float4* W4 = reinterpret_cast<const float4*>(W1T + o * 480 + base);
            const float* nf0 = nfs + off + m;
            float ax = 0.f, ay = 0.f, az = 0.f, aw = 0.f;
            const int n4 = mul >> 2;
            for (int i4 = 0; i4 < n4; ++i4) {
                float4 w = W4[i4];
                int ib = 4 * i4 * d;
                ax += nf0[ib]         * w.x;
                ay += nf0[ib + d]     * w.y;
                az += nf0[ib + 2 * d] * w.z;
                aw += nf0[ib + 3 * d] * w.w;
            }
            a[mi] = (ax + ay) + (az + aw);
        }
        float b[9];
        #pragma unroll
        for (int mi = 0; mi < 9; ++mi) b[mi] = __shfl_xor(a[mi], 1, 64);
        if ((o & 1) == 0) {
            uint32_t* dst = (src ? AsndG : ArecG) + (size_t)n * 288 + (o >> 1);
            #pragma unroll
            for (int mi = 0; mi < 9; ++mi)
                dst[mi * 32] = ((uint32_t)f2bf(b[mi]) << 16) | (uint32_t)f2bf(a[mi]);
        }
    }
}

// ------------------------------------------------- q.k logits -> L (SoA)
__global__ __launch_bounds__(256) void kQK(
    const float* __restrict__ qS, const float* __restrict__ kT4,
    float* __restrict__ L)
{
    __shared__ float qL[16 * 120];        // [r16][(h-hb)*60 + j]
    const int t = threadIdx.x;
    const int lane = t & 63, wave = t >> 6;
    const int s0 = blockIdx.x * 64, r0 = blockIdx.y * 16, hb = blockIdx.z * 2;

    {
        float4* qL4 = reinterpret_cast<float4*>(qL);
        for (int i = t; i < 480; i += 256) {
            int rr = i / 30, c4 = i - rr * 30;
            qL4[i] = reinterpret_cast<const float4*>(
                         qS + (size_t)(r0 + rr) * 480 + hb * 60)[c4];
        }
    }
    __syncthreads();

    const int s = s0 + lane;
    const int rw = wave * 4;
    const float4* qL4 = reinterpret_cast<const float4*>(qL);
    const float4* k4  = reinterpret_cast<const float4*>(kT4);

    float acc[8];
    #pragma unroll
    for (int i = 0; i < 8; ++i) acc[i] = 0.f;

    #pragma unroll
    for (int h4 = 0; h4 < 2; ++h4) {
        const int h = hb + h4;
        #pragma unroll 5
        for (int j4 = 0; j4 < 15; ++j4) {
            float4 kv = k4[(size_t)(h * 15 + j4) * 512 + s];
            #pragma unroll
            for (int r = 0; r < 4; ++r) {
                float4 qv = qL4[(rw + r) * 30 + h4 * 15 + j4];
                acc[r * 2 + h4] += qv.x * kv.x + qv.y * kv.y + qv.z * kv.z + qv.w * kv.w;
            }
        }
    }
    #pragma unroll
    for (int r = 0; r < 4; ++r) {
        #pragma unroll
        for (int h4 = 0; h4 < 2; ++h4) {
            L[(((size_t)(hb + h4)) << 18) + (((size_t)(r0 + rw + r)) << 9) + s] = acc[r * 2 + h4];
        }
    }
}

// ------------------------------------------------- edge MLP (full grid)
// Phase 1 (VALU, per-thread = per-edge): h = tanh(b1 + sh.(Arec+Asnd) + ea@W1a)
// Phase 2 (MFMA): h2 = tanh(b2 + h@W2) ; ew = b3 + h2@W3 ; L += ew
__global__ __launch_bounds__(256) void kB(
    const void* __restrict__ eaG, const void* __restrict__ shG,
    const uint32_t* __restrict__ ArecG, const uint32_t* __restrict__ AsndG,
    const float* __restrict__ Wf, float* __restrict__ L,
    const int* __restrict__ flagp)
{
    // phase1: ArecS[16*292] @0, AsndS[16*292] @4672  (37376 B)
    // phase2: hS  256 rows x 32 u32 (bf16 pairs), 16B-chunk XOR swizzle (32768 B)
    __shared__ __align__(16) uint32_t smem[9344];
    uint32_t* ArecS = smem;
    uint32_t* AsndS = smem + 4672;
    const int f32 = flagp[0];
    const int t = threadIdx.x;
    const int s0 = blockIdx.x * 16, r0 = blockIdx.y * 16;
    const int lane = t & 63, wv = t >> 6;
    const int g = lane >> 4, nl = lane & 15;

    for (int i = t; i < 16 * 288; i += 256) {
        int row = i / 288, c = i - row * 288;
        ArecS[row * 292 + c] = ArecG[(size_t)(r0 + row) * 288 + c];
        AsndS[row * 292 + c] = AsndG[(size_t)(s0 + row) * 288 + c];
    }

    // ---- W2T/W3T B-fragments + biases into registers (once per block) ----
    // B-frag 16x16x32: lane holds col n = (l&15)+16*nt, k = ks*32 + (l>>4)*8 + j
    s16x8 w2f[4][2];
    #pragma unroll
    for (int nt = 0; nt < 4; ++nt) {
        #pragma unroll
        for (int ks = 0; ks < 2; ++ks) {
            const float* p = Wf + 2048 + (nt * 16 + nl) * 64 + ks * 32 + g * 8;
            s16x8 b;
            #pragma unroll
            for (int j = 0; j < 8; ++j) b[j] = (short)f2bf(p[j]);
            w2f[nt][ks] = b;
        }
    }
    s16x8 w3f[2];
    #pragma unroll
    for (int ks = 0; ks < 2; ++ks) {
        s16x8 b;
        #pragma unroll
        for (int j = 0; j < 8; ++j)
            b[j] = (short)((nl < 8) ? f2bf(Wf[6144 + (ks * 32 + g * 8 + j) * 8 + nl]) : 0);
        w3f[ks] = b;
    }
    float b2v[4];
    #pragma unroll
    for (int nt = 0; nt < 4; ++nt) b2v[nt] = Wf[6720 + nt * 16 + nl];
    const float b3v = (nl < 8) ? Wf[6784 + nl] : 0.f;

    const int rl = t >> 4, sl = t & 15;
    const int r = r0 + rl, s = s0 + sl;
    const size_t eidx = (((size_t)r) << 9) + s;

    uint32_t eaR[16];
    if (f32) {
        const float4* ep = reinterpret_cast<const float4*>((const float*)eaG + eidx * 32);
        #pragma unroll
        for (int i = 0; i < 8; ++i) {
            float4 v = ep[i];
            eaR[2 * i]     = ((uint32_t)f2bf(v.y) << 16) | (uint32_t)f2bf(v.x);
            eaR[2 * i + 1] = ((uint32_t)f2bf(v.w) << 16) | (uint32_t)f2bf(v.z);
        }
    } else {
        const uint4* ep = reinterpret_cast<const uint4*>((const uint32_t*)eaG + eidx * 16);
        #pragma unroll
        for (int i = 0; i < 4; ++i) {
            uint4 v = ep[i];
            eaR[4 * i] = v.x; eaR[4 * i + 1] = v.y; eaR[4 * i + 2] = v.z; eaR[4 * i + 3] = v.w;
        }
    }

    float sh0, sh1, sh2, sh3, sh4, sh5, sh6, sh7, sh8;
    {
        const size_t sb = eidx * 9;
        if (f32) {
            const float* shp = (const float*)shG + sb;
            sh0 = shp[0]; sh1 = shp[1]; sh2 = shp[2]; sh3 = shp[3]; sh4 = shp[4];
            sh5 = shp[5]; sh6 = shp[6]; sh7 = shp[7]; sh8 = shp[8];
        } else {
            const uint16_t* shp = (const uint16_t*)shG + sb;
            sh0 = bf2f(shp[0]); sh1 = bf2f(shp[1]); sh2 = bf2f(shp[2]);
            sh3 = bf2f(shp[3]); sh4 = bf2f(shp[4]); sh5 = bf2f(shp[5]);
            sh6 = bf2f(shp[6]); sh7 = bf2f(shp[7]); sh8 = bf2f(shp[8]);
        }
    }

    float h[64];
    #pragma unroll
    for (int o = 0; o < 64; ++o) h[o] = Wf[6656 + o];   // b1

    __syncthreads();

    {
        const int rb = rl * 292, sb = sl * 292;
        #pragma unroll 1
        for (int mi = 0; mi < 9; ++mi) {
            float shv = sh0;
            shv = (mi == 1) ? sh1 : shv;  shv = (mi == 2) ? sh2 : shv;
            shv = (mi == 3) ? sh3 : shv;  shv = (mi == 4) ? sh4 : shv;
            shv = (mi == 5) ? sh5 : shv;  shv = (mi == 6) ? sh6 : shv;
            shv = (mi == 7) ? sh7 : shv;  shv = (mi == 8) ? sh8 : shv;
            const int ro = rb + mi * 32, so = sb + mi * 32;
            #pragma unroll
            for (int oc = 0; oc < 32; ++oc) {
                uint32_t pa = ArecS[ro + oc];
                uint32_t pb = AsndS[so + oc];
                float a0 = __uint_as_float(pa << 16);
                float b0 = __uint_as_float(pb << 16);
                float a1 = __uint_as_float(pa & 0xffff0000u);
                float b1 = __uint_as_float(pb & 0xffff0000u);
                h[2 * oc]     += shv * (a0 + b0);
                h[2 * oc + 1] += shv * (a1 + b1);
            }
        }
    }

    {
        #pragma unroll 1
        for (int cd = 0; cd < 16; ++cd) {
            uint32_t p = eaR[cd];
            float e0 = __uint_as_float(p << 16);
            float e1 = __uint_as_float(p & 0xffff0000u);
            const float* w0 = Wf + (2 * cd) * 64;
            #pragma unroll
            for (int o = 0; o < 64; ++o) h[o] += e0 * w0[o];
            #pragma unroll
            for (int o = 0; o < 64; ++o) h[o] += e1 * w0[64 + o];
        }
    }

    #pragma unroll
    for (int o = 0; o < 64; ++o) h[o] = ftanh(h[o]);

    // ---- pack h -> bf16, write swizzled LDS tile (row e = t, stride 32 u32;
    //      16B chunk c stored at c ^ (row&7)) ----
    __syncthreads();   // all ArecS/AsndS reads complete before overwrite
    #pragma unroll
    for (int c = 0; c < 8; ++c) {
        const int cc = c ^ (t & 7);
        *(uint4*)&smem[t * 32 + cc * 4] =
            make_uint4(packbf(h[c * 8 + 0], h[c * 8 + 1]),
                       packbf(h[c * 8 + 2], h[c * 8 + 3]),
                       packbf(h[c * 8 + 4], h[c * 8 + 5]),
                       packbf(h[c * 8 + 6], h[c * 8 + 7]));
    }
    // From here on every LDS row this wave touches is in [wv*64, wv*64+64):
    // written by this wave's own threads -> no further barriers needed
    // (compiler orders ds_write->ds_read via lgkmcnt).

    // ---- layer 2: h2 = tanh(b2 + h @ W2)  via MFMA 16x16x32 bf16 ----
    // A-frag: row = mt*16 + (l&15), k = ks*32 + (l>>4)*8 + j  -> chunk ks*4+g
    f32x4 acc[4][4];
    #pragma unroll
    for (int mm = 0; mm < 4; ++mm) {
        const int row = (wv * 4 + mm) * 16 + nl;
        const s16x8 a0 = *(const s16x8*)&smem[row * 32 + ((g    ) ^ (row & 7)) * 4];
        const s16x8 a1 = *(const s16x8*)&smem[row * 32 + ((4 + g) ^ (row & 7)) * 4];
        #pragma unroll
        for (int nt = 0; nt < 4; ++nt) {
            f32x4 a = {b2v[nt], b2v[nt], b2v[nt], b2v[nt]};
            a = __builtin_amdgcn_mfma_f32_16x16x32_bf16(a0, w2f[nt][0], a, 0, 0, 0);
            a = __builtin_amdgcn_mfma_f32_16x16x32_bf16(a1, w2f[nt][1], a, 0, 0, 0);
            acc[mm][nt] = a;
        }
    }

    // ---- tanh + write h2 (bf16, same swizzle; C layout: col=l&15, row=g*4+reg) ----
    uint16_t* sm16 = (uint16_t*)smem;
    #pragma unroll
    for (int mm = 0; mm < 4; ++mm) {
        const int e2base = (wv * 4 + mm) * 16 + g * 4;
        #pragma unroll
        for (int nt = 0; nt < 4; ++nt) {
            const int n = nt * 16 + nl;
            #pragma unroll
            for (int rg = 0; rg < 4; ++rg) {
                const int e2 = e2base + rg;
                const int cc = (n >> 3) ^ (e2 & 7);
                sm16[e2 * 64 + cc * 8 + (n & 7)] = f2bf(ftanh(acc[mm][nt][rg]));
            }
        }
    }

    // ---- layer 3: ew = b3 + h2 @ W3 ; L += ew ----
    #pragma unroll
    for (int mm = 0; mm < 4; ++mm) {
        const int mt = wv * 4 + mm;
        const int row = mt * 16 + nl;
        const s16x8 a0 = *(const s16x8*)&smem[row * 32 + ((g    ) ^ (row & 7)) * 4];
        const s16x8 a1 = *(const s16x8*)&smem[row * 32 + ((4 + g) ^ (row & 7)) * 4];
        f32x4 a3 = {b3v, b3v, b3v, b3v};
        a3 = __builtin_amdgcn_mfma_f32_16x16x32_bf16(a0, w3f[0], a3, 0, 0, 0);
        a3 = __builtin_amdgcn_mfma_f32_16x16x32_bf16(a1, w3f[1], a3, 0, 0, 0);
        if (nl < 8) {
            float* Lp = L + (((size_t)nl) << 18) + (((size_t)(r0 + mt)) << 9) + s0 + g * 4;
            #pragma unroll
            for (int rg = 0; rg < 4; ++rg) Lp[rg] += a3[rg];
        }
    }
}

// ------------------------------------------------- softmax over senders (SoA)
__global__ __launch_bounds__(256) void kSM(float* __restrict__ L)
{
    const int r = blockIdx.x;
    const int w = threadIdx.x >> 6, lane = threadIdx.x & 63;
    const float C = 1.4426950408889634f;
    #pragma unroll
    for (int hi = 0; hi < 2; ++hi) {
        const int h = w * 2 + hi;
        float4* row4 = reinterpret_cast<float4*>(L + (((size_t)h) << 18) + (((size_t)r) << 9));
        float4 a = row4[lane * 2], b = row4[lane * 2 + 1];
        float m = fmaxf(fmaxf(fmaxf(a.x, a.y), fmaxf(a.z, a.w)),
                        fmaxf(fmaxf(b.x, b.y), fmaxf(b.z, b.w)));
        #pragma unroll
        for (int off = 32; off >= 1; off >>= 1) m = fmaxf(m, __shfl_xor(m, off, 64));
        a.x = __builtin_amdgcn_exp2f((a.x - m) * C);
        a.y = __builtin_amdgcn_exp2f((a.y - m) * C);
        a.z = __builtin_amdgcn_exp2f((a.z - m) * C);
        a.w = __builtin_amdgcn_exp2f((a.w - m) * C);
        b.x = __builtin_amdgcn_exp2f((b.x - m) * C);
        b.y = __builtin_amdgcn_exp2f((b.y - m) * C);
        b.z = __builtin_amdgcn_exp2f((b.z - m) * C);
        b.w = __builtin_amdgcn_exp2f((b.w - m) * C);
        float sm = (a.x + a.y) + (a.z + a.w) + (b.x + b.y) + (b.z + b.w);
        #pragma unroll
        for (int off = 32; off >= 1; off >>= 1) sm += __shfl_xor(sm, off, 64);
        float inv = __builtin_amdgcn_rcpf(sm);
        a.x *= inv; a.y *= inv; a.z *= inv; a.w *= inv;
        b.x *= inv; b.y *= inv; b.z *= inv; b.w *= inv;
        row4[lane * 2] = a; row4[lane * 2 + 1] = b;
    }
}

// ------------------------------------------------- aggregation + residual + store
// 512 threads: task = (j-pair, rr); 8 waves/block; LDS reads broadcast.
__global__ __launch_bounds__(512) void kAgg(
    const float* __restrict__ L, const float* __restrict__ vB,
    const void* __restrict__ nfu, void* __restrict__ out,
    const int* __restrict__ flagp)
{
    __shared__ float Ls[8192];             // [rr(2)][s(512)][h(8)]
    const int f32 = flagp[0];
    const int t = threadIdx.x;
    const int r0 = blockIdx.x * 2;

    for (int i = t; i < 8192; i += 512) {
        int rr = i >> 12, rem = i & 4095;
        int h = rem >> 9, s = rem & 511;
        Ls[rr * 4096 + s * 8 + h] =
            L[(((size_t)h) << 18) + (((size_t)(r0 + rr)) << 9) + s];
    }
    __syncthreads();

    if (t >= 480) return;
    const int jp = t >> 1, rr = t & 1;
    const int j0 = 2 * jp;
    int hh;
    if (j0 < 128)      hh = j0 >> 4;
    else if (j0 < 320) hh = (j0 - 128) / 24;
    else               hh = (j0 - 320) / 20;

    const float* Lrow = Ls + rr * 4096 + hh;
    float a0 = 0.f, a1 = 0.f;
    const float2* vp = reinterpret_cast<const float2*>(vB + j0);
    #pragma unroll 8
    for (int s = 0; s < 512; ++s) {
        float2 v = vp[(size_t)s * 240];
        float w = Lrow[s * 8];
        a0 += w * v.x; a1 += w * v.y;
    }

    const size_t o0 = (size_t)(r0 + rr) * 480 + j0;
    float r00 = ldin(nfu, o0, f32) + a0;
    float r01 = ldin(nfu, o0 + 1, f32) + a1;
    if (f32) {
        float* op = (float*)out;
        op[o0] = r00; op[o0 + 1] = r01;
    } else {
        uint16_t* op = (uint16_t*)out;
        op[o0] = f2bf(r00); op[o0 + 1] = f2bf(r01);
    }
}

extern "C" void kernel_launch(void* const* d_in, const int* in_sizes, int n_in,
                              void* d_out, int out_size, void* d_ws, size_t ws_size,
                              hipStream_t stream)
{
    (void)in_sizes; (void)n_in; (void)out_size; (void)ws_size;
    const void* nf  = d_in[0];
    const void* eaG = d_in[1];
    const void* shG = d_in[2];

    float* ws = (float*)d_ws;
    float* qS  = ws + QS_OFF;
    float* kT4 = ws + KT_OFF;
    float* vB  = ws + VB_OFF;
    uint32_t* ArecG = (uint32_t*)(ws + ARE_OFF);
    uint32_t* AsndG = (uint32_t*)(ws + ASN_OFF);
    float* Wf  = ws + WF_OFF;
    int* flag  = (int*)(ws + FLAG_OFF);
    float* L   = ws + L_OFF;
    float* WtQ = ws + WTQ_OFF;
    float* WtK = ws + WTK_OFF;
    float* WtV = ws + WTV_OFF;
    float* W1T = ws + W1T_OFF;

    kDet<<<1, 64, 0, stream>>>((const uint32_t*)nf, flag);
    kW<<<64, 256, 0, stream>>>(d_in[12], d_in[13], d_in[14], d_in[15], d_in[16], d_in[17],
                               d_in[3], d_in[4], d_in[5], d_in[6], d_in[7], d_in[8],
                               d_in[9], d_in[10], d_in[11], ws, flag);
    kA<<<512, 256, 0, stream>>>(nf, WtQ, WtK, WtV, W1T, qS, kT4, vB, ArecG, AsndG, flag);
    kQK<<<dim3(8, 32, 4), 256, 0, stream>>>(qS, kT4, L);
    kB<<<dim3(32, 32), 256, 0, stream>>>(eaG, shG, ArecG, AsndG, Wf, L, flag);
    kSM<<<512, 256, 0, stream>>>(L);
    kAgg<<<256, 512, 0, stream>>>(L, vB, nf, d_out, flag);
}

// Round 3
// 259.400 us; speedup vs baseline: 1.1572x; 1.1572x over previous
//
#include <hip/hip_runtime.h>
#include <hip/hip_bf16.h>
#include <stdint.h>

// ---------------------------------------------------------------------------
// EquivariantAttention on MI355X.  Dtype-adaptive (bf16 or fp32 inputs).
// R11: consolidated pipeline; kB = 99us, VALU-bound (VALUBusy 46%, MfmaUtil 0).
// R12/R13: kB layers 2+3 -> MFMA 16x16x32 bf16.  Result: VALUBusy 46->30 as
//   predicted BUT VGPR 68->144, occupancy 22.8->10.8%, kB 99->119us.  kB is
//   latency-bound; occupancy is the binding resource (R10 post-mortem).
// R14: same MFMA structure, register-pressure fix:
//   (a) W2/W3 fragment + bias loads moved AFTER phase 1 (post h-pack), pinned
//       by sched_barrier(0) so they are not hoisted into the h[64] region;
//   (b) per-mm fusion: layer2 -> tanh -> h2 pack -> layer3 -> L update per
//       16-row tile, so acc live set is 16 regs not 64.
//   All phase-2 LDS hazards remain intra-wave (same as R13, which passed).
// ---------------------------------------------------------------------------

#define NNODES 512
#define NDIM   480

// ws layout (4-byte word offsets)
#define QS_OFF    0u         // 512*480 f32 q, per-head layout, folds applied
#define KT_OFF    245760u    // k packed: [h(8)][j4(15)][n(512)][4] f32
#define VB_OFF    491520u    // 512*480 f32 v, output-irrep (final) layout
#define ARE_OFF   737280u    // 512*288 u32 (bf16 pairs over o): [n][mi(9)][oc(32)]
#define ASN_OFF   884736u    // 512*288 u32
#define WF_OFF    1032192u   // 8192 f32: W1a[32][64]@0, W2T[64][64]@2048, W3[64][8]@6144, b1@6656, b2@6720, b3@6784
#define FLAG_OFF  1040384u   // flag[0] = 1 if inputs fp32, 0 if bf16
#define L_OFF     1040448u   // L SoA: [h(8)][r(512)][s(512)] f32 (8MB)
#define WTQ_OFF   3137600u   // q weights transposed [o][i] f32 + folds
#define WTK_OFF   3159104u
#define WTV_OFF   3180608u
#define W1T_OFF   3202112u   // mW1 transposed [o(64)][row(480)] f32, cg folded

typedef float f32x4 __attribute__((ext_vector_type(4)));
typedef short s16x8 __attribute__((ext_vector_type(8)));

__device__ __forceinline__ float bf2f(uint16_t u) {
    return __uint_as_float(((uint32_t)u) << 16);
}
__device__ __forceinline__ uint16_t f2bf(float f) {
    union { __hip_bfloat16 h; uint16_t u; } cv;
    cv.h = __float2bfloat16(f);
    return cv.u;
}
__device__ __forceinline__ uint32_t packbf(float lo, float hi) {
    return ((uint32_t)f2bf(hi) << 16) | (uint32_t)f2bf(lo);
}
__device__ __forceinline__ float ldin(const void* p, size_t i, int f32) {
    return f32 ? ((const float*)p)[i] : bf2f(((const uint16_t*)p)[i]);
}
// tanh(x) = 1 - 2/(exp(2x)+1)
__device__ __forceinline__ float ftanh(float x) {
    float e = __builtin_amdgcn_exp2f(x * 2.885390081777927f);
    return 1.0f - 2.0f * __builtin_amdgcn_rcpf(e + 1.0f);
}

// ------------------------------------------------- dtype detector
__global__ __launch_bounds__(64) void kDet(const uint32_t* __restrict__ nf,
                                           int* __restrict__ flag)
{
    int t = threadIdx.x;
    uint32_t x = nf[64 + t];
    int e = (x >> 7) & 0xff;
    int good = (x != 0u) && (e >= 100) && (e <= 140);
    unsigned long long m = __ballot(good);
    if (t == 0) flag[0] = (__popcll(m) < 32) ? 1 : 0;
}

// ---------------------------------------------------------------- weights prep
#define NS 16384
__global__ __launch_bounds__(256) void kW(
    const void* __restrict__ mW1, const void* __restrict__ mb1,
    const void* __restrict__ mW2, const void* __restrict__ mb2,
    const void* __restrict__ mW3, const void* __restrict__ mb3,
    const void* __restrict__ Wq0, const void* __restrict__ Wq1, const void* __restrict__ Wq2,
    const void* __restrict__ Wk0, const void* __restrict__ Wk1, const void* __restrict__ Wk2,
    const void* __restrict__ Wv0, const void* __restrict__ Wv1, const void* __restrict__ Wv2,
    float* __restrict__ ws, const int* __restrict__ flagp)
{
    const int f32 = flagp[0];
    const int gt = blockIdx.x * 256 + threadIdx.x;
    float* Wf = ws + WF_OFF;

    for (int i = gt; i < 2048; i += NS) Wf[i] = ldin(mW1, i, f32);
    for (int i = gt; i < 4096; i += NS) {
        int o2 = i >> 6, ii = i & 63;
        Wf[2048 + i] = ldin(mW2, ii * 64 + o2, f32);
    }
    for (int i = gt; i < 512; i += NS) Wf[6144 + i] = ldin(mW3, i, f32);
    for (int i = gt; i < 64; i += NS) Wf[6656 + i] = ldin(mb1, i, f32);
    for (int i = gt; i < 64; i += NS) Wf[6720 + i] = ldin(mb2, i, f32);
    for (int i = gt; i < 8; i += NS)  Wf[6784 + i] = ldin(mb3, i, f32);

    const float e3n0 = 0.08838834764831845f, e3n1 = 0.125f, e3n2 = 0.17677669529663687f;
    const float cg1 = 0.5773502691896258f, cg2 = 0.4472135954999579f;
    const float attn = 0.1889822365046136f;

    const void* Wsrc[9] = {Wq0, Wq1, Wq2, Wk0, Wk1, Wk2, Wv0, Wv1, Wv2};
    float* Wdst[3] = {ws + WTQ_OFF, ws + WTK_OFF, ws + WTV_OFF};
    for (int kind = 0; kind < 3; ++kind) {
        const float f0 = (kind == 0) ? e3n0 * attn : e3n0;
        const float f1 = (kind == 0) ? e3n1 * cg1 * attn : e3n1;
        const float f2 = (kind == 0) ? e3n2 * cg2 * attn : e3n2;
        for (int i = gt; i < 16384; i += NS) {
            int o = i >> 7, ii = i & 127;
            Wdst[kind][i] = ldin(Wsrc[kind * 3], (size_t)ii * 128 + o, f32) * f0;
        }
        for (int i = gt; i < 4096; i += NS) {
            int o = i >> 6, ii = i & 63;
            Wdst[kind][16384 + i] = ldin(Wsrc[kind * 3 + 1], (size_t)ii * 64 + o, f32) * f1;
        }
        for (int i = gt; i < 1024; i += NS) {
            int o = i >> 5, ii = i & 31;
            Wdst[kind][20480 + i] = ldin(Wsrc[kind * 3 + 2], (size_t)ii * 32 + o, f32) * f2;
        }
    }
    float* W1T = ws + W1T_OFF;
    for (int i = gt; i < 30720; i += NS) {
        int o = i / 480, row = i - o * 480;
        float cgv;
        if (row < 160)      cgv = 1.0f;
        else if (row < 224) cgv = cg1;
        else if (row < 256) cgv = cg2;
        else if (row < 384) cgv = 1.0f;
        else if (row < 448) cgv = cg1;
        else                cgv = cg2;
        W1T[i] = ldin(mW1, (size_t)row * 64 + o, f32) * cgv;
    }
}

// ------------------------------------------------- per-node precompute
__global__ __launch_bounds__(256) void kA(
    const void* __restrict__ nfu,
    const float* __restrict__ WtQ, const float* __restrict__ WtK,
    const float* __restrict__ WtV, const float* __restrict__ W1T,
    float* __restrict__ qS, float* __restrict__ kT4, float* __restrict__ vB,
    uint32_t* __restrict__ ArecG, uint32_t* __restrict__ AsndG,
    const int* __restrict__ flagp)
{
    const int f32 = flagp[0];
    const int n = blockIdx.x, t = threadIdx.x;
    __shared__ float nfs[480];
    for (int i = t; i < 480; i += 256) nfs[i] = ldin(nfu, (size_t)n * 480 + i, f32);
    __syncthreads();

    for (int idx = t; idx < 1440; idx += 256) {
        int kind = idx / 480, rem = idx - kind * 480;
        int o, m, mul, d, off, am, qoff, sub;
        if (rem < 128)      { o = rem;           m = 0;          mul = 128; d = 1; off = 0;   am = 16; qoff = 0;  sub = 0; }
        else if (rem < 320) { int x = rem - 128; o = x / 3; m = x - o * 3; mul = 64;  d = 3; off = 128; am = 8;  qoff = 16; sub = 16384; }
        else                { int x = rem - 320; o = x / 5; m = x - o * 5; mul = 32;  d = 5; off = 320; am = 4;  qoff = 40; sub = 20480; }
        const float* base = (kind == 0) ? WtQ : (kind == 1) ? WtK : WtV;
        const float4* W4 = reinterpret_cast<const float4*>(base + sub + o * mul);
        const float* nf0 = nfs + off + m;
        float ax = 0.f, ay = 0.f, az = 0.f, aw = 0.f;
        const int n4 = mul >> 2;
        for (int i4 = 0; i4 < n4; ++i4) {
            float4 w = W4[i4];
            int ib = 4 * i4 * d;
            ax += nf0[ib]         * w.x;
            ay += nf0[ib + d]     * w.y;
            az += nf0[ib + 2 * d] * w.z;
            aw += nf0[ib + 3 * d] * w.w;
        }
        float acc = (ax + ay) + (az + aw);
        if (kind == 2) {
            vB[(size_t)n * 480 + rem] = acc;
        } else {
            int hh = o / am, a = o - hh * am;
            int j = qoff + a * d + m;
            if (kind == 0) qS[(size_t)n * 480 + hh * 60 + j] = acc;
            else           kT4[((size_t)(hh * 15 + (j >> 2)) * 512 + n) * 4 + (j & 3)] = acc;
        }
    }

    if (t < 128) {
        const int src = t >> 6, o = t & 63;
        float a[9];
        #pragma unroll
        for (int mi = 0; mi < 9; ++mi) {
            const int l = (mi == 0) ? 0 : (mi < 4 ? 1 : 2);
            const int m = (mi == 0) ? 0 : (mi < 4 ? mi - 1 : mi - 4);
            const int mul = (l == 0 ? 128 : l == 1 ? 64 : 32);
            const int d = 2 * l + 1;
            const int off = (l == 0 ? 0 : l == 1 ? 128 : 320);
            const int base = (src == 0) ? (l == 0 ? 32 : l == 1 ? 160 : 224)
                                        : (l == 0 ? 256 : l == 1 ? 384 : 448);
            const float4* W4 = reinterpret_cast<const float4*>(W1T + o * 480 + base);
            const float* nf0 = nfs + off + m;
            float ax = 0.f, ay = 0.f, az = 0.f, aw = 0.f;
            const int n4 = mul >> 2;
            for (int i4 = 0; i4 < n4; ++i4) {
                float4 w = W4[i4];
                int ib = 4 * i4 * d;
                ax += nf0[ib]         * w.x;
                ay += nf0[ib + d]     * w.y;
                az += nf0[ib + 2 * d] * w.z;
                aw += nf0[ib + 3 * d] * w.w;
            }
            a[mi] = (ax + ay) + (az + aw);
        }
        float b[9];
        #pragma unroll
        for (int mi = 0; mi < 9; ++mi) b[mi] = __shfl_xor(a[mi], 1, 64);
        if ((o & 1) == 0) {
            uint32_t* dst = (src ? AsndG : ArecG) + (size_t)n * 288 + (o >> 1);
            #pragma unroll
            for (int mi = 0; mi < 9; ++mi)
                dst[mi * 32] = ((uint32_t)f2bf(b[mi]) << 16) | (uint32_t)f2bf(a[mi]);
        }
    }
}

// ------------------------------------------------- q.k logits -> L (SoA)
__global__ __launch_bounds__(256) void kQK(
    const float* __restrict__ qS, const float* __restrict__ kT4,
    float* __restrict__ L)
{
    __shared__ float qL[16 * 120];        // [r16][(h-hb)*60 + j]
    const int t = threadIdx.x;
    const int lane = t & 63, wave = t >> 6;
    const int s0 = blockIdx.x * 64, r0 = blockIdx.y * 16, hb = blockIdx.z * 2;

    {
        float4* qL4 = reinterpret_cast<float4*>(qL);
        for (int i = t; i < 480; i += 256) {
            int rr = i / 30, c4 = i - rr * 30;
            qL4[i] = reinterpret_cast<const float4*>(
                         qS + (size_t)(r0 + rr) * 480 + hb * 60)[c4];
        }
    }
    __syncthreads();

    const int s = s0 + lane;
    const int rw = wave * 4;
    const float4* qL4 = reinterpret_cast<const float4*>(qL);
    const float4* k4  = reinterpret_cast<const float4*>(kT4);

    float acc[8];
    #pragma unroll
    for (int i = 0; i < 8; ++i) acc[i] = 0.f;

    #pragma unroll
    for (int h4 = 0; h4 < 2; ++h4) {
        const int h = hb + h4;
        #pragma unroll 5
        for (int j4 = 0; j4 < 15; ++j4) {
            float4 kv = k4[(size_t)(h * 15 + j4) * 512 + s];
            #pragma unroll
            for (int r = 0; r < 4; ++r) {
                float4 qv = qL4[(rw + r) * 30 + h4 * 15 + j4];
                acc[r * 2 + h4] += qv.x * kv.x + qv.y * kv.y + qv.z * kv.z + qv.w * kv.w;
            }
        }
    }
    #pragma unroll
    for (int r = 0; r < 4; ++r) {
        #pragma unroll
        for (int h4 = 0; h4 < 2; ++h4) {
            L[(((size_t)(hb + h4)) << 18) + (((size_t)(r0 + rw + r)) << 9) + s] = acc[r * 2 + h4];
        }
    }
}

// ------------------------------------------------- edge MLP (full grid)
// Phase 1 (VALU, per-thread = per-edge): h = tanh(b1 + sh.(Arec+Asnd) + ea@W1a)
// Phase 2 (MFMA, per-mm fused): h2 = tanh(b2 + h@W2) ; ew = b3 + h2@W3 ; L += ew
__global__ __launch_bounds__(256) void kB(
    const void* __restrict__ eaG, const void* __restrict__ shG,
    const uint32_t* __restrict__ ArecG, const uint32_t* __restrict__ AsndG,
    const float* __restrict__ Wf, float* __restrict__ L,
    const int* __restrict__ flagp)
{
    // phase1: ArecS[16*292] @0, AsndS[16*292] @4672  (37376 B)
    // phase2: hS  256 rows x 32 u32 (bf16 pairs), 16B-chunk XOR swizzle (32768 B)
    __shared__ __align__(16) uint32_t smem[9344];
    uint32_t* ArecS = smem;
    uint32_t* AsndS = smem + 4672;
    const int f32 = flagp[0];
    const int t = threadIdx.x;
    const int s0 = blockIdx.x * 16, r0 = blockIdx.y * 16;
    const int lane = t & 63, wv = t >> 6;
    const int g = lane >> 4, nl = lane & 15;

    for (int i = t; i < 16 * 288; i += 256) {
        int row = i / 288, c = i - row * 288;
        ArecS[row * 292 + c] = ArecG[(size_t)(r0 + row) * 288 + c];
        AsndS[row * 292 + c] = AsndG[(size_t)(s0 + row) * 288 + c];
    }

    const int rl = t >> 4, sl = t & 15;
    const int r = r0 + rl, s = s0 + sl;
    const size_t eidx = (((size_t)r) << 9) + s;

    uint32_t eaR[16];
    if (f32) {
        const float4* ep = reinterpret_cast<const float4*>((const float*)eaG + eidx * 32);
        #pragma unroll
        for (int i = 0; i < 8; ++i) {
            float4 v = ep[i];
            eaR[2 * i]     = ((uint32_t)f2bf(v.y) << 16) | (uint32_t)f2bf(v.x);
            eaR[2 * i + 1] = ((uint32_t)f2bf(v.w) << 16) | (uint32_t)f2bf(v.z);
        }
    } else {
        const uint4* ep = reinterpret_cast<const uint4*>((const uint32_t*)eaG + eidx * 16);
        #pragma unroll
        for (int i = 0; i < 4; ++i) {
            uint4 v = ep[i];
            eaR[4 * i] = v.x; eaR[4 * i + 1] = v.y; eaR[4 * i + 2] = v.z; eaR[4 * i + 3] = v.w;
        }
    }

    float sh0, sh1, sh2, sh3, sh4, sh5, sh6, sh7, sh8;
    {
        const size_t sb = eidx * 9;
        if (f32) {
            const float* shp = (const float*)shG + sb;
            sh0 = shp[0]; sh1 = shp[1]; sh2 = shp[2]; sh3 = shp[3]; sh4 = shp[4];
            sh5 = shp[5]; sh6 = shp[6]; sh7 = shp[7]; sh8 = shp[8];
        } else {
            const uint16_t* shp = (const uint16_t*)shG + sb;
            sh0 = bf2f(shp[0]); sh1 = bf2f(shp[1]); sh2 = bf2f(shp[2]);
            sh3 = bf2f(shp[3]); sh4 = bf2f(shp[4]); sh5 = bf2f(shp[5]);
            sh6 = bf2f(shp[6]); sh7 = bf2f(shp[7]); sh8 = bf2f(shp[8]);
        }
    }

    float h[64];
    #pragma unroll
    for (int o = 0; o < 64; ++o) h[o] = Wf[6656 + o];   // b1

    __syncthreads();

    {
        const int rb = rl * 292, sb = sl * 292;
        #pragma unroll 1
        for (int mi = 0; mi < 9; ++mi) {
            float shv = sh0;
            shv = (mi == 1) ? sh1 : shv;  shv = (mi == 2) ? sh2 : shv;
            shv = (mi == 3) ? sh3 : shv;  shv = (mi == 4) ? sh4 : shv;
            shv = (mi == 5) ? sh5 : shv;  shv = (mi == 6) ? sh6 : shv;
            shv = (mi == 7) ? sh7 : shv;  shv = (mi == 8) ? sh8 : shv;
            const int ro = rb + mi * 32, so = sb + mi * 32;
            #pragma unroll
            for (int oc = 0; oc < 32; ++oc) {
                uint32_t pa = ArecS[ro + oc];
                uint32_t pb = AsndS[so + oc];
                float a0 = __uint_as_float(pa << 16);
                float b0 = __uint_as_float(pb << 16);
                float a1 = __uint_as_float(pa & 0xffff0000u);
                float b1 = __uint_as_float(pb & 0xffff0000u);
                h[2 * oc]     += shv * (a0 + b0);
                h[2 * oc + 1] += shv * (a1 + b1);
            }
        }
    }

    {
        #pragma unroll 1
        for (int cd = 0; cd < 16; ++cd) {
            uint32_t p = eaR[cd];
            float e0 = __uint_as_float(p << 16);
            float e1 = __uint_as_float(p & 0xffff0000u);
            const float* w0 = Wf + (2 * cd) * 64;
            #pragma unroll
            for (int o = 0; o < 64; ++o) h[o] += e0 * w0[o];
            #pragma unroll
            for (int o = 0; o < 64; ++o) h[o] += e1 * w0[64 + o];
        }
    }

    #pragma unroll
    for (int o = 0; o < 64; ++o) h[o] = ftanh(h[o]);

    // ---- pack h -> bf16, write swizzled LDS tile (row e = t, stride 32 u32;
    //      16B chunk c stored at c ^ (row&7)) ----
    __syncthreads();   // all ArecS/AsndS reads complete before overwrite
    #pragma unroll
    for (int c = 0; c < 8; ++c) {
        const int cc = c ^ (t & 7);
        *(uint4*)&smem[t * 32 + cc * 4] =
            make_uint4(packbf(h[c * 8 + 0], h[c * 8 + 1]),
                       packbf(h[c * 8 + 2], h[c * 8 + 3]),
                       packbf(h[c * 8 + 4], h[c * 8 + 5]),
                       packbf(h[c * 8 + 6], h[c * 8 + 7]));
    }
    // Pin: nothing below (W-fragment loads) may be hoisted above this point —
    // keeping phase-1 peak pressure at the R11 level is the whole point.
    __builtin_amdgcn_sched_barrier(0);

    // ---- W2T/W3T B-fragments + biases into registers (AFTER phase 1) ----
    // B-frag 16x16x32: lane holds col n = (l&15)+16*nt, k = ks*32 + (l>>4)*8 + j
    s16x8 w2f[4][2];
    #pragma unroll
    for (int nt = 0; nt < 4; ++nt) {
        #pragma unroll
        for (int ks = 0; ks < 2; ++ks) {
            const float* p = Wf + 2048 + (nt * 16 + nl) * 64 + ks * 32 + g * 8;
            s16x8 b;
            #pragma unroll
            for (int j = 0; j < 8; ++j) b[j] = (short)f2bf(p[j]);
            w2f[nt][ks] = b;
        }
    }
    s16x8 w3f[2];
    #pragma unroll
    for (int ks = 0; ks < 2; ++ks) {
        s16x8 b;
        #pragma unroll
        for (int j = 0; j < 8; ++j)
            b[j] = (short)((nl < 8) ? f2bf(Wf[6144 + (ks * 32 + g * 8 + j) * 8 + nl]) : 0);
        w3f[ks] = b;
    }
    float b2v[4];
    #pragma unroll
    for (int nt = 0; nt < 4; ++nt) b2v[nt] = Wf[6720 + nt * 16 + nl];
    const float b3v = (nl < 8) ? Wf[6784 + nl] : 0.f;

    // From here on every LDS row this wave touches is in [wv*64, wv*64+64):
    // written by this wave's own threads -> no barriers needed (per-wave LDS
    // ordering + compiler lgkmcnt).

    // ---- fused per-mm: layer2 -> tanh -> h2 pack -> layer3 -> L update ----
    uint16_t* sm16 = (uint16_t*)smem;
    #pragma unroll 1
    for (int mm = 0; mm < 4; ++mm) {
        const int mt = wv * 4 + mm;
        const int row = mt * 16 + nl;
        const int sw0 = ((g    ) ^ (row & 7)) * 4;
        const int sw1 = ((4 + g) ^ (row & 7)) * 4;
        // layer 2: A-frag row = mt*16 + (l&15), k = ks*32 + (l>>4)*8 + j
        const s16x8 a0 = *(const s16x8*)&smem[row * 32 + sw0];
        const s16x8 a1 = *(const s16x8*)&smem[row * 32 + sw1];
        f32x4 acc[4];
        #pragma unroll
        for (int nt = 0; nt < 4; ++nt) {
            f32x4 a = {b2v[nt], b2v[nt], b2v[nt], b2v[nt]};
            a = __builtin_amdgcn_mfma_f32_16x16x32_bf16(a0, w2f[nt][0], a, 0, 0, 0);
            a = __builtin_amdgcn_mfma_f32_16x16x32_bf16(a1, w2f[nt][1], a, 0, 0, 0);
            acc[nt] = a;
        }
        // tanh + h2 write (bf16, same swizzle; C layout: col=l&15, row=g*4+reg)
        const int e2base = mt * 16 + g * 4;
        #pragma unroll
        for (int nt = 0; nt < 4; ++nt) {
            const int n = nt * 16 + nl;
            #pragma unroll
            for (int rg = 0; rg < 4; ++rg) {
                const int e2 = e2base + rg;
                const int cc = (n >> 3) ^ (e2 & 7);
                sm16[e2 * 64 + cc * 8 + (n & 7)] = f2bf(ftanh(acc[nt][rg]));
            }
        }
        // layer 3: re-read same rows (now h2) — in-wave LDS ordering guarantees
        // the writes above are observed.
        const s16x8 c0 = *(const s16x8*)&smem[row * 32 + sw0];
        const s16x8 c1 = *(const s16x8*)&smem[row * 32 + sw1];
        f32x4 a3 = {b3v, b3v, b3v, b3v};
        a3 = __builtin_amdgcn_mfma_f32_16x16x32_bf16(c0, w3f[0], a3, 0, 0, 0);
        a3 = __builtin_amdgcn_mfma_f32_16x16x32_bf16(c1, w3f[1], a3, 0, 0, 0);
        if (nl < 8) {
            float* Lp = L + (((size_t)nl) << 18) + (((size_t)(r0 + mt)) << 9) + s0 + g * 4;
            #pragma unroll
            for (int rg = 0; rg < 4; ++rg) Lp[rg] += a3[rg];
        }
    }
}

// ------------------------------------------------- softmax over senders (SoA)
__global__ __launch_bounds__(256) void kSM(float* __restrict__ L)
{
    const int r = blockIdx.x;
    const int w = threadIdx.x >> 6, lane = threadIdx.x & 63;
    const float C = 1.4426950408889634f;
    #pragma unroll
    for (int hi = 0; hi < 2; ++hi) {
        const int h = w * 2 + hi;
        float4* row4 = reinterpret_cast<float4*>(L + (((size_t)h) << 18) + (((size_t)r) << 9));
        float4 a = row4[lane * 2], b = row4[lane * 2 + 1];
        float m = fmaxf(fmaxf(fmaxf(a.x, a.y), fmaxf(a.z, a.w)),
                        fmaxf(fmaxf(b.x, b.y), fmaxf(b.z, b.w)));
        #pragma unroll
        for (int off = 32; off >= 1; off >>= 1) m = fmaxf(m, __shfl_xor(m, off, 64));
        a.x = __builtin_amdgcn_exp2f((a.x - m) * C);
        a.y = __builtin_amdgcn_exp2f((a.y - m) * C);
        a.z = __builtin_amdgcn_exp2f((a.z - m) * C);
        a.w = __builtin_amdgcn_exp2f((a.w - m) * C);
        b.x = __builtin_amdgcn_exp2f((b.x - m) * C);
        b.y = __builtin_amdgcn_exp2f((b.y - m) * C);
        b.z = __builtin_amdgcn_exp2f((b.z - m) * C);
        b.w = __builtin_amdgcn_exp2f((b.w - m) * C);
        float sm = (a.x + a.y) + (a.z + a.w) + (b.x + b.y) + (b.z + b.w);
        #pragma unroll
        for (int off = 32; off >= 1; off >>= 1) sm += __shfl_xor(sm, off, 64);
        float inv = __builtin_amdgcn_rcpf(sm);
        a.x *= inv; a.y *= inv; a.z *= inv; a.w *= inv;
        b.x *= inv; b.y *= inv; b.z *= inv; b.w *= inv;
        row4[lane * 2] = a; row4[lane * 2 + 1] = b;
    }
}

// ------------------------------------------------- aggregation + residual + store
// 512 threads: task = (j-pair, rr); 8 waves/block; LDS reads broadcast.
__global__ __launch_bounds__(512) void kAgg(
    const float* __restrict__ L, const float* __restrict__ vB,
    const void* __restrict__ nfu, void* __restrict__ out,
    const int* __restrict__ flagp)
{
    __shared__ float Ls[8192];             // [rr(2)][s(512)][h(8)]
    const int f32 = flagp[0];
    const int t = threadIdx.x;
    const int r0 = blockIdx.x * 2;

    for (int i = t; i < 8192; i += 512) {
        int rr = i >> 12, rem = i & 4095;
        int h = rem >> 9, s = rem & 511;
        Ls[rr * 4096 + s * 8 + h] =
            L[(((size_t)h) << 18) + (((size_t)(r0 + rr)) << 9) + s];
    }
    __syncthreads();

    if (t >= 480) return;
    const int jp = t >> 1, rr = t & 1;
    const int j0 = 2 * jp;
    int hh;
    if (j0 < 128)      hh = j0 >> 4;
    else if (j0 < 320) hh = (j0 - 128) / 24;
    else               hh = (j0 - 320) / 20;

    const float* Lrow = Ls + rr * 4096 + hh;
    float a0 = 0.f, a1 = 0.f;
    const float2* vp = reinterpret_cast<const float2*>(vB + j0);
    #pragma unroll 8
    for (int s = 0; s < 512; ++s) {
        float2 v = vp[(size_t)s * 240];
        float w = Lrow[s * 8];
        a0 += w * v.x; a1 += w * v.y;
    }

    const size_t o0 = (size_t)(r0 + rr) * 480 + j0;
    float r00 = ldin(nfu, o0, f32) + a0;
    float r01 = ldin(nfu, o0 + 1, f32) + a1;
    if (f32) {
        float* op = (float*)out;
        op[o0] = r00; op[o0 + 1] = r01;
    } else {
        uint16_t* op = (uint16_t*)out;
        op[o0] = f2bf(r00); op[o0 + 1] = f2bf(r01);
    }
}

extern "C" void kernel_launch(void* const* d_in, const int* in_sizes, int n_in,
                              void* d_out, int out_size, void* d_ws, size_t ws_size,
                              hipStream_t stream)
{
    (void)in_sizes; (void)n_in; (void)out_size; (void)ws_size;
    const void* nf  = d_in[0];
    const void* eaG = d_in[1];
    const void* shG = d_in[2];

    float* ws = (float*)d_ws;
    float* qS  = ws + QS_OFF;
    float* kT4 = ws + KT_OFF;
    float* vB  = ws + VB_OFF;
    uint32_t* ArecG = (uint32_t*)(ws + ARE_OFF);
    uint32_t* AsndG = (uint32_t*)(ws + ASN_OFF);
    float* Wf  = ws + WF_OFF;
    int* flag  = (int*)(ws + FLAG_OFF);
    float* L   = ws + L_OFF;
    float* WtQ = ws + WTQ_OFF;
    float* WtK = ws + WTK_OFF;
    float* WtV = ws + WTV_OFF;
    float* W1T = ws + W1T_OFF;

    kDet<<<1, 64, 0, stream>>>((const uint32_t*)nf, flag);
    kW<<<64, 256, 0, stream>>>(d_in[12], d_in[13], d_in[14], d_in[15], d_in[16], d_in[17],
                               d_in[3], d_in[4], d_in[5], d_in[6], d_in[7], d_in[8],
                               d_in[9], d_in[10], d_in[11], ws, flag);
    kA<<<512, 256, 0, stream>>>(nf, WtQ, WtK, WtV, W1T, qS, kT4, vB, ArecG, AsndG, flag);
    kQK<<<dim3(8, 32, 4), 256, 0, stream>>>(qS, kT4, L);
    kB<<<dim3(32, 32), 256, 0, stream>>>(eaG, shG, ArecG, AsndG, Wf, L, flag);
    kSM<<<512, 256, 0, stream>>>(L);
    kAgg<<<256, 512, 0, stream>>>(L, vB, nf, d_out, flag);
}

// Round 4
// 252.771 us; speedup vs baseline: 1.1876x; 1.0262x over previous
//
#include <hip/hip_runtime.h>
#include <hip/hip_bf16.h>
#include <stdint.h>

// ---------------------------------------------------------------------------
// EquivariantAttention on MI355X.  Dtype-adaptive (bf16 or fp32 inputs).
// R11: consolidated pipeline; kB = 99us, VALU-bound (VALUBusy 46%, MfmaUtil 0).
// R12/R13: kB layers 2+3 -> MFMA.  VGPR 68->144, occ 22.8->10.8%, kB 119us.
// R14: register-pressure fix (W-frags loaded post-phase-1 behind
//   sched_barrier(0); per-mm fusion).  VGPR 84, occ 22.4%, kB 74us, tot 259.
// R15: fuse kQK INTO kB (logits via MFMA) and delete the kQK dispatch.
//   - kA now writes k row-major per-head (kS[n][h*60+j], mirror of qS).
//   - kB prologue: stage q/k tiles bf16 [h][row][64] (K 60->64 zero-pad) into
//     the 32KB h-tile LDS region with the same XOR swizzle (measured 0 bank
//     conflicts), 2 heads/wave x 2 MFMA -> write raw logits to L.  Later
//     "L += ew" epilogue unchanged (same-block RMW; 2 barriers drain vmcnt).
//   - Arec/Asnd staging moved after logits phase; LDS stays 37376B.
//   - __launch_bounds__(256,4) pins VGPR <= 128 (R13 failure mode insurance).
// ---------------------------------------------------------------------------

#define NNODES 512
#define NDIM   480

// ws layout (4-byte word offsets)
#define QS_OFF    0u         // 512*480 f32 q, per-head layout, folds applied
#define KT_OFF    245760u    // 512*480 f32 k, per-head layout (row-major, R15)
#define VB_OFF    491520u    // 512*480 f32 v, output-irrep (final) layout
#define ARE_OFF   737280u    // 512*288 u32 (bf16 pairs over o): [n][mi(9)][oc(32)]
#define ASN_OFF   884736u    // 512*288 u32
#define WF_OFF    1032192u   // 8192 f32: W1a[32][64]@0, W2T[64][64]@2048, W3[64][8]@6144, b1@6656, b2@6720, b3@6784
#define FLAG_OFF  1040384u   // flag[0] = 1 if inputs fp32, 0 if bf16
#define L_OFF     1040448u   // L SoA: [h(8)][r(512)][s(512)] f32 (8MB)
#define WTQ_OFF   3137600u   // q weights transposed [o][i] f32 + folds
#define WTK_OFF   3159104u
#define WTV_OFF   3180608u
#define W1T_OFF   3202112u   // mW1 transposed [o(64)][row(480)] f32, cg folded

typedef float f32x4 __attribute__((ext_vector_type(4)));
typedef short s16x8 __attribute__((ext_vector_type(8)));

__device__ __forceinline__ float bf2f(uint16_t u) {
    return __uint_as_float(((uint32_t)u) << 16);
}
__device__ __forceinline__ uint16_t f2bf(float f) {
    union { __hip_bfloat16 h; uint16_t u; } cv;
    cv.h = __float2bfloat16(f);
    return cv.u;
}
__device__ __forceinline__ uint32_t packbf(float lo, float hi) {
    return ((uint32_t)f2bf(hi) << 16) | (uint32_t)f2bf(lo);
}
__device__ __forceinline__ float ldin(const void* p, size_t i, int f32) {
    return f32 ? ((const float*)p)[i] : bf2f(((const uint16_t*)p)[i]);
}
// tanh(x) = 1 - 2/(exp(2x)+1)
__device__ __forceinline__ float ftanh(float x) {
    float e = __builtin_amdgcn_exp2f(x * 2.885390081777927f);
    return 1.0f - 2.0f * __builtin_amdgcn_rcpf(e + 1.0f);
}

// ------------------------------------------------- dtype detector
__global__ __launch_bounds__(64) void kDet(const uint32_t* __restrict__ nf,
                                           int* __restrict__ flag)
{
    int t = threadIdx.x;
    uint32_t x = nf[64 + t];
    int e = (x >> 7) & 0xff;
    int good = (x != 0u) && (e >= 100) && (e <= 140);
    unsigned long long m = __ballot(good);
    if (t == 0) flag[0] = (__popcll(m) < 32) ? 1 : 0;
}

// ---------------------------------------------------------------- weights prep
#define NS 16384
__global__ __launch_bounds__(256) void kW(
    const void* __restrict__ mW1, const void* __restrict__ mb1,
    const void* __restrict__ mW2, const void* __restrict__ mb2,
    const void* __restrict__ mW3, const void* __restrict__ mb3,
    const void* __restrict__ Wq0, const void* __restrict__ Wq1, const void* __restrict__ Wq2,
    const void* __restrict__ Wk0, const void* __restrict__ Wk1, const void* __restrict__ Wk2,
    const void* __restrict__ Wv0, const void* __restrict__ Wv1, const void* __restrict__ Wv2,
    float* __restrict__ ws, const int* __restrict__ flagp)
{
    const int f32 = flagp[0];
    const int gt = blockIdx.x * 256 + threadIdx.x;
    float* Wf = ws + WF_OFF;

    for (int i = gt; i < 2048; i += NS) Wf[i] = ldin(mW1, i, f32);
    for (int i = gt; i < 4096; i += NS) {
        int o2 = i >> 6, ii = i & 63;
        Wf[2048 + i] = ldin(mW2, ii * 64 + o2, f32);
    }
    for (int i = gt; i < 512; i += NS) Wf[6144 + i] = ldin(mW3, i, f32);
    for (int i = gt; i < 64; i += NS) Wf[6656 + i] = ldin(mb1, i, f32);
    for (int i = gt; i < 64; i += NS) Wf[6720 + i] = ldin(mb2, i, f32);
    for (int i = gt; i < 8; i += NS)  Wf[6784 + i] = ldin(mb3, i, f32);

    const float e3n0 = 0.08838834764831845f, e3n1 = 0.125f, e3n2 = 0.17677669529663687f;
    const float cg1 = 0.5773502691896258f, cg2 = 0.4472135954999579f;
    const float attn = 0.1889822365046136f;

    const void* Wsrc[9] = {Wq0, Wq1, Wq2, Wk0, Wk1, Wk2, Wv0, Wv1, Wv2};
    float* Wdst[3] = {ws + WTQ_OFF, ws + WTK_OFF, ws + WTV_OFF};
    for (int kind = 0; kind < 3; ++kind) {
        const float f0 = (kind == 0) ? e3n0 * attn : e3n0;
        const float f1 = (kind == 0) ? e3n1 * cg1 * attn : e3n1;
        const float f2 = (kind == 0) ? e3n2 * cg2 * attn : e3n2;
        for (int i = gt; i < 16384; i += NS) {
            int o = i >> 7, ii = i & 127;
            Wdst[kind][i] = ldin(Wsrc[kind * 3], (size_t)ii * 128 + o, f32) * f0;
        }
        for (int i = gt; i < 4096; i += NS) {
            int o = i >> 6, ii = i & 63;
            Wdst[kind][16384 + i] = ldin(Wsrc[kind * 3 + 1], (size_t)ii * 64 + o, f32) * f1;
        }
        for (int i = gt; i < 1024; i += NS) {
            int o = i >> 5, ii = i & 31;
            Wdst[kind][20480 + i] = ldin(Wsrc[kind * 3 + 2], (size_t)ii * 32 + o, f32) * f2;
        }
    }
    float* W1T = ws + W1T_OFF;
    for (int i = gt; i < 30720; i += NS) {
        int o = i / 480, row = i - o * 480;
        float cgv;
        if (row < 160)      cgv = 1.0f;
        else if (row < 224) cgv = cg1;
        else if (row < 256) cgv = cg2;
        else if (row < 384) cgv = 1.0f;
        else if (row < 448) cgv = cg1;
        else                cgv = cg2;
        W1T[i] = ldin(mW1, (size_t)row * 64 + o, f32) * cgv;
    }
}

// ------------------------------------------------- per-node precompute
__global__ __launch_bounds__(256) void kA(
    const void* __restrict__ nfu,
    const float* __restrict__ WtQ, const float* __restrict__ WtK,
    const float* __restrict__ WtV, const float* __restrict__ W1T,
    float* __restrict__ qS, float* __restrict__ kS, float* __restrict__ vB,
    uint32_t* __restrict__ ArecG, uint32_t* __restrict__ AsndG,
    const int* __restrict__ flagp)
{
    const int f32 = flagp[0];
    const int n = blockIdx.x, t = threadIdx.x;
    __shared__ float nfs[480];
    for (int i = t; i < 480; i += 256) nfs[i] = ldin(nfu, (size_t)n * 480 + i, f32);
    __syncthreads();

    for (int idx = t; idx < 1440; idx += 256) {
        int kind = idx / 480, rem = idx - kind * 480;
        int o, m, mul, d, off, am, qoff, sub;
        if (rem < 128)      { o = rem;           m = 0;          mul = 128; d = 1; off = 0;   am = 16; qoff = 0;  sub = 0; }
        else if (rem < 320) { int x = rem - 128; o = x / 3; m = x - o * 3; mul = 64;  d = 3; off = 128; am = 8;  qoff = 16; sub = 16384; }
        else                { int x = rem - 320; o = x / 5; m = x - o * 5; mul = 32;  d = 5; off = 320; am = 4;  qoff = 40; sub = 20480; }
        const float* base = (kind == 0) ? WtQ : (kind == 1) ? WtK : WtV;
        const float4* W4 = reinterpret_cast<const float4*>(base + sub + o * mul);
        const float* nf0 = nfs + off + m;
        float ax = 0.f, ay = 0.f, az = 0.f, aw = 0.f;
        const int n4 = mul >> 2;
        for (int i4 = 0; i4 < n4; ++i4) {
            float4 w = W4[i4];
            int ib = 4 * i4 * d;
            ax += nf0[ib]         * w.x;
            ay += nf0[ib + d]     * w.y;
            az += nf0[ib + 2 * d] * w.z;
            aw += nf0[ib + 3 * d] * w.w;
        }
        float acc = (ax + ay) + (az + aw);
        if (kind == 2) {
            vB[(size_t)n * 480 + rem] = acc;
        } else {
            int hh = o / am, a = o - hh * am;
            int j = qoff + a * d + m;
            if (kind == 0) qS[(size_t)n * 480 + hh * 60 + j] = acc;
            else           kS[(size_t)n * 480 + hh * 60 + j] = acc;
        }
    }

    if (t < 128) {
        const int src = t >> 6, o = t & 63;
        float a[9];
        #pragma unroll
        for (int mi = 0; mi < 9; ++mi) {
            const int l = (mi == 0) ? 0 : (mi < 4 ? 1 : 2);
            const int m = (mi == 0) ? 0 : (mi < 4 ? mi - 1 : mi - 4);
            const int mul = (l == 0 ? 128 : l == 1 ? 64 : 32);
            const int d = 2 * l + 1;
            const int off = (l == 0 ? 0 : l == 1 ? 128 : 320);
            const int base = (src == 0) ? (l == 0 ? 32 : l == 1 ? 160 : 224)
                                        : (l == 0 ? 256 : l == 1 ? 384 : 448);
            const float4* W4 = reinterpret_cast<const float4*>(W1T + o * 480 + base);
            const float* nf0 = nfs + off + m;
            float ax = 0.f, ay = 0.f, az = 0.f, aw = 0.f;
            const int n4 = mul >> 2;
            for (int i4 = 0; i4 < n4; ++i4) {
                float4 w = W4[i4];
                int ib = 4 * i4 * d;
                ax += nf0[ib]         * w.x;
                ay += nf0[ib + d]     * w.y;
                az += nf0[ib + 2 * d] * w.z;
                aw += nf0[ib + 3 * d] * w.w;
            }
            a[mi] = (ax + ay) + (az + aw);
        }
        float b[9];
        #pragma unroll
        for (int mi = 0; mi < 9; ++mi) b[mi] = __shfl_xor(a[mi], 1, 64);
        if ((o & 1) == 0) {
            uint32_t* dst = (src ? AsndG : ArecG) + (size_t)n * 288 + (o >> 1);
            #pragma unroll
            for (int mi = 0; mi < 9; ++mi)
                dst[mi * 32] = ((uint32_t)f2bf(b[mi]) << 16) | (uint32_t)f2bf(a[mi]);
        }
    }
}

// ------------------------------------------------- edge MLP + logits (full grid)
// Phase 0 (MFMA): stage q/k tiles bf16 -> logits = q.k -> write L
// Phase 1 (VALU, per-thread = per-edge): h = tanh(b1 + sh.(Arec+Asnd) + ea@W1a)
// Phase 2 (MFMA, per-mm fused): h2 = tanh(b2 + h@W2) ; ew = b3 + h2@W3 ; L += ew
__global__ __launch_bounds__(256, 4) void kB(
    const void* __restrict__ eaG, const void* __restrict__ shG,
    const uint32_t* __restrict__ ArecG, const uint32_t* __restrict__ AsndG,
    const float* __restrict__ qS, const float* __restrict__ kS,
    const float* __restrict__ Wf, float* __restrict__ L,
    const int* __restrict__ flagp)
{
    // phase0: q tile [h(8)][r(16)][64] bf16 @u32[0,4096), k tile @[4096,8192)
    // phase1: ArecS[16*292] @0, AsndS[16*292] @4672  (37376 B total)
    // phase2: hS  256 rows x 32 u32 (bf16 pairs), 16B-chunk XOR swizzle (32768 B)
    __shared__ __align__(16) uint32_t smem[9344];
    uint32_t* ArecS = smem;
    uint32_t* AsndS = smem + 4672;
    const int f32 = flagp[0];
    const int t = threadIdx.x;
    const int s0 = blockIdx.x * 16, r0 = blockIdx.y * 16;
    const int lane = t & 63, wv = t >> 6;
    const int g = lane >> 4, nl = lane & 15;

    const int rl = t >> 4, sl = t & 15;
    const int r = r0 + rl, s = s0 + sl;
    const size_t eidx = (((size_t)r) << 9) + s;

    // ---- per-edge ea / sh loads early (registers; independent of LDS) ----
    uint32_t eaR[16];
    if (f32) {
        const float4* ep = reinterpret_cast<const float4*>((const float*)eaG + eidx * 32);
        #pragma unroll
        for (int i = 0; i < 8; ++i) {
            float4 v = ep[i];
            eaR[2 * i]     = ((uint32_t)f2bf(v.y) << 16) | (uint32_t)f2bf(v.x);
            eaR[2 * i + 1] = ((uint32_t)f2bf(v.w) << 16) | (uint32_t)f2bf(v.z);
        }
    } else {
        const uint4* ep = reinterpret_cast<const uint4*>((const uint32_t*)eaG + eidx * 16);
        #pragma unroll
        for (int i = 0; i < 4; ++i) {
            uint4 v = ep[i];
            eaR[4 * i] = v.x; eaR[4 * i + 1] = v.y; eaR[4 * i + 2] = v.z; eaR[4 * i + 3] = v.w;
        }
    }

    float sh0, sh1, sh2, sh3, sh4, sh5, sh6, sh7, sh8;
    {
        const size_t sb = eidx * 9;
        if (f32) {
            const float* shp = (const float*)shG + sb;
            sh0 = shp[0]; sh1 = shp[1]; sh2 = shp[2]; sh3 = shp[3]; sh4 = shp[4];
            sh5 = shp[5]; sh6 = shp[6]; sh7 = shp[7]; sh8 = shp[8];
        } else {
            const uint16_t* shp = (const uint16_t*)shG + sb;
            sh0 = bf2f(shp[0]); sh1 = bf2f(shp[1]); sh2 = bf2f(shp[2]);
            sh3 = bf2f(shp[3]); sh4 = bf2f(shp[4]); sh5 = bf2f(shp[5]);
            sh6 = bf2f(shp[6]); sh7 = bf2f(shp[7]); sh8 = bf2f(shp[8]);
        }
    }

    // ---- phase 0a: stage q/k tiles -> LDS bf16, XOR-swizzled 16B chunks ----
    // 2048 chunk-tasks: {q,k} x 8 heads x 16 rows x 8 chunks (chunk = 8 bf16)
    for (int task = t; task < 2048; task += 256) {
        const int c    = task & 7;
        const int row  = (task >> 3) & 15;
        const int hh2  = (task >> 7) & 7;
        const int isk  = task >> 10;
        const float* src = (isk ? kS + (size_t)(s0 + row) * 480
                                : qS + (size_t)(r0 + row) * 480) + hh2 * 60 + c * 8;
        const float4 x = *reinterpret_cast<const float4*>(src);
        float4 y = make_float4(0.f, 0.f, 0.f, 0.f);
        if (c < 7) y = *reinterpret_cast<const float4*>(src + 4);
        uint4 p;
        p.x = packbf(x.x, x.y); p.y = packbf(x.z, x.w);
        p.z = packbf(y.x, y.y); p.w = packbf(y.z, y.w);
        *(uint4*)&smem[isk * 4096 + hh2 * 512 + row * 32 + ((c ^ (row & 7)) << 2)] = p;
    }
    __syncthreads();

    // ---- phase 0b: logits = q.k via MFMA, write L (raw; kSM normalizes) ----
    {
        const int sw0 = ((g    ) ^ (nl & 7)) << 2;
        const int sw1 = ((4 + g) ^ (nl & 7)) << 2;
        #pragma unroll
        for (int hh2 = 0; hh2 < 2; ++hh2) {
            const int h = wv * 2 + hh2;
            const uint32_t* qb = smem + h * 512;
            const uint32_t* kb = smem + 4096 + h * 512;
            const s16x8 qa0 = *(const s16x8*)&qb[nl * 32 + sw0];
            const s16x8 qa1 = *(const s16x8*)&qb[nl * 32 + sw1];
            const s16x8 ka0 = *(const s16x8*)&kb[nl * 32 + sw0];
            const s16x8 ka1 = *(const s16x8*)&kb[nl * 32 + sw1];
            f32x4 a = {0.f, 0.f, 0.f, 0.f};
            a = __builtin_amdgcn_mfma_f32_16x16x32_bf16(qa0, ka0, a, 0, 0, 0);
            a = __builtin_amdgcn_mfma_f32_16x16x32_bf16(qa1, ka1, a, 0, 0, 0);
            float* Lp = L + (((size_t)h) << 18) + (((size_t)(r0 + g * 4)) << 9) + s0 + nl;
            #pragma unroll
            for (int rg = 0; rg < 4; ++rg) Lp[(size_t)rg << 9] = a[rg];
        }
    }
    __syncthreads();   // q/k reads done before restage; L stores drained
    __builtin_amdgcn_sched_barrier(0);

    // ---- stage Arec/Asnd (overwrites q/k region) ----
    for (int i = t; i < 16 * 288; i += 256) {
        int row = i / 288, c = i - row * 288;
        ArecS[row * 292 + c] = ArecG[(size_t)(r0 + row) * 288 + c];
        AsndS[row * 292 + c] = AsndG[(size_t)(s0 + row) * 288 + c];
    }

    float h[64];
    #pragma unroll
    for (int o = 0; o < 64; ++o) h[o] = Wf[6656 + o];   // b1

    __syncthreads();

    {
        const int rb = rl * 292, sb = sl * 292;
        #pragma unroll 1
        for (int mi = 0; mi < 9; ++mi) {
            float shv = sh0;
            shv = (mi == 1) ? sh1 : shv;  shv = (mi == 2) ? sh2 : shv;
            shv = (mi == 3) ? sh3 : shv;  shv = (mi == 4) ? sh4 : shv;
            shv = (mi == 5) ? sh5 : shv;  shv = (mi == 6) ? sh6 : shv;
            shv = (mi == 7) ? sh7 : shv;  shv = (mi == 8) ? sh8 : shv;
            const int ro = rb + mi * 32, so = sb + mi * 32;
            #pragma unroll
            for (int oc = 0; oc < 32; ++oc) {
                uint32_t pa = ArecS[ro + oc];
                uint32_t pb = AsndS[so + oc];
                float a0 = __uint_as_float(pa << 16);
                float b0 = __uint_as_float(pb << 16);
                float a1 = __uint_as_float(pa & 0xffff0000u);
                float b1 = __uint_as_float(pb & 0xffff0000u);
                h[2 * oc]     += shv * (a0 + b0);
                h[2 * oc + 1] += shv * (a1 + b1);
            }
        }
    }

    {
        #pragma unroll 1
        for (int cd = 0; cd < 16; ++cd) {
            uint32_t p = eaR[cd];
            float e0 = __uint_as_float(p << 16);
            float e1 = __uint_as_float(p & 0xffff0000u);
            const float* w0 = Wf + (2 * cd) * 64;
            #pragma unroll
            for (int o = 0; o < 64; ++o) h[o] += e0 * w0[o];
            #pragma unroll
            for (int o = 0; o < 64; ++o) h[o] += e1 * w0[64 + o];
        }
    }

    #pragma unroll
    for (int o = 0; o < 64; ++o) h[o] = ftanh(h[o]);

    // ---- pack h -> bf16, write swizzled LDS tile (row e = t, stride 32 u32;
    //      16B chunk c stored at c ^ (row&7)) ----
    __syncthreads();   // all ArecS/AsndS reads complete before overwrite
    #pragma unroll
    for (int c = 0; c < 8; ++c) {
        const int cc = c ^ (t & 7);
        *(uint4*)&smem[t * 32 + cc * 4] =
            make_uint4(packbf(h[c * 8 + 0], h[c * 8 + 1]),
                       packbf(h[c * 8 + 2], h[c * 8 + 3]),
                       packbf(h[c * 8 + 4], h[c * 8 + 5]),
                       packbf(h[c * 8 + 6], h[c * 8 + 7]));
    }
    // Pin: nothing below (W-fragment loads) may be hoisted above this point —
    // keeping phase-1 peak pressure low is the point (R14).
    __builtin_amdgcn_sched_barrier(0);

    // ---- W2T/W3T B-fragments + biases into registers (AFTER phase 1) ----
    // B-frag 16x16x32: lane holds col n = (l&15)+16*nt, k = ks*32 + (l>>4)*8 + j
    s16x8 w2f[4][2];
    #pragma unroll
    for (int nt = 0; nt < 4; ++nt) {
        #pragma unroll
        for (int ks = 0; ks < 2; ++ks) {
            const float* p = Wf + 2048 + (nt * 16 + nl) * 64 + ks * 32 + g * 8;
            s16x8 b;
            #pragma unroll
            for (int j = 0; j < 8; ++j) b[j] = (short)f2bf(p[j]);
            w2f[nt][ks] = b;
        }
    }
    s16x8 w3f[2];
    #pragma unroll
    for (int ks = 0; ks < 2; ++ks) {
        s16x8 b;
        #pragma unroll
        for (int j = 0; j < 8; ++j)
            b[j] = (short)((nl < 8) ? f2bf(Wf[6144 + (ks * 32 + g * 8 + j) * 8 + nl]) : 0);
        w3f[ks] = b;
    }
    float b2v[4];
    #pragma unroll
    for (int nt = 0; nt < 4; ++nt) b2v[nt] = Wf[6720 + nt * 16 + nl];
    const float b3v = (nl < 8) ? Wf[6784 + nl] : 0.f;

    // From here on every LDS row this wave touches is in [wv*64, wv*64+64):
    // written by this wave's own threads -> no barriers needed (per-wave LDS
    // ordering + compiler lgkmcnt).

    // ---- fused per-mm: layer2 -> tanh -> h2 pack -> layer3 -> L update ----
    uint16_t* sm16 = (uint16_t*)smem;
    #pragma unroll 1
    for (int mm = 0; mm < 4; ++mm) {
        const int mt = wv * 4 + mm;
        const int row = mt * 16 + nl;
        const int sw0 = ((g    ) ^ (row & 7)) * 4;
        const int sw1 = ((4 + g) ^ (row & 7)) * 4;
        // layer 2: A-frag row = mt*16 + (l&15), k = ks*32 + (l>>4)*8 + j
        const s16x8 a0 = *(const s16x8*)&smem[row * 32 + sw0];
        const s16x8 a1 = *(const s16x8*)&smem[row * 32 + sw1];
        f32x4 acc[4];
        #pragma unroll
        for (int nt = 0; nt < 4; ++nt) {
            f32x4 a = {b2v[nt], b2v[nt], b2v[nt], b2v[nt]};
            a = __builtin_amdgcn_mfma_f32_16x16x32_bf16(a0, w2f[nt][0], a, 0, 0, 0);
            a = __builtin_amdgcn_mfma_f32_16x16x32_bf16(a1, w2f[nt][1], a, 0, 0, 0);
            acc[nt] = a;
        }
        // tanh + h2 write (bf16, same swizzle; C layout: col=l&15, row=g*4+reg)
        const int e2base = mt * 16 + g * 4;
        #pragma unroll
        for (int nt = 0; nt < 4; ++nt) {
            const int n = nt * 16 + nl;
            #pragma unroll
            for (int rg = 0; rg < 4; ++rg) {
                const int e2 = e2base + rg;
                const int cc = (n >> 3) ^ (e2 & 7);
                sm16[e2 * 64 + cc * 8 + (n & 7)] = f2bf(ftanh(acc[nt][rg]));
            }
        }
        // layer 3: re-read same rows (now h2) — in-wave LDS ordering guarantees
        // the writes above are observed.
        const s16x8 c0 = *(const s16x8*)&smem[row * 32 + sw0];
        const s16x8 c1 = *(const s16x8*)&smem[row * 32 + sw1];
        f32x4 a3 = {b3v, b3v, b3v, b3v};
        a3 = __builtin_amdgcn_mfma_f32_16x16x32_bf16(c0, w3f[0], a3, 0, 0, 0);
        a3 = __builtin_amdgcn_mfma_f32_16x16x32_bf16(c1, w3f[1], a3, 0, 0, 0);
        if (nl < 8) {
            float* Lp = L + (((size_t)nl) << 18) + (((size_t)(r0 + mt)) << 9) + s0 + g * 4;
            #pragma unroll
            for (int rg = 0; rg < 4; ++rg) Lp[rg] += a3[rg];
        }
    }
}

// ------------------------------------------------- softmax over senders (SoA)
__global__ __launch_bounds__(256) void kSM(float* __restrict__ L)
{
    const int r = blockIdx.x;
    const int w = threadIdx.x >> 6, lane = threadIdx.x & 63;
    const float C = 1.4426950408889634f;
    #pragma unroll
    for (int hi = 0; hi < 2; ++hi) {
        const int h = w * 2 + hi;
        float4* row4 = reinterpret_cast<float4*>(L + (((size_t)h) << 18) + (((size_t)r) << 9));
        float4 a = row4[lane * 2], b = row4[lane * 2 + 1];
        float m = fmaxf(fmaxf(fmaxf(a.x, a.y), fmaxf(a.z, a.w)),
                        fmaxf(fmaxf(b.x, b.y), fmaxf(b.z, b.w)));
        #pragma unroll
        for (int off = 32; off >= 1; off >>= 1) m = fmaxf(m, __shfl_xor(m, off, 64));
        a.x = __builtin_amdgcn_exp2f((a.x - m) * C);
        a.y = __builtin_amdgcn_exp2f((a.y - m) * C);
        a.z = __builtin_amdgcn_exp2f((a.z - m) * C);
        a.w = __builtin_amdgcn_exp2f((a.w - m) * C);
        b.x = __builtin_amdgcn_exp2f((b.x - m) * C);
        b.y = __builtin_amdgcn_exp2f((b.y - m) * C);
        b.z = __builtin_amdgcn_exp2f((b.z - m) * C);
        b.w = __builtin_amdgcn_exp2f((b.w - m) * C);
        float sm = (a.x + a.y) + (a.z + a.w) + (b.x + b.y) + (b.z + b.w);
        #pragma unroll
        for (int off = 32; off >= 1; off >>= 1) sm += __shfl_xor(sm, off, 64);
        float inv = __builtin_amdgcn_rcpf(sm);
        a.x *= inv; a.y *= inv; a.z *= inv; a.w *= inv;
        b.x *= inv; b.y *= inv; b.z *= inv; b.w *= inv;
        row4[lane * 2] = a; row4[lane * 2 + 1] = b;
    }
}

// ------------------------------------------------- aggregation + residual + store
// 512 threads: task = (j-pair, rr); 8 waves/block; LDS reads broadcast.
__global__ __launch_bounds__(512) void kAgg(
    const float* __restrict__ L, const float* __restrict__ vB,
    const void* __restrict__ nfu, void* __restrict__ out,
    const int* __restrict__ flagp)
{
    __shared__ float Ls[8192];             // [rr(2)][s(512)][h(8)]
    const int f32 = flagp[0];
    const int t = threadIdx.x;
    const int r0 = blockIdx.x * 2;

    for (int i = t; i < 8192; i += 512) {
        int rr = i >> 12, rem = i & 4095;
        int h = rem >> 9, s = rem & 511;
        Ls[rr * 4096 + s * 8 + h] =
            L[(((size_t)h) << 18) + (((size_t)(r0 + rr)) << 9) + s];
    }
    __syncthreads();

    if (t >= 480) return;
    const int jp = t >> 1, rr = t & 1;
    const int j0 = 2 * jp;
    int hh;
    if (j0 < 128)      hh = j0 >> 4;
    else if (j0 < 320) hh = (j0 - 128) / 24;
    else               hh = (j0 - 320) / 20;

    const float* Lrow = Ls + rr * 4096 + hh;
    float a0 = 0.f, a1 = 0.f;
    const float2* vp = reinterpret_cast<const float2*>(vB + j0);
    #pragma unroll 8
    for (int s = 0; s < 512; ++s) {
        float2 v = vp[(size_t)s * 240];
        float w = Lrow[s * 8];
        a0 += w * v.x; a1 += w * v.y;
    }

    const size_t o0 = (size_t)(r0 + rr) * 480 + j0;
    float r00 = ldin(nfu, o0, f32) + a0;
    float r01 = ldin(nfu, o0 + 1, f32) + a1;
    if (f32) {
        float* op = (float*)out;
        op[o0] = r00; op[o0 + 1] = r01;
    } else {
        uint16_t* op = (uint16_t*)out;
        op[o0] = f2bf(r00); op[o0 + 1] = f2bf(r01);
    }
}

extern "C" void kernel_launch(void* const* d_in, const int* in_sizes, int n_in,
                              void* d_out, int out_size, void* d_ws, size_t ws_size,
                              hipStream_t stream)
{
    (void)in_sizes; (void)n_in; (void)out_size; (void)ws_size;
    const void* nf  = d_in[0];
    const void* eaG = d_in[1];
    const void* shG = d_in[2];

    float* ws = (float*)d_ws;
    float* qS  = ws + QS_OFF;
    float* kS  = ws + KT_OFF;
    float* vB  = ws + VB_OFF;
    uint32_t* ArecG = (uint32_t*)(ws + ARE_OFF);
    uint32_t* AsndG = (uint32_t*)(ws + ASN_OFF);
    float* Wf  = ws + WF_OFF;
    int* flag  = (int*)(ws + FLAG_OFF);
    float* L   = ws + L_OFF;
    float* WtQ = ws + WTQ_OFF;
    float* WtK = ws + WTK_OFF;
    float* WtV = ws + WTV_OFF;
    float* W1T = ws + W1T_OFF;

    kDet<<<1, 64, 0, stream>>>((const uint32_t*)nf, flag);
    kW<<<64, 256, 0, stream>>>(d_in[12], d_in[13], d_in[14], d_in[15], d_in[16], d_in[17],
                               d_in[3], d_in[4], d_in[5], d_in[6], d_in[7], d_in[8],
                               d_in[9], d_in[10], d_in[11], ws, flag);
    kA<<<512, 256, 0, stream>>>(nf, WtQ, WtK, WtV, W1T, qS, kS, vB, ArecG, AsndG, flag);
    kB<<<dim3(32, 32), 256, 0, stream>>>(eaG, shG, ArecG, AsndG, qS, kS, Wf, L, flag);
    kSM<<<512, 256, 0, stream>>>(L);
    kAgg<<<256, 512, 0, stream>>>(L, vB, nf, d_out, flag);
}

// Round 5
// 230.907 us; speedup vs baseline: 1.3000x; 1.0947x over previous
//
#include <hip/hip_runtime.h>
#include <hip/hip_bf16.h>
#include <stdint.h>

// ---------------------------------------------------------------------------
// EquivariantAttention on MI355X.  Dtype-adaptive (bf16 or fp32 inputs).
// R11: consolidated pipeline; kB = 99us, VALU-bound.
// R12/R13: kB layers 2+3 -> MFMA.  VGPR 144, occ 10.8%, kB 119us (regressed).
// R14: W-frags post-phase-1 + per-mm fusion.  VGPR 84, occ 22%, kB 74, tot 259.
// R15: kQK fused into kB (logits via MFMA), kQK deleted.  VGPR 64, occ 37%,
//   kB 82, tot 253.  BUT kB WRITE 32MB (logit store + L-RMW, ~2x partial-line
//   amplification) and FETCH 45MB (8MB RMW read) — L round-trips inside kB.
// R16: (a) single-L-write kB: reorder phases {Arec/Asnd+phase1, phase2 -> ew
//   into 8KB LDS scratch, q/k stage, logits MFMA + ew -> ONE L store}.
//   LDS 37376->40960B = exactly 160KB/4 -> 4 blocks/CU retained.
//   (b) softmax fused into kAgg prologue (16 grps x 32 lanes, width-32
//   shuffles); kSM dispatch deleted (-16MB L traffic).
// ---------------------------------------------------------------------------

#define NNODES 512
#define NDIM   480

// ws layout (4-byte word offsets)
#define QS_OFF    0u         // 512*480 f32 q, per-head layout, folds applied
#define KT_OFF    245760u    // 512*480 f32 k, per-head layout (row-major)
#define VB_OFF    491520u    // 512*480 f32 v, output-irrep (final) layout
#define ARE_OFF   737280u    // 512*288 u32 (bf16 pairs over o): [n][mi(9)][oc(32)]
#define ASN_OFF   884736u    // 512*288 u32
#define WF_OFF    1032192u   // 8192 f32: W1a[32][64]@0, W2T[64][64]@2048, W3[64][8]@6144, b1@6656, b2@6720, b3@6784
#define FLAG_OFF  1040384u   // flag[0] = 1 if inputs fp32, 0 if bf16
#define L_OFF     1040448u   // L SoA: [h(8)][r(512)][s(512)] f32 (8MB)
#define WTQ_OFF   3137600u   // q weights transposed [o][i] f32 + folds
#define WTK_OFF   3159104u
#define WTV_OFF   3180608u
#define W1T_OFF   3202112u   // mW1 transposed [o(64)][row(480)] f32, cg folded

typedef float f32x4 __attribute__((ext_vector_type(4)));
typedef short s16x8 __attribute__((ext_vector_type(8)));

__device__ __forceinline__ float bf2f(uint16_t u) {
    return __uint_as_float(((uint32_t)u) << 16);
}
__device__ __forceinline__ uint16_t f2bf(float f) {
    union { __hip_bfloat16 h; uint16_t u; } cv;
    cv.h = __float2bfloat16(f);
    return cv.u;
}
__device__ __forceinline__ uint32_t packbf(float lo, float hi) {
    return ((uint32_t)f2bf(hi) << 16) | (uint32_t)f2bf(lo);
}
__device__ __forceinline__ float ldin(const void* p, size_t i, int f32) {
    return f32 ? ((const float*)p)[i] : bf2f(((const uint16_t*)p)[i]);
}
// tanh(x) = 1 - 2/(exp(2x)+1)
__device__ __forceinline__ float ftanh(float x) {
    float e = __builtin_amdgcn_exp2f(x * 2.885390081777927f);
    return 1.0f - 2.0f * __builtin_amdgcn_rcpf(e + 1.0f);
}

// ------------------------------------------------- dtype detector
__global__ __launch_bounds__(64) void kDet(const uint32_t* __restrict__ nf,
                                           int* __restrict__ flag)
{
    int t = threadIdx.x;
    uint32_t x = nf[64 + t];
    int e = (x >> 7) & 0xff;
    int good = (x != 0u) && (e >= 100) && (e <= 140);
    unsigned long long m = __ballot(good);
    if (t == 0) flag[0] = (__popcll(m) < 32) ? 1 : 0;
}

// ---------------------------------------------------------------- weights prep
#define NS 16384
__global__ __launch_bounds__(256) void kW(
    const void* __restrict__ mW1, const void* __restrict__ mb1,
    const void* __restrict__ mW2, const void* __restrict__ mb2,
    const void* __restrict__ mW3, const void* __restrict__ mb3,
    const void* __restrict__ Wq0, const void* __restrict__ Wq1, const void* __restrict__ Wq2,
    const void* __restrict__ Wk0, const void* __restrict__ Wk1, const void* __restrict__ Wk2,
    const void* __restrict__ Wv0, const void* __restrict__ Wv1, const void* __restrict__ Wv2,
    float* __restrict__ ws, const int* __restrict__ flagp)
{
    const int f32 = flagp[0];
    const int gt = blockIdx.x * 256 + threadIdx.x;
    float* Wf = ws + WF_OFF;

    for (int i = gt; i < 2048; i += NS) Wf[i] = ldin(mW1, i, f32);
    for (int i = gt; i < 4096; i += NS) {
        int o2 = i >> 6, ii = i & 63;
        Wf[2048 + i] = ldin(mW2, ii * 64 + o2, f32);
    }
    for (int i = gt; i < 512; i += NS) Wf[6144 + i] = ldin(mW3, i, f32);
    for (int i = gt; i < 64; i += NS) Wf[6656 + i] = ldin(mb1, i, f32);
    for (int i = gt; i < 64; i += NS) Wf[6720 + i] = ldin(mb2, i, f32);
    for (int i = gt; i < 8; i += NS)  Wf[6784 + i] = ldin(mb3, i, f32);

    const float e3n0 = 0.08838834764831845f, e3n1 = 0.125f, e3n2 = 0.17677669529663687f;
    const float cg1 = 0.5773502691896258f, cg2 = 0.4472135954999579f;
    const float attn = 0.1889822365046136f;

    const void* Wsrc[9] = {Wq0, Wq1, Wq2, Wk0, Wk1, Wk2, Wv0, Wv1, Wv2};
    float* Wdst[3] = {ws + WTQ_OFF, ws + WTK_OFF, ws + WTV_OFF};
    for (int kind = 0; kind < 3; ++kind) {
        const float f0 = (kind == 0) ? e3n0 * attn : e3n0;
        const float f1 = (kind == 0) ? e3n1 * cg1 * attn : e3n1;
        const float f2 = (kind == 0) ? e3n2 * cg2 * attn : e3n2;
        for (int i = gt; i < 16384; i += NS) {
            int o = i >> 7, ii = i & 127;
            Wdst[kind][i] = ldin(Wsrc[kind * 3], (size_t)ii * 128 + o, f32) * f0;
        }
        for (int i = gt; i < 4096; i += NS) {
            int o = i >> 6, ii = i & 63;
            Wdst[kind][16384 + i] = ldin(Wsrc[kind * 3 + 1], (size_t)ii * 64 + o, f32) * f1;
        }
        for (int i = gt; i < 1024; i += NS) {
            int o = i >> 5, ii = i & 31;
            Wdst[kind][20480 + i] = ldin(Wsrc[kind * 3 + 2], (size_t)ii * 32 + o, f32) * f2;
        }
    }
    float* W1T = ws + W1T_OFF;
    for (int i = gt; i < 30720; i += NS) {
        int o = i / 480, row = i - o * 480;
        float cgv;
        if (row < 160)      cgv = 1.0f;
        else if (row < 224) cgv = cg1;
        else if (row < 256) cgv = cg2;
        else if (row < 384) cgv = 1.0f;
        else if (row < 448) cgv = cg1;
        else                cgv = cg2;
        W1T[i] = ldin(mW1, (size_t)row * 64 + o, f32) * cgv;
    }
}

// ------------------------------------------------- per-node precompute
__global__ __launch_bounds__(256) void kA(
    const void* __restrict__ nfu,
    const float* __restrict__ WtQ, const float* __restrict__ WtK,
    const float* __restrict__ WtV, const float* __restrict__ W1T,
    float* __restrict__ qS, float* __restrict__ kS, float* __restrict__ vB,
    uint32_t* __restrict__ ArecG, uint32_t* __restrict__ AsndG,
    const int* __restrict__ flagp)
{
    const int f32 = flagp[0];
    const int n = blockIdx.x, t = threadIdx.x;
    __shared__ float nfs[480];
    for (int i = t; i < 480; i += 256) nfs[i] = ldin(nfu, (size_t)n * 480 + i, f32);
    __syncthreads();

    for (int idx = t; idx < 1440; idx += 256) {
        int kind = idx / 480, rem = idx - kind * 480;
        int o, m, mul, d, off, am, qoff, sub;
        if (rem < 128)      { o = rem;           m = 0;          mul = 128; d = 1; off = 0;   am = 16; qoff = 0;  sub = 0; }
        else if (rem < 320) { int x = rem - 128; o = x / 3; m = x - o * 3; mul = 64;  d = 3; off = 128; am = 8;  qoff = 16; sub = 16384; }
        else                { int x = rem - 320; o = x / 5; m = x - o * 5; mul = 32;  d = 5; off = 320; am = 4;  qoff = 40; sub = 20480; }
        const float* base = (kind == 0) ? WtQ : (kind == 1) ? WtK : WtV;
        const float4* W4 = reinterpret_cast<const float4*>(base + sub + o * mul);
        const float* nf0 = nfs + off + m;
        float ax = 0.f, ay = 0.f, az = 0.f, aw = 0.f;
        const int n4 = mul >> 2;
        for (int i4 = 0; i4 < n4; ++i4) {
            float4 w = W4[i4];
            int ib = 4 * i4 * d;
            ax += nf0[ib]         * w.x;
            ay += nf0[ib + d]     * w.y;
            az += nf0[ib + 2 * d] * w.z;
            aw += nf0[ib + 3 * d] * w.w;
        }
        float acc = (ax + ay) + (az + aw);
        if (kind == 2) {
            vB[(size_t)n * 480 + rem] = acc;
        } else {
            int hh = o / am, a = o - hh * am;
            int j = qoff + a * d + m;
            if (kind == 0) qS[(size_t)n * 480 + hh * 60 + j] = acc;
            else           kS[(size_t)n * 480 + hh * 60 + j] = acc;
        }
    }

    if (t < 128) {
        const int src = t >> 6, o = t & 63;
        float a[9];
        #pragma unroll
        for (int mi = 0; mi < 9; ++mi) {
            const int l = (mi == 0) ? 0 : (mi < 4 ? 1 : 2);
            const int m = (mi == 0) ? 0 : (mi < 4 ? mi - 1 : mi - 4);
            const int mul = (l == 0 ? 128 : l == 1 ? 64 : 32);
            const int d = 2 * l + 1;
            const int off = (l == 0 ? 0 : l == 1 ? 128 : 320);
            const int base = (src == 0) ? (l == 0 ? 32 : l == 1 ? 160 : 224)
                                        : (l == 0 ? 256 : l == 1 ? 384 : 448);
            const float4* W4 = reinterpret_cast<const float4*>(W1T + o * 480 + base);
            const float* nf0 = nfs + off + m;
            float ax = 0.f, ay = 0.f, az = 0.f, aw = 0.f;
            const int n4 = mul >> 2;
            for (int i4 = 0; i4 < n4; ++i4) {
                float4 w = W4[i4];
                int ib = 4 * i4 * d;
                ax += nf0[ib]         * w.x;
                ay += nf0[ib + d]     * w.y;
                az += nf0[ib + 2 * d] * w.z;
                aw += nf0[ib + 3 * d] * w.w;
            }
            a[mi] = (ax + ay) + (az + aw);
        }
        float b[9];
        #pragma unroll
        for (int mi = 0; mi < 9; ++mi) b[mi] = __shfl_xor(a[mi], 1, 64);
        if ((o & 1) == 0) {
            uint32_t* dst = (src ? AsndG : ArecG) + (size_t)n * 288 + (o >> 1);
            #pragma unroll
            for (int mi = 0; mi < 9; ++mi)
                dst[mi * 32] = ((uint32_t)f2bf(b[mi]) << 16) | (uint32_t)f2bf(a[mi]);
        }
    }
}

// ------------------------------------------------- edge MLP + logits (full grid)
// Phase 1 (VALU, per-thread = per-edge): h = tanh(b1 + sh.(Arec+Asnd) + ea@W1a)
// Phase 2 (MFMA, per-mm fused): h2 = tanh(b2 + h@W2) ; ew = b3 + h2@W3 -> ewS (LDS)
// Phase 0 (MFMA, LAST): stage q/k bf16 -> logits = q.k ; L = logits + ew (ONE write)
__global__ __launch_bounds__(256, 4) void kB(
    const void* __restrict__ eaG, const void* __restrict__ shG,
    const uint32_t* __restrict__ ArecG, const uint32_t* __restrict__ AsndG,
    const float* __restrict__ qS, const float* __restrict__ kS,
    const float* __restrict__ Wf, float* __restrict__ L,
    const int* __restrict__ flagp)
{
    // words [0,4672)   ArecS        (phase 1)
    // words [4672,9344) AsndS       (phase 1)
    // words [0,8192)   h-tile / q,k tiles (phases 2 / 0)
    // words [8192,10240) ewS: [h(8)][e2(256)^ (h<<2)] f32  (written ph2, read ph0)
    __shared__ __align__(16) uint32_t smem[10240];   // 40960 B = 160KB / 4
    uint32_t* ArecS = smem;
    uint32_t* AsndS = smem + 4672;
    float* ewS = (float*)(smem + 8192);
    const int f32 = flagp[0];
    const int t = threadIdx.x;
    const int s0 = blockIdx.x * 16, r0 = blockIdx.y * 16;
    const int lane = t & 63, wv = t >> 6;
    const int g = lane >> 4, nl = lane & 15;

    const int rl = t >> 4, sl = t & 15;
    const int r = r0 + rl, s = s0 + sl;
    const size_t eidx = (((size_t)r) << 9) + s;

    // ---- per-edge ea / sh loads early (registers; independent of LDS) ----
    uint32_t eaR[16];
    if (f32) {
        const float4* ep = reinterpret_cast<const float4*>((const float*)eaG + eidx * 32);
        #pragma unroll
        for (int i = 0; i < 8; ++i) {
            float4 v = ep[i];
            eaR[2 * i]     = ((uint32_t)f2bf(v.y) << 16) | (uint32_t)f2bf(v.x);
            eaR[2 * i + 1] = ((uint32_t)f2bf(v.w) << 16) | (uint32_t)f2bf(v.z);
        }
    } else {
        const uint4* ep = reinterpret_cast<const uint4*>((const uint32_t*)eaG + eidx * 16);
        #pragma unroll
        for (int i = 0; i < 4; ++i) {
            uint4 v = ep[i];
            eaR[4 * i] = v.x; eaR[4 * i + 1] = v.y; eaR[4 * i + 2] = v.z; eaR[4 * i + 3] = v.w;
        }
    }

    float sh0, sh1, sh2, sh3, sh4, sh5, sh6, sh7, sh8;
    {
        const size_t sb = eidx * 9;
        if (f32) {
            const float* shp = (const float*)shG + sb;
            sh0 = shp[0]; sh1 = shp[1]; sh2 = shp[2]; sh3 = shp[3]; sh4 = shp[4];
            sh5 = shp[5]; sh6 = shp[6]; sh7 = shp[7]; sh8 = shp[8];
        } else {
            const uint16_t* shp = (const uint16_t*)shG + sb;
            sh0 = bf2f(shp[0]); sh1 = bf2f(shp[1]); sh2 = bf2f(shp[2]);
            sh3 = bf2f(shp[3]); sh4 = bf2f(shp[4]); sh5 = bf2f(shp[5]);
            sh6 = bf2f(shp[6]); sh7 = bf2f(shp[7]); sh8 = bf2f(shp[8]);
        }
    }

    // ---- stage Arec/Asnd ----
    for (int i = t; i < 16 * 288; i += 256) {
        int row = i / 288, c = i - row * 288;
        ArecS[row * 292 + c] = ArecG[(size_t)(r0 + row) * 288 + c];
        AsndS[row * 292 + c] = AsndG[(size_t)(s0 + row) * 288 + c];
    }

    float h[64];
    #pragma unroll
    for (int o = 0; o < 64; ++o) h[o] = Wf[6656 + o];   // b1

    __syncthreads();

    // ---- phase 1: sh.(Arec+Asnd) ----
    {
        const int rb = rl * 292, sb = sl * 292;
        #pragma unroll 1
        for (int mi = 0; mi < 9; ++mi) {
            float shv = sh0;
            shv = (mi == 1) ? sh1 : shv;  shv = (mi == 2) ? sh2 : shv;
            shv = (mi == 3) ? sh3 : shv;  shv = (mi == 4) ? sh4 : shv;
            shv = (mi == 5) ? sh5 : shv;  shv = (mi == 6) ? sh6 : shv;
            shv = (mi == 7) ? sh7 : shv;  shv = (mi == 8) ? sh8 : shv;
            const int ro = rb + mi * 32, so = sb + mi * 32;
            #pragma unroll
            for (int oc = 0; oc < 32; ++oc) {
                uint32_t pa = ArecS[ro + oc];
                uint32_t pb = AsndS[so + oc];
                float a0 = __uint_as_float(pa << 16);
                float b0 = __uint_as_float(pb << 16);
                float a1 = __uint_as_float(pa & 0xffff0000u);
                float b1 = __uint_as_float(pb & 0xffff0000u);
                h[2 * oc]     += shv * (a0 + b0);
                h[2 * oc + 1] += shv * (a1 + b1);
            }
        }
    }

    // ---- phase 1b: ea @ W1a ----
    {
        #pragma unroll 1
        for (int cd = 0; cd < 16; ++cd) {
            uint32_t p = eaR[cd];
            float e0 = __uint_as_float(p << 16);
            float e1 = __uint_as_float(p & 0xffff0000u);
            const float* w0 = Wf + (2 * cd) * 64;
            #pragma unroll
            for (int o = 0; o < 64; ++o) h[o] += e0 * w0[o];
            #pragma unroll
            for (int o = 0; o < 64; ++o) h[o] += e1 * w0[64 + o];
        }
    }

    #pragma unroll
    for (int o = 0; o < 64; ++o) h[o] = ftanh(h[o]);

    // ---- pack h -> bf16, write swizzled LDS tile (row e = t, stride 32 u32;
    //      16B chunk c stored at c ^ (row&7)) ----
    __syncthreads();   // all ArecS/AsndS reads complete before overwrite
    #pragma unroll
    for (int c = 0; c < 8; ++c) {
        const int cc = c ^ (t & 7);
        *(uint4*)&smem[t * 32 + cc * 4] =
            make_uint4(packbf(h[c * 8 + 0], h[c * 8 + 1]),
                       packbf(h[c * 8 + 2], h[c * 8 + 3]),
                       packbf(h[c * 8 + 4], h[c * 8 + 5]),
                       packbf(h[c * 8 + 6], h[c * 8 + 7]));
    }
    // Pin: nothing below (W-fragment loads) may be hoisted above this point —
    // keeping phase-1 peak pressure low is the point (R14).
    __builtin_amdgcn_sched_barrier(0);

    // ---- W2T/W3T B-fragments + biases into registers (AFTER phase 1) ----
    // B-frag 16x16x32: lane holds col n = (l&15)+16*nt, k = ks*32 + (l>>4)*8 + j
    s16x8 w2f[4][2];
    #pragma unroll
    for (int nt = 0; nt < 4; ++nt) {
        #pragma unroll
        for (int ks = 0; ks < 2; ++ks) {
            const float* p = Wf + 2048 + (nt * 16 + nl) * 64 + ks * 32 + g * 8;
            s16x8 b;
            #pragma unroll
            for (int j = 0; j < 8; ++j) b[j] = (short)f2bf(p[j]);
            w2f[nt][ks] = b;
        }
    }
    s16x8 w3f[2];
    #pragma unroll
    for (int ks = 0; ks < 2; ++ks) {
        s16x8 b;
        #pragma unroll
        for (int j = 0; j < 8; ++j)
            b[j] = (short)((nl < 8) ? f2bf(Wf[6144 + (ks * 32 + g * 8 + j) * 8 + nl]) : 0);
        w3f[ks] = b;
    }
    float b2v[4];
    #pragma unroll
    for (int nt = 0; nt < 4; ++nt) b2v[nt] = Wf[6720 + nt * 16 + nl];
    const float b3v = (nl < 8) ? Wf[6784 + nl] : 0.f;

    // From here on every h-tile LDS row this wave touches is in
    // [wv*64, wv*64+64): written by this wave's own threads -> no barriers
    // needed inside phase 2 (per-wave LDS ordering + compiler lgkmcnt).

    // ---- phase 2 fused per-mm: layer2 -> tanh -> h2 pack -> layer3 -> ewS ----
    uint16_t* sm16 = (uint16_t*)smem;
    #pragma unroll 1
    for (int mm = 0; mm < 4; ++mm) {
        const int mt = wv * 4 + mm;
        const int row = mt * 16 + nl;
        const int sw0 = ((g    ) ^ (row & 7)) * 4;
        const int sw1 = ((4 + g) ^ (row & 7)) * 4;
        // layer 2: A-frag row = mt*16 + (l&15), k = ks*32 + (l>>4)*8 + j
        const s16x8 a0 = *(const s16x8*)&smem[row * 32 + sw0];
        const s16x8 a1 = *(const s16x8*)&smem[row * 32 + sw1];
        f32x4 acc[4];
        #pragma unroll
        for (int nt = 0; nt < 4; ++nt) {
            f32x4 a = {b2v[nt], b2v[nt], b2v[nt], b2v[nt]};
            a = __builtin_amdgcn_mfma_f32_16x16x32_bf16(a0, w2f[nt][0], a, 0, 0, 0);
            a = __builtin_amdgcn_mfma_f32_16x16x32_bf16(a1, w2f[nt][1], a, 0, 0, 0);
            acc[nt] = a;
        }
        // tanh + h2 write (bf16, same swizzle; C layout: col=l&15, row=g*4+reg)
        const int e2base = mt * 16 + g * 4;
        #pragma unroll
        for (int nt = 0; nt < 4; ++nt) {
            const int n = nt * 16 + nl;
            #pragma unroll
            for (int rg = 0; rg < 4; ++rg) {
                const int e2 = e2base + rg;
                const int cc = (n >> 3) ^ (e2 & 7);
                sm16[e2 * 64 + cc * 8 + (n & 7)] = f2bf(ftanh(acc[nt][rg]));
            }
        }
        // layer 3: re-read same rows (now h2) — in-wave LDS ordering guarantees
        // the writes above are observed.
        const s16x8 c0 = *(const s16x8*)&smem[row * 32 + sw0];
        const s16x8 c1 = *(const s16x8*)&smem[row * 32 + sw1];
        f32x4 a3 = {b3v, b3v, b3v, b3v};
        a3 = __builtin_amdgcn_mfma_f32_16x16x32_bf16(c0, w3f[0], a3, 0, 0, 0);
        a3 = __builtin_amdgcn_mfma_f32_16x16x32_bf16(c1, w3f[1], a3, 0, 0, 0);
        if (nl < 8) {
            // ew -> LDS scratch (read back in phase 0b); XOR swizzle -> 4-way
            #pragma unroll
            for (int rg = 0; rg < 4; ++rg) {
                const int e2 = mt * 16 + g * 4 + rg;
                ewS[nl * 256 + (e2 ^ (nl << 2))] = a3[rg];
            }
        }
    }

    __syncthreads();   // phase-2 h-tile reads + ewS writes complete

    // ---- phase 0a: stage q/k tiles -> LDS bf16, XOR-swizzled 16B chunks ----
    // 2048 chunk-tasks: {q,k} x 8 heads x 16 rows x 8 chunks (chunk = 8 bf16)
    for (int task = t; task < 2048; task += 256) {
        const int c    = task & 7;
        const int row  = (task >> 3) & 15;
        const int hh2  = (task >> 7) & 7;
        const int isk  = task >> 10;
        const float* src = (isk ? kS + (size_t)(s0 + row) * 480
                                : qS + (size_t)(r0 + row) * 480) + hh2 * 60 + c * 8;
        const float4 x = *reinterpret_cast<const float4*>(src);
        float4 y = make_float4(0.f, 0.f, 0.f, 0.f);
        if (c < 7) y = *reinterpret_cast<const float4*>(src + 4);
        uint4 p;
        p.x = packbf(x.x, x.y); p.y = packbf(x.z, x.w);
        p.z = packbf(y.x, y.y); p.w = packbf(y.z, y.w);
        *(uint4*)&smem[isk * 4096 + hh2 * 512 + row * 32 + ((c ^ (row & 7)) << 2)] = p;
    }
    __syncthreads();

    // ---- phase 0b: logits = q.k via MFMA; L = logits + ew (single write) ----
    {
        const int sw0 = ((g    ) ^ (nl & 7)) << 2;
        const int sw1 = ((4 + g) ^ (nl & 7)) << 2;
        #pragma unroll
        for (int hh2 = 0; hh2 < 2; ++hh2) {
            const int h = wv * 2 + hh2;
            const uint32_t* qb = smem + h * 512;
            const uint32_t* kb = smem + 4096 + h * 512;
            const s16x8 qa0 = *(const s16x8*)&qb[nl * 32 + sw0];
            const s16x8 qa1 = *(const s16x8*)&qb[nl * 32 + sw1];
            const s16x8 ka0 = *(const s16x8*)&kb[nl * 32 + sw0];
            const s16x8 ka1 = *(const s16x8*)&kb[nl * 32 + sw1];
            f32x4 a = {0.f, 0.f, 0.f, 0.f};
            a = __builtin_amdgcn_mfma_f32_16x16x32_bf16(qa0, ka0, a, 0, 0, 0);
            a = __builtin_amdgcn_mfma_f32_16x16x32_bf16(qa1, ka1, a, 0, 0, 0);
            float* Lp = L + (((size_t)h) << 18) + (((size_t)(r0 + g * 4)) << 9) + s0 + nl;
            #pragma unroll
            for (int rg = 0; rg < 4; ++rg) {
                const int e2 = (g * 4 + rg) * 16 + nl;
                Lp[(size_t)rg << 9] = a[rg] + ewS[h * 256 + (e2 ^ (h << 2))];
            }
        }
    }
}

// ------------------------------------------------- softmax + aggregation + store
// Prologue: fused softmax over senders (raw L in, normalized weights -> LDS).
// 512 threads: softmax = 16 groups (rr,h) x 32 lanes; agg task = (j-pair, rr).
__global__ __launch_bounds__(512) void kAgg(
    const float* __restrict__ L, const float* __restrict__ vB,
    const void* __restrict__ nfu, void* __restrict__ out,
    const int* __restrict__ flagp)
{
    __shared__ float Ls[8192];             // [rr(2)][s(512)][h(8)]
    const int f32 = flagp[0];
    const int t = threadIdx.x;
    const int r0 = blockIdx.x * 2;

    // ---- fused softmax: group (rr,h) owns one 512-long sender row ----
    {
        const int grp = t >> 5, l = t & 31;
        const int rr = grp >> 3, hsm = grp & 7;
        const float* Lg = L + (((size_t)hsm) << 18) + (((size_t)(r0 + rr)) << 9);
        float v[16];
        float mx = -3.402823466e38f;
        #pragma unroll
        for (int i = 0; i < 16; ++i) {
            v[i] = Lg[l + 32 * i];
            mx = fmaxf(mx, v[i]);
        }
        #pragma unroll
        for (int off = 16; off >= 1; off >>= 1) mx = fmaxf(mx, __shfl_xor(mx, off, 32));
        const float C = 1.4426950408889634f;
        float sm = 0.f;
        #pragma unroll
        for (int i = 0; i < 16; ++i) {
            v[i] = __builtin_amdgcn_exp2f((v[i] - mx) * C);
            sm += v[i];
        }
        #pragma unroll
        for (int off = 16; off >= 1; off >>= 1) sm += __shfl_xor(sm, off, 32);
        const float inv = __builtin_amdgcn_rcpf(sm);
        #pragma unroll
        for (int i = 0; i < 16; ++i)
            Ls[rr * 4096 + (l + 32 * i) * 8 + hsm] = v[i] * inv;
    }
    __syncthreads();

    if (t >= 480) return;
    const int jp = t >> 1, rr = t & 1;
    const int j0 = 2 * jp;
    int hh;
    if (j0 < 128)      hh = j0 >> 4;
    else if (j0 < 320) hh = (j0 - 128) / 24;
    else               hh = (j0 - 320) / 20;

    const float* Lrow = Ls + rr * 4096 + hh;
    float a0 = 0.f, a1 = 0.f;
    const float2* vp = reinterpret_cast<const float2*>(vB + j0);
    #pragma unroll 8
    for (int s = 0; s < 512; ++s) {
        float2 v = vp[(size_t)s * 240];
        float w = Lrow[s * 8];
        a0 += w * v.x; a1 += w * v.y;
    }

    const size_t o0 = (size_t)(r0 + rr) * 480 + j0;
    float r00 = ldin(nfu, o0, f32) + a0;
    float r01 = ldin(nfu, o0 + 1, f32) + a1;
    if (f32) {
        float* op = (float*)out;
        op[o0] = r00; op[o0 + 1] = r01;
    } else {
        uint16_t* op = (uint16_t*)out;
        op[o0] = f2bf(r00); op[o0 + 1] = f2bf(r01);
    }
}

extern "C" void kernel_launch(void* const* d_in, const int* in_sizes, int n_in,
                              void* d_out, int out_size, void* d_ws, size_t ws_size,
                              hipStream_t stream)
{
    (void)in_sizes; (void)n_in; (void)out_size; (void)ws_size;
    const void* nf  = d_in[0];
    const void* eaG = d_in[1];
    const void* shG = d_in[2];

    float* ws = (float*)d_ws;
    float* qS  = ws + QS_OFF;
    float* kS  = ws + KT_OFF;
    float* vB  = ws + VB_OFF;
    uint32_t* ArecG = (uint32_t*)(ws + ARE_OFF);
    uint32_t* AsndG = (uint32_t*)(ws + ASN_OFF);
    float* Wf  = ws + WF_OFF;
    int* flag  = (int*)(ws + FLAG_OFF);
    float* L   = ws + L_OFF;
    float* WtQ = ws + WTQ_OFF;
    float* WtK = ws + WTK_OFF;
    float* WtV = ws + WTV_OFF;
    float* W1T = ws + W1T_OFF;

    kDet<<<1, 64, 0, stream>>>((const uint32_t*)nf, flag);
    kW<<<64, 256, 0, stream>>>(d_in[12], d_in[13], d_in[14], d_in[15], d_in[16], d_in[17],
                               d_in[3], d_in[4], d_in[5], d_in[6], d_in[7], d_in[8],
                               d_in[9], d_in[10], d_in[11], ws, flag);
    kA<<<512, 256, 0, stream>>>(nf, WtQ, WtK, WtV, W1T, qS, kS, vB, ArecG, AsndG, flag);
    kB<<<dim3(32, 32), 256, 0, stream>>>(eaG, shG, ArecG, AsndG, qS, kS, Wf, L, flag);
    kAgg<<<256, 512, 0, stream>>>(L, vB, nf, d_out, flag);
}

// Round 6
// 221.982 us; speedup vs baseline: 1.3523x; 1.0402x over previous
//
#include <hip/hip_runtime.h>
#include <hip/hip_bf16.h>
#include <stdint.h>

// ---------------------------------------------------------------------------
// EquivariantAttention on MI355X.  Dtype-adaptive (bf16 or fp32 inputs).
// R14: W-frags post-phase-1 + per-mm fusion.  VGPR 84, occ 22%, kB 74, tot 259.
// R15: kQK fused into kB (logits via MFMA).  VGPR 64, occ 37%, kB 82, tot 253.
// R16: single-L-write kB (ew via LDS scratch) + softmax fused into kAgg;
//   kSM deleted.  kB 70us (VALUBusy 48% -> VALU-issue bound), tot 231.
// R17: eliminate per-block re-conversion VALU + duplicate traffic:
//   (a) kA writes q/k as bf16 PRE-SWIZZLED tiles ([rt][h][row][chunk^swz]);
//       kB phase-0a is now a pure uint4 copy (no f32 loads, no packbf).
//   (b) kW pre-builds W2/W3 MFMA B-fragments as per-lane bf16 images (stored
//       in the freed qS-region tail); kB loads 10x16B, zero conversion.
//       kW drops dead f32 W2T/W3 copies.
//   (c) kAgg: 240 threads own a j-pair for BOTH rows (4 acc) -> vB L2 traffic
//       halved.  kDet fused into kW (self-detect + block-0 publish).
// ---------------------------------------------------------------------------

#define NNODES 512
#define NDIM   480

// ws layout (4-byte word offsets)
#define QG_OFF    0u         // q bf16 tiles: [rt(32)][h(8)][row(16)][32 u32] = 131072 u32
#define W2B_OFF   131072u    // W2 B-frag bf16 per-lane image: 2048 u32
#define W3B_OFF   133120u    // W3 B-frag bf16 per-lane image: 512 u32
#define KG_OFF    245760u    // k bf16 tiles, same layout as qG
#define VB_OFF    491520u    // 512*480 f32 v, output-irrep (final) layout
#define ARE_OFF   737280u    // 512*288 u32 (bf16 pairs over o): [n][mi(9)][oc(32)]
#define ASN_OFF   884736u    // 512*288 u32
#define WF_OFF    1032192u   // W1a[32][64]@0, b1@6656, b2@6720, b3@6784
#define FLAG_OFF  1040384u   // flag[0] = 1 if inputs fp32, 0 if bf16
#define L_OFF     1040448u   // L SoA: [h(8)][r(512)][s(512)] f32 (8MB)
#define WTQ_OFF   3137600u   // q weights transposed [o][i] f32 + folds
#define WTK_OFF   3159104u
#define WTV_OFF   3180608u
#define W1T_OFF   3202112u   // mW1 transposed [o(64)][row(480)] f32, cg folded

typedef float f32x4 __attribute__((ext_vector_type(4)));
typedef short s16x8 __attribute__((ext_vector_type(8)));

__device__ __forceinline__ float bf2f(uint16_t u) {
    return __uint_as_float(((uint32_t)u) << 16);
}
__device__ __forceinline__ uint16_t f2bf(float f) {
    union { __hip_bfloat16 h; uint16_t u; } cv;
    cv.h = __float2bfloat16(f);
    return cv.u;
}
__device__ __forceinline__ uint32_t packbf(float lo, float hi) {
    return ((uint32_t)f2bf(hi) << 16) | (uint32_t)f2bf(lo);
}
__device__ __forceinline__ float ldin(const void* p, size_t i, int f32) {
    return f32 ? ((const float*)p)[i] : bf2f(((const uint16_t*)p)[i]);
}
// tanh(x) = 1 - 2/(exp(2x)+1)
__device__ __forceinline__ float ftanh(float x) {
    float e = __builtin_amdgcn_exp2f(x * 2.885390081777927f);
    return 1.0f - 2.0f * __builtin_amdgcn_rcpf(e + 1.0f);
}

// ---------------------------------------------------------------- weights prep
// (kDet fused: every block self-detects dtype from nf; block 0 publishes flag.)
#define NS 16384
__global__ __launch_bounds__(256) void kW(
    const void* __restrict__ mW1, const void* __restrict__ mb1,
    const void* __restrict__ mW2, const void* __restrict__ mb2,
    const void* __restrict__ mW3, const void* __restrict__ mb3,
    const void* __restrict__ Wq0, const void* __restrict__ Wq1, const void* __restrict__ Wq2,
    const void* __restrict__ Wk0, const void* __restrict__ Wk1, const void* __restrict__ Wk2,
    const void* __restrict__ Wv0, const void* __restrict__ Wv1, const void* __restrict__ Wv2,
    float* __restrict__ ws, const void* __restrict__ nfu, int* __restrict__ flagp)
{
    __shared__ int sflag;
    const int t = threadIdx.x;
    if (t < 64) {
        uint32_t x = ((const uint32_t*)nfu)[64 + t];
        int e = (x >> 7) & 0xff;
        int good = (x != 0u) && (e >= 100) && (e <= 140);
        unsigned long long m = __ballot(good);
        if (t == 0) sflag = (__popcll(m) < 32) ? 1 : 0;
    }
    __syncthreads();
    const int f32 = sflag;
    if (blockIdx.x == 0 && t == 0) flagp[0] = f32;

    const int gt = blockIdx.x * 256 + t;
    float* Wf = ws + WF_OFF;

    for (int i = gt; i < 2048; i += NS) Wf[i] = ldin(mW1, i, f32);   // W1a
    for (int i = gt; i < 64; i += NS) Wf[6656 + i] = ldin(mb1, i, f32);
    for (int i = gt; i < 64; i += NS) Wf[6720 + i] = ldin(mb2, i, f32);
    for (int i = gt; i < 8; i += NS)  Wf[6784 + i] = ldin(mb3, i, f32);

    // W2 B-fragment per-lane image: idx = ((nt*2+ks)*64 + lane)*4 + w
    // value = pack(W2[kb][n], W2[kb+1][n]), n = nt*16+(lane&15), kb = ks*32+(lane>>4)*8+2w
    {
        uint32_t* W2B = (uint32_t*)(ws + W2B_OFF);
        for (int i = gt; i < 2048; i += NS) {
            int f = i >> 8, lane = (i >> 2) & 63, w = i & 3;
            int nt = f >> 1, ks = f & 1, nl2 = lane & 15, gg = lane >> 4;
            int n = nt * 16 + nl2, kb = ks * 32 + gg * 8 + 2 * w;
            float lo = ldin(mW2, (size_t)kb * 64 + n, f32);
            float hi = ldin(mW2, (size_t)(kb + 1) * 64 + n, f32);
            W2B[i] = packbf(lo, hi);
        }
        uint32_t* W3B = (uint32_t*)(ws + W3B_OFF);
        for (int i = gt; i < 512; i += NS) {
            int ks = i >> 8, lane = (i >> 2) & 63, w = i & 3;
            int nl2 = lane & 15, gg = lane >> 4;
            int kb = ks * 32 + gg * 8 + 2 * w;
            float lo = (nl2 < 8) ? ldin(mW3, (size_t)kb * 8 + nl2, f32) : 0.f;
            float hi = (nl2 < 8) ? ldin(mW3, (size_t)(kb + 1) * 8 + nl2, f32) : 0.f;
            W3B[i] = packbf(lo, hi);
        }
    }

    const float e3n0 = 0.08838834764831845f, e3n1 = 0.125f, e3n2 = 0.17677669529663687f;
    const float cg1 = 0.5773502691896258f, cg2 = 0.4472135954999579f;
    const float attn = 0.1889822365046136f;

    const void* Wsrc[9] = {Wq0, Wq1, Wq2, Wk0, Wk1, Wk2, Wv0, Wv1, Wv2};
    float* Wdst[3] = {ws + WTQ_OFF, ws + WTK_OFF, ws + WTV_OFF};
    for (int kind = 0; kind < 3; ++kind) {
        const float f0 = (kind == 0) ? e3n0 * attn : e3n0;
        const float f1 = (kind == 0) ? e3n1 * cg1 * attn : e3n1;
        const float f2 = (kind == 0) ? e3n2 * cg2 * attn : e3n2;
        for (int i = gt; i < 16384; i += NS) {
            int o = i >> 7, ii = i & 127;
            Wdst[kind][i] = ldin(Wsrc[kind * 3], (size_t)ii * 128 + o, f32) * f0;
        }
        for (int i = gt; i < 4096; i += NS) {
            int o = i >> 6, ii = i & 63;
            Wdst[kind][16384 + i] = ldin(Wsrc[kind * 3 + 1], (size_t)ii * 64 + o, f32) * f1;
        }
        for (int i = gt; i < 1024; i += NS) {
            int o = i >> 5, ii = i & 31;
            Wdst[kind][20480 + i] = ldin(Wsrc[kind * 3 + 2], (size_t)ii * 32 + o, f32) * f2;
        }
    }
    float* W1T = ws + W1T_OFF;
    for (int i = gt; i < 30720; i += NS) {
        int o = i / 480, row = i - o * 480;
        float cgv;
        if (row < 160)      cgv = 1.0f;
        else if (row < 224) cgv = cg1;
        else if (row < 256) cgv = cg2;
        else if (row < 384) cgv = 1.0f;
        else if (row < 448) cgv = cg1;
        else                cgv = cg2;
        W1T[i] = ldin(mW1, (size_t)row * 64 + o, f32) * cgv;
    }
}

// ------------------------------------------------- per-node precompute
__global__ __launch_bounds__(256) void kA(
    const void* __restrict__ nfu,
    const float* __restrict__ WtQ, const float* __restrict__ WtK,
    const float* __restrict__ WtV, const float* __restrict__ W1T,
    uint32_t* __restrict__ qG, uint32_t* __restrict__ kG, float* __restrict__ vB,
    uint32_t* __restrict__ ArecG, uint32_t* __restrict__ AsndG,
    const int* __restrict__ flagp)
{
    const int f32 = flagp[0];
    const int n = blockIdx.x, t = threadIdx.x;
    __shared__ float nfs[480];
    for (int i = t; i < 480; i += 256) nfs[i] = ldin(nfu, (size_t)n * 480 + i, f32);

    // zero-fill q/k tile pad (j = 60..63): 2 kinds x 8 heads x 4 j = 64 tasks
    if (t < 64) {
        const int kind2 = t >> 5, hh = (t >> 2) & 7, j = 60 + (t & 3);
        const int row = n & 15, rt = n >> 4;
        const int cc = (j >> 3) ^ (n & 7);
        uint16_t* dst = (uint16_t*)(kind2 == 0 ? qG : kG);
        dst[((((size_t)rt * 8 + hh) * 16 + row) * 8 + cc) * 8 + (j & 7)] = 0;
    }
    __syncthreads();

    for (int idx = t; idx < 1440; idx += 256) {
        int kind = idx / 480, rem = idx - kind * 480;
        int o, m, mul, d, off, am, qoff, sub;
        if (rem < 128)      { o = rem;           m = 0;          mul = 128; d = 1; off = 0;   am = 16; qoff = 0;  sub = 0; }
        else if (rem < 320) { int x = rem - 128; o = x / 3; m = x - o * 3; mul = 64;  d = 3; off = 128; am = 8;  qoff = 16; sub = 16384; }
        else                { int x = rem - 320; o = x / 5; m = x - o * 5; mul = 32;  d = 5; off = 320; am = 4;  qoff = 40; sub = 20480; }
        const float* base = (kind == 0) ? WtQ : (kind == 1) ? WtK : WtV;
        const float4* W4 = reinterpret_cast<const float4*>(base + sub + o * mul);
        const float* nf0 = nfs + off + m;
        float ax = 0.f, ay = 0.f, az = 0.f, aw = 0.f;
        const int n4 = mul >> 2;
        for (int i4 = 0; i4 < n4; ++i4) {
            float4 w = W4[i4];
            int ib = 4 * i4 * d;
            ax += nf0[ib]         * w.x;
            ay += nf0[ib + d]     * w.y;
            az += nf0[ib + 2 * d] * w.z;
            aw += nf0[ib + 3 * d] * w.w;
        }
        float acc = (ax + ay) + (az + aw);
        if (kind == 2) {
            vB[(size_t)n * 480 + rem] = acc;
        } else {
            int hh = o / am, a = o - hh * am;
            int j = qoff + a * d + m;
            // bf16 pre-swizzled tile write: [rt][hh][row][chunk^(row&7)][j&7]
            const int row = n & 15, rt = n >> 4;
            const int cc = (j >> 3) ^ (n & 7);
            uint16_t* dst = (uint16_t*)(kind == 0 ? qG : kG);
            dst[((((size_t)rt * 8 + hh) * 16 + row) * 8 + cc) * 8 + (j & 7)] = f2bf(acc);
        }
    }

    if (t < 128) {
        const int src = t >> 6, o = t & 63;
        float a[9];
        #pragma unroll
        for (int mi = 0; mi < 9; ++mi) {
            const int l = (mi == 0) ? 0 : (mi < 4 ? 1 : 2);
            const int m = (mi == 0) ? 0 : (mi < 4 ? mi - 1 : mi - 4);
            const int mul = (l == 0 ? 128 : l == 1 ? 64 : 32);
            const int d = 2 * l + 1;
            const int off = (l == 0 ? 0 : l == 1 ? 128 : 320);
            const int base = (src == 0) ? (l == 0 ? 32 : l == 1 ? 160 : 224)
                                        : (l == 0 ? 256 : l == 1 ? 384 : 448);
            const float4* W4 = reinterpret_cast<const float4*>(W1T + o * 480 + base);
            const float* nf0 = nfs + off + m;
            float ax = 0.f, ay = 0.f, az = 0.f, aw = 0.f;
            const int n4 = mul >> 2;
            for (int i4 = 0; i4 < n4; ++i4) {
                float4 w = W4[i4];
                int ib = 4 * i4 * d;
                ax += nf0[ib]         * w.x;
                ay += nf0[ib + d]     * w.y;
                az += nf0[ib + 2 * d] * w.z;
                aw += nf0[ib + 3 * d] * w.w;
            }
            a[mi] = (ax + ay) + (az + aw);
        }
        float b[9];
        #pragma unroll
        for (int mi = 0; mi < 9; ++mi) b[mi] = __shfl_xor(a[mi], 1, 64);
        if ((o & 1) == 0) {
            uint32_t* dst = (src ? AsndG : ArecG) + (size_t)n * 288 + (o >> 1);
            #pragma unroll
            for (int mi = 0; mi < 9; ++mi)
                dst[mi * 32] = ((uint32_t)f2bf(b[mi]) << 16) | (uint32_t)f2bf(a[mi]);
        }
    }
}

// ------------------------------------------------- edge MLP + logits (full grid)
// Phase 1 (VALU, per-thread = per-edge): h = tanh(b1 + sh.(Arec+Asnd) + ea@W1a)
// Phase 2 (MFMA, per-mm fused): h2 = tanh(b2 + h@W2) ; ew = b3 + h2@W3 -> ewS (LDS)
// Phase 0 (MFMA, LAST): copy prebuilt q/k bf16 tiles -> logits = q.k ;
//                       L = logits + ew (ONE write)
__global__ __launch_bounds__(256, 4) void kB(
    const void* __restrict__ eaG, const void* __restrict__ shG,
    const uint32_t* __restrict__ ArecG, const uint32_t* __restrict__ AsndG,
    const uint32_t* __restrict__ qG, const uint32_t* __restrict__ kG,
    const uint32_t* __restrict__ W2B, const uint32_t* __restrict__ W3B,
    const float* __restrict__ Wf, float* __restrict__ L,
    const int* __restrict__ flagp)
{
    // words [0,4672)   ArecS        (phase 1)
    // words [4672,9344) AsndS       (phase 1)
    // words [0,8192)   h-tile / q,k tiles (phases 2 / 0)
    // words [8192,10240) ewS: [h(8)][e2(256)^ (h<<2)] f32  (written ph2, read ph0)
    __shared__ __align__(16) uint32_t smem[10240];   // 40960 B = 160KB / 4
    uint32_t* ArecS = smem;
    uint32_t* AsndS = smem + 4672;
    float* ewS = (float*)(smem + 8192);
    const int f32 = flagp[0];
    const int t = threadIdx.x;
    const int s0 = blockIdx.x * 16, r0 = blockIdx.y * 16;
    const int lane = t & 63, wv = t >> 6;
    const int g = lane >> 4, nl = lane & 15;

    const int rl = t >> 4, sl = t & 15;
    const int r = r0 + rl, s = s0 + sl;
    const size_t eidx = (((size_t)r) << 9) + s;

    // ---- per-edge ea / sh loads early (registers; independent of LDS) ----
    uint32_t eaR[16];
    if (f32) {
        const float4* ep = reinterpret_cast<const float4*>((const float*)eaG + eidx * 32);
        #pragma unroll
        for (int i = 0; i < 8; ++i) {
            float4 v = ep[i];
            eaR[2 * i]     = ((uint32_t)f2bf(v.y) << 16) | (uint32_t)f2bf(v.x);
            eaR[2 * i + 1] = ((uint32_t)f2bf(v.w) << 16) | (uint32_t)f2bf(v.z);
        }
    } else {
        const uint4* ep = reinterpret_cast<const uint4*>((const uint32_t*)eaG + eidx * 16);
        #pragma unroll
        for (int i = 0; i < 4; ++i) {
            uint4 v = ep[i];
            eaR[4 * i] = v.x; eaR[4 * i + 1] = v.y; eaR[4 * i + 2] = v.z; eaR[4 * i + 3] = v.w;
        }
    }

    float sh0, sh1, sh2, sh3, sh4, sh5, sh6, sh7, sh8;
    {
        const size_t sb = eidx * 9;
        if (f32) {
            const float* shp = (const float*)shG + sb;
            sh0 = shp[0]; sh1 = shp[1]; sh2 = shp[2]; sh3 = shp[3]; sh4 = shp[4];
            sh5 = shp[5]; sh6 = shp[6]; sh7 = shp[7]; sh8 = shp[8];
        } else {
            const uint16_t* shp = (const uint16_t*)shG + sb;
            sh0 = bf2f(shp[0]); sh1 = bf2f(shp[1]); sh2 = bf2f(shp[2]);
            sh3 = bf2f(shp[3]); sh4 = bf2f(shp[4]); sh5 = bf2f(shp[5]);
            sh6 = bf2f(shp[6]); sh7 = bf2f(shp[7]); sh8 = bf2f(shp[8]);
        }
    }

    // ---- stage Arec/Asnd ----
    for (int i = t; i < 16 * 288; i += 256) {
        int row = i / 288, c = i - row * 288;
        ArecS[row * 292 + c] = ArecG[(size_t)(r0 + row) * 288 + c];
        AsndS[row * 292 + c] = AsndG[(size_t)(s0 + row) * 288 + c];
    }

    float h[64];
    #pragma unroll
    for (int o = 0; o < 64; ++o) h[o] = Wf[6656 + o];   // b1

    __syncthreads();

    // ---- phase 1: sh.(Arec+Asnd) ----
    {
        const int rb = rl * 292, sb = sl * 292;
        #pragma unroll 1
        for (int mi = 0; mi < 9; ++mi) {
            float shv = sh0;
            shv = (mi == 1) ? sh1 : shv;  shv = (mi == 2) ? sh2 : shv;
            shv = (mi == 3) ? sh3 : shv;  shv = (mi == 4) ? sh4 : shv;
            shv = (mi == 5) ? sh5 : shv;  shv = (mi == 6) ? sh6 : shv;
            shv = (mi == 7) ? sh7 : shv;  shv = (mi == 8) ? sh8 : shv;
            const int ro = rb + mi * 32, so = sb + mi * 32;
            #pragma unroll
            for (int oc = 0; oc < 32; ++oc) {
                uint32_t pa = ArecS[ro + oc];
                uint32_t pb = AsndS[so + oc];
                float a0 = __uint_as_float(pa << 16);
                float b0 = __uint_as_float(pb << 16);
                float a1 = __uint_as_float(pa & 0xffff0000u);
                float b1 = __uint_as_float(pb & 0xffff0000u);
                h[2 * oc]     += shv * (a0 + b0);
                h[2 * oc + 1] += shv * (a1 + b1);
            }
        }
    }

    // ---- phase 1b: ea @ W1a ----
    {
        #pragma unroll 1
        for (int cd = 0; cd < 16; ++cd) {
            uint32_t p = eaR[cd];
            float e0 = __uint_as_float(p << 16);
            float e1 = __uint_as_float(p & 0xffff0000u);
            const float* w0 = Wf + (2 * cd) * 64;
            #pragma unroll
            for (int o = 0; o < 64; ++o) h[o] += e0 * w0[o];
            #pragma unroll
            for (int o = 0; o < 64; ++o) h[o] += e1 * w0[64 + o];
        }
    }

    #pragma unroll
    for (int o = 0; o < 64; ++o) h[o] = ftanh(h[o]);

    // ---- pack h -> bf16, write swizzled LDS tile (row e = t, stride 32 u32;
    //      16B chunk c stored at c ^ (row&7)) ----
    __syncthreads();   // all ArecS/AsndS reads complete before overwrite
    #pragma unroll
    for (int c = 0; c < 8; ++c) {
        const int cc = c ^ (t & 7);
        *(uint4*)&smem[t * 32 + cc * 4] =
            make_uint4(packbf(h[c * 8 + 0], h[c * 8 + 1]),
                       packbf(h[c * 8 + 2], h[c * 8 + 3]),
                       packbf(h[c * 8 + 4], h[c * 8 + 5]),
                       packbf(h[c * 8 + 6], h[c * 8 + 7]));
    }
    // Pin: nothing below (W-fragment loads) may be hoisted above this point —
    // keeping phase-1 peak pressure low is the point (R14).
    __builtin_amdgcn_sched_barrier(0);

    // ---- W2/W3 B-fragments: direct 16B loads of prebuilt per-lane images ----
    s16x8 w2f[4][2];
    #pragma unroll
    for (int nt = 0; nt < 4; ++nt) {
        #pragma unroll
        for (int ks = 0; ks < 2; ++ks)
            w2f[nt][ks] = ((const s16x8*)W2B)[(nt * 2 + ks) * 64 + lane];
    }
    s16x8 w3f[2];
    w3f[0] = ((const s16x8*)W3B)[lane];
    w3f[1] = ((const s16x8*)W3B)[64 + lane];
    float b2v[4];
    #pragma unroll
    for (int nt = 0; nt < 4; ++nt) b2v[nt] = Wf[6720 + nt * 16 + nl];
    const float b3v = (nl < 8) ? Wf[6784 + nl] : 0.f;

    // From here on every h-tile LDS row this wave touches is in
    // [wv*64, wv*64+64): written by this wave's own threads -> no barriers
    // needed inside phase 2 (per-wave LDS ordering + compiler lgkmcnt).

    // ---- phase 2 fused per-mm: layer2 -> tanh -> h2 pack -> layer3 -> ewS ----
    uint16_t* sm16 = (uint16_t*)smem;
    #pragma unroll 1
    for (int mm = 0; mm < 4; ++mm) {
        const int mt = wv * 4 + mm;
        const int row = mt * 16 + nl;
        const int sw0 = ((g    ) ^ (row & 7)) * 4;
        const int sw1 = ((4 + g) ^ (row & 7)) * 4;
        // layer 2: A-frag row = mt*16 + (l&15), k = ks*32 + (l>>4)*8 + j
        const s16x8 a0 = *(const s16x8*)&smem[row * 32 + sw0];
        const s16x8 a1 = *(const s16x8*)&smem[row * 32 + sw1];
        f32x4 acc[4];
        #pragma unroll
        for (int nt = 0; nt < 4; ++nt) {
            f32x4 a = {b2v[nt], b2v[nt], b2v[nt], b2v[nt]};
            a = __builtin_amdgcn_mfma_f32_16x16x32_bf16(a0, w2f[nt][0], a, 0, 0, 0);
            a = __builtin_amdgcn_mfma_f32_16x16x32_bf16(a1, w2f[nt][1], a, 0, 0, 0);
            acc[nt] = a;
        }
        // tanh + h2 write (bf16, same swizzle; C layout: col=l&15, row=g*4+reg)
        const int e2base = mt * 16 + g * 4;
        #pragma unroll
        for (int nt = 0; nt < 4; ++nt) {
            const int n = nt * 16 + nl;
            #pragma unroll
            for (int rg = 0; rg < 4; ++rg) {
                const int e2 = e2base + rg;
                const int cc = (n >> 3) ^ (e2 & 7);
                sm16[e2 * 64 + cc * 8 + (n & 7)] = f2bf(ftanh(acc[nt][rg]));
            }
        }
        // layer 3: re-read same rows (now h2) — in-wave LDS ordering guarantees
        // the writes above are observed.
        const s16x8 c0 = *(const s16x8*)&smem[row * 32 + sw0];
        const s16x8 c1 = *(const s16x8*)&smem[row * 32 + sw1];
        f32x4 a3 = {b3v, b3v, b3v, b3v};
        a3 = __builtin_amdgcn_mfma_f32_16x16x32_bf16(c0, w3f[0], a3, 0, 0, 0);
        a3 = __builtin_amdgcn_mfma_f32_16x16x32_bf16(c1, w3f[1], a3, 0, 0, 0);
        if (nl < 8) {
            // ew -> LDS scratch (read back in phase 0b); XOR swizzle -> 4-way
            #pragma unroll
            for (int rg = 0; rg < 4; ++rg) {
                const int e2 = mt * 16 + g * 4 + rg;
                ewS[nl * 256 + (e2 ^ (nl << 2))] = a3[rg];
            }
        }
    }

    __syncthreads();   // phase-2 h-tile reads + ewS writes complete

    // ---- phase 0a: copy prebuilt q/k bf16 tiles -> LDS (pure uint4 copy) ----
    {
        const uint4* qg4 = (const uint4*)qG + (size_t)blockIdx.y * 1024;
        const uint4* kg4 = (const uint4*)kG + (size_t)blockIdx.x * 1024;
        uint4* sm4 = (uint4*)smem;
        for (int i = t; i < 2048; i += 256)
            sm4[i] = (i < 1024) ? qg4[i] : kg4[i - 1024];
    }
    __syncthreads();

    // ---- phase 0b: logits = q.k via MFMA; L = logits + ew (single write) ----
    {
        const int sw0 = ((g    ) ^ (nl & 7)) << 2;
        const int sw1 = ((4 + g) ^ (nl & 7)) << 2;
        #pragma unroll
        for (int hh2 = 0; hh2 < 2; ++hh2) {
            const int h = wv * 2 + hh2;
            const uint32_t* qb = smem + h * 512;
            const uint32_t* kb = smem + 4096 + h * 512;
            const s16x8 qa0 = *(const s16x8*)&qb[nl * 32 + sw0];
            const s16x8 qa1 = *(const s16x8*)&qb[nl * 32 + sw1];
            const s16x8 ka0 = *(const s16x8*)&kb[nl * 32 + sw0];
            const s16x8 ka1 = *(const s16x8*)&kb[nl * 32 + sw1];
            f32x4 a = {0.f, 0.f, 0.f, 0.f};
            a = __builtin_amdgcn_mfma_f32_16x16x32_bf16(qa0, ka0, a, 0, 0, 0);
            a = __builtin_amdgcn_mfma_f32_16x16x32_bf16(qa1, ka1, a, 0, 0, 0);
            float* Lp = L + (((size_t)h) << 18) + (((size_t)(r0 + g * 4)) << 9) + s0 + nl;
            #pragma unroll
            for (int rg = 0; rg < 4; ++rg) {
                const int e2 = (g * 4 + rg) * 16 + nl;
                Lp[(size_t)rg << 9] = a[rg] + ewS[h * 256 + (e2 ^ (h << 2))];
            }
        }
    }
}

// ------------------------------------------------- softmax + aggregation + store
// Prologue: fused softmax over senders (raw L in, normalized weights -> LDS).
// Agg: 240 threads, each owns a j-pair for BOTH rows (vB loaded once, 4 acc).
__global__ __launch_bounds__(512) void kAgg(
    const float* __restrict__ L, const float* __restrict__ vB,
    const void* __restrict__ nfu, void* __restrict__ out,
    const int* __restrict__ flagp)
{
    __shared__ float Ls[8192];             // [rr(2)][s(512)][h(8)]
    const int f32 = flagp[0];
    const int t = threadIdx.x;
    const int r0 = blockIdx.x * 2;

    // ---- fused softmax: group (rr,h) owns one 512-long sender row ----
    {
        const int grp = t >> 5, l = t & 31;
        const int rr = grp >> 3, hsm = grp & 7;
        const float* Lg = L + (((size_t)hsm) << 18) + (((size_t)(r0 + rr)) << 9);
        float v[16];
        float mx = -3.402823466e38f;
        #pragma unroll
        for (int i = 0; i < 16; ++i) {
            v[i] = Lg[l + 32 * i];
            mx = fmaxf(mx, v[i]);
        }
        #pragma unroll
        for (int off = 16; off >= 1; off >>= 1) mx = fmaxf(mx, __shfl_xor(mx, off, 32));
        const float C = 1.4426950408889634f;
        float sm = 0.f;
        #pragma unroll
        for (int i = 0; i < 16; ++i) {
            v[i] = __builtin_amdgcn_exp2f((v[i] - mx) * C);
            sm += v[i];
        }
        #pragma unroll
        for (int off = 16; off >= 1; off >>= 1) sm += __shfl_xor(sm, off, 32);
        const float inv = __builtin_amdgcn_rcpf(sm);
        #pragma unroll
        for (int i = 0; i < 16; ++i)
            Ls[rr * 4096 + (l + 32 * i) * 8 + hsm] = v[i] * inv;
    }
    __syncthreads();

    if (t >= 240) return;
    const int j0 = 2 * t;
    int hh;
    if (j0 < 128)      hh = j0 >> 4;
    else if (j0 < 320) hh = (j0 - 128) / 24;
    else               hh = (j0 - 320) / 20;

    const float* L0 = Ls + hh;
    const float* L1 = Ls + 4096 + hh;
    float a0 = 0.f, a1 = 0.f, b0 = 0.f, b1 = 0.f;
    const float2* vp = reinterpret_cast<const float2*>(vB + j0);
    #pragma unroll 8
    for (int s = 0; s < 512; ++s) {
        float2 v = vp[(size_t)s * 240];
        float w0 = L0[s * 8], w1 = L1[s * 8];
        a0 += w0 * v.x; a1 += w0 * v.y;
        b0 += w1 * v.x; b1 += w1 * v.y;
    }

    const size_t o0 = (size_t)r0 * 480 + j0;
    const size_t o1 = o0 + 480;
    float r00 = ldin(nfu, o0, f32) + a0;
    float r01 = ldin(nfu, o0 + 1, f32) + a1;
    float r10 = ldin(nfu, o1, f32) + b0;
    float r11 = ldin(nfu, o1 + 1, f32) + b1;
    if (f32) {
        float* op = (float*)out;
        op[o0] = r00; op[o0 + 1] = r01;
        op[o1] = r10; op[o1 + 1] = r11;
    } else {
        uint16_t* op = (uint16_t*)out;
        op[o0] = f2bf(r00); op[o0 + 1] = f2bf(r01);
        op[o1] = f2bf(r10); op[o1 + 1] = f2bf(r11);
    }
}

extern "C" void kernel_launch(void* const* d_in, const int* in_sizes, int n_in,
                              void* d_out, int out_size, void* d_ws, size_t ws_size,
                              hipStream_t stream)
{
    (void)in_sizes; (void)n_in; (void)out_size; (void)ws_size;
    const void* nf  = d_in[0];
    const void* eaG = d_in[1];
    const void* shG = d_in[2];

    float* ws = (float*)d_ws;
    uint32_t* qG = (uint32_t*)(ws + QG_OFF);
    uint32_t* kG = (uint32_t*)(ws + KG_OFF);
    uint32_t* W2B = (uint32_t*)(ws + W2B_OFF);
    uint32_t* W3B = (uint32_t*)(ws + W3B_OFF);
    float* vB  = ws + VB_OFF;
    uint32_t* ArecG = (uint32_t*)(ws + ARE_OFF);
    uint32_t* AsndG = (uint32_t*)(ws + ASN_OFF);
    float* Wf  = ws + WF_OFF;
    int* flag  = (int*)(ws + FLAG_OFF);
    float* L   = ws + L_OFF;
    float* WtQ = ws + WTQ_OFF;
    float* WtK = ws + WTK_OFF;
    float* WtV = ws + WTV_OFF;
    float* W1T = ws + W1T_OFF;

    kW<<<64, 256, 0, stream>>>(d_in[12], d_in[13], d_in[14], d_in[15], d_in[16], d_in[17],
                               d_in[3], d_in[4], d_in[5], d_in[6], d_in[7], d_in[8],
                               d_in[9], d_in[10], d_in[11], ws, nf, flag);
    kA<<<512, 256, 0, stream>>>(nf, WtQ, WtK, WtV, W1T, qG, kG, vB, ArecG, AsndG, flag);
    kB<<<dim3(32, 32), 256, 0, stream>>>(eaG, shG, ArecG, AsndG, qG, kG, W2B, W3B, Wf, L, flag);
    kAgg<<<256, 512, 0, stream>>>(L, vB, nf, d_out, flag);
}

// Round 7
// 198.641 us; speedup vs baseline: 1.5112x; 1.1175x over previous
//
#include <hip/hip_runtime.h>
#include <hip/hip_bf16.h>
#include <stdint.h>

// ---------------------------------------------------------------------------
// EquivariantAttention on MI355X.  Dtype-adaptive (bf16 or fp32 inputs).
// R14: W-frags post-phase-1 + per-mm fusion.  VGPR 84, occ 22%, kB 74, tot 259.
// R15: kQK fused into kB (logits via MFMA).  kB 82, tot 253.
// R16: single-L-write kB + softmax fused into kAgg; kSM deleted.  kB 70, tot 231.
// R17: pre-converted bf16 q/k tiles + prebuilt W2/W3 fragment images + paired
//   kAgg rows + kDet folded into kW.  kB 58.6 (VALUBusy 53%), tot 222.
// R18: kAgg rewritten as per-(r-tile, head) MFMA GEMM:
//   out_h[16r x 60j] = softmax(L_h)[16 x 512] @ V_h[512 x 60(pad 64)].
//   - softmax: 16-lane groups, float4 loads, width-16 shuffles, bf16 pack into
//     16KB XOR-swizzled LDS A-tile (same swizzle family as kB, 2-way = free).
//   - kA writes v as bf16 vT[h][j(64,zero-pad)][s] (transposed) so B-frags are
//     16B contiguous GLOBAL loads (L2-resident, 64KB/head, no LDS staging).
//   - wave = one 16-col n-tile; K=512 in 16 MFMA steps; epilogue maps local
//     j -> 3 contiguous column spans per head, adds residual, stores once.
//   Replaces the old 512-deep serial f32 loop (latency-bound at 1 block/CU).
// ---------------------------------------------------------------------------

#define NNODES 512
#define NDIM   480

// ws layout (4-byte word offsets)
#define QG_OFF    0u         // q bf16 tiles: [rt(32)][h(8)][row(16)][32 u32] = 131072 u32
#define W2B_OFF   131072u    // W2 B-frag bf16 per-lane image: 2048 u32
#define W3B_OFF   133120u    // W3 B-frag bf16 per-lane image: 512 u32
#define KG_OFF    245760u    // k bf16 tiles, same layout as qG
#define VT_OFF    491520u    // v bf16 transposed: [h(8)][j(64)][s(512)] u16 = 512KB
#define ARE_OFF   737280u    // 512*288 u32 (bf16 pairs over o): [n][mi(9)][oc(32)]
#define ASN_OFF   884736u    // 512*288 u32
#define WF_OFF    1032192u   // W1a[32][64]@0, b1@6656, b2@6720, b3@6784
#define FLAG_OFF  1040384u   // flag[0] = 1 if inputs fp32, 0 if bf16
#define L_OFF     1040448u   // L SoA: [h(8)][r(512)][s(512)] f32 (8MB)
#define WTQ_OFF   3137600u   // q weights transposed [o][i] f32 + folds
#define WTK_OFF   3159104u
#define WTV_OFF   3180608u
#define W1T_OFF   3202112u   // mW1 transposed [o(64)][row(480)] f32, cg folded

typedef float f32x4 __attribute__((ext_vector_type(4)));
typedef short s16x8 __attribute__((ext_vector_type(8)));

__device__ __forceinline__ float bf2f(uint16_t u) {
    return __uint_as_float(((uint32_t)u) << 16);
}
__device__ __forceinline__ uint16_t f2bf(float f) {
    union { __hip_bfloat16 h; uint16_t u; } cv;
    cv.h = __float2bfloat16(f);
    return cv.u;
}
__device__ __forceinline__ uint32_t packbf(float lo, float hi) {
    return ((uint32_t)f2bf(hi) << 16) | (uint32_t)f2bf(lo);
}
__device__ __forceinline__ float ldin(const void* p, size_t i, int f32) {
    return f32 ? ((const float*)p)[i] : bf2f(((const uint16_t*)p)[i]);
}
// tanh(x) = 1 - 2/(exp(2x)+1)
__device__ __forceinline__ float ftanh(float x) {
    float e = __builtin_amdgcn_exp2f(x * 2.885390081777927f);
    return 1.0f - 2.0f * __builtin_amdgcn_rcpf(e + 1.0f);
}

// ---------------------------------------------------------------- weights prep
// (kDet fused: every block self-detects dtype from nf; block 0 publishes flag.)
#define NS 16384
__global__ __launch_bounds__(256) void kW(
    const void* __restrict__ mW1, const void* __restrict__ mb1,
    const void* __restrict__ mW2, const void* __restrict__ mb2,
    const void* __restrict__ mW3, const void* __restrict__ mb3,
    const void* __restrict__ Wq0, const void* __restrict__ Wq1, const void* __restrict__ Wq2,
    const void* __restrict__ Wk0, const void* __restrict__ Wk1, const void* __restrict__ Wk2,
    const void* __restrict__ Wv0, const void* __restrict__ Wv1, const void* __restrict__ Wv2,
    float* __restrict__ ws, const void* __restrict__ nfu, int* __restrict__ flagp)
{
    __shared__ int sflag;
    const int t = threadIdx.x;
    if (t < 64) {
        uint32_t x = ((const uint32_t*)nfu)[64 + t];
        int e = (x >> 7) & 0xff;
        int good = (x != 0u) && (e >= 100) && (e <= 140);
        unsigned long long m = __ballot(good);
        if (t == 0) sflag = (__popcll(m) < 32) ? 1 : 0;
    }
    __syncthreads();
    const int f32 = sflag;
    if (blockIdx.x == 0 && t == 0) flagp[0] = f32;

    const int gt = blockIdx.x * 256 + t;
    float* Wf = ws + WF_OFF;

    for (int i = gt; i < 2048; i += NS) Wf[i] = ldin(mW1, i, f32);   // W1a
    for (int i = gt; i < 64; i += NS) Wf[6656 + i] = ldin(mb1, i, f32);
    for (int i = gt; i < 64; i += NS) Wf[6720 + i] = ldin(mb2, i, f32);
    for (int i = gt; i < 8; i += NS)  Wf[6784 + i] = ldin(mb3, i, f32);

    // W2 B-fragment per-lane image: idx = ((nt*2+ks)*64 + lane)*4 + w
    // value = pack(W2[kb][n], W2[kb+1][n]), n = nt*16+(lane&15), kb = ks*32+(lane>>4)*8+2w
    {
        uint32_t* W2B = (uint32_t*)(ws + W2B_OFF);
        for (int i = gt; i < 2048; i += NS) {
            int f = i >> 8, lane = (i >> 2) & 63, w = i & 3;
            int nt = f >> 1, ks = f & 1, nl2 = lane & 15, gg = lane >> 4;
            int n = nt * 16 + nl2, kb = ks * 32 + gg * 8 + 2 * w;
            float lo = ldin(mW2, (size_t)kb * 64 + n, f32);
            float hi = ldin(mW2, (size_t)(kb + 1) * 64 + n, f32);
            W2B[i] = packbf(lo, hi);
        }
        uint32_t* W3B = (uint32_t*)(ws + W3B_OFF);
        for (int i = gt; i < 512; i += NS) {
            int ks = i >> 8, lane = (i >> 2) & 63, w = i & 3;
            int nl2 = lane & 15, gg = lane >> 4;
            int kb = ks * 32 + gg * 8 + 2 * w;
            float lo = (nl2 < 8) ? ldin(mW3, (size_t)kb * 8 + nl2, f32) : 0.f;
            float hi = (nl2 < 8) ? ldin(mW3, (size_t)(kb + 1) * 8 + nl2, f32) : 0.f;
            W3B[i] = packbf(lo, hi);
        }
    }

    const float e3n0 = 0.08838834764831845f, e3n1 = 0.125f, e3n2 = 0.17677669529663687f;
    const float cg1 = 0.5773502691896258f, cg2 = 0.4472135954999579f;
    const float attn = 0.1889822365046136f;

    const void* Wsrc[9] = {Wq0, Wq1, Wq2, Wk0, Wk1, Wk2, Wv0, Wv1, Wv2};
    float* Wdst[3] = {ws + WTQ_OFF, ws + WTK_OFF, ws + WTV_OFF};
    for (int kind = 0; kind < 3; ++kind) {
        const float f0 = (kind == 0) ? e3n0 * attn : e3n0;
        const float f1 = (kind == 0) ? e3n1 * cg1 * attn : e3n1;
        const float f2 = (kind == 0) ? e3n2 * cg2 * attn : e3n2;
        for (int i = gt; i < 16384; i += NS) {
            int o = i >> 7, ii = i & 127;
            Wdst[kind][i] = ldin(Wsrc[kind * 3], (size_t)ii * 128 + o, f32) * f0;
        }
        for (int i = gt; i < 4096; i += NS) {
            int o = i >> 6, ii = i & 63;
            Wdst[kind][16384 + i] = ldin(Wsrc[kind * 3 + 1], (size_t)ii * 64 + o, f32) * f1;
        }
        for (int i = gt; i < 1024; i += NS) {
            int o = i >> 5, ii = i & 31;
            Wdst[kind][20480 + i] = ldin(Wsrc[kind * 3 + 2], (size_t)ii * 32 + o, f32) * f2;
        }
    }
    float* W1T = ws + W1T_OFF;
    for (int i = gt; i < 30720; i += NS) {
        int o = i / 480, row = i - o * 480;
        float cgv;
        if (row < 160)      cgv = 1.0f;
        else if (row < 224) cgv = cg1;
        else if (row < 256) cgv = cg2;
        else if (row < 384) cgv = 1.0f;
        else if (row < 448) cgv = cg1;
        else                cgv = cg2;
        W1T[i] = ldin(mW1, (size_t)row * 64 + o, f32) * cgv;
    }
}

// ------------------------------------------------- per-node precompute
__global__ __launch_bounds__(256) void kA(
    const void* __restrict__ nfu,
    const float* __restrict__ WtQ, const float* __restrict__ WtK,
    const float* __restrict__ WtV, const float* __restrict__ W1T,
    uint32_t* __restrict__ qG, uint32_t* __restrict__ kG, uint16_t* __restrict__ vT,
    uint32_t* __restrict__ ArecG, uint32_t* __restrict__ AsndG,
    const int* __restrict__ flagp)
{
    const int f32 = flagp[0];
    const int n = blockIdx.x, t = threadIdx.x;
    __shared__ float nfs[480];
    for (int i = t; i < 480; i += 256) nfs[i] = ldin(nfu, (size_t)n * 480 + i, f32);

    // zero-fill tile pad (j = 60..63): {q,k,v} x 8 heads x 4 j = 96 tasks
    if (t < 96) {
        const int kind3 = t >> 5, hh = (t >> 2) & 7, j = 60 + (t & 3);
        if (kind3 < 2) {
            const int row = n & 15, rt = n >> 4;
            const int cc = (j >> 3) ^ (n & 7);
            uint16_t* dst = (uint16_t*)(kind3 == 0 ? qG : kG);
            dst[((((size_t)rt * 8 + hh) * 16 + row) * 8 + cc) * 8 + (j & 7)] = 0;
        } else {
            vT[((size_t)(hh * 64 + j)) * 512 + n] = 0;
        }
    }
    __syncthreads();

    for (int idx = t; idx < 1440; idx += 256) {
        int kind = idx / 480, rem = idx - kind * 480;
        int o, m, mul, d, off, am, qoff, sub;
        if (rem < 128)      { o = rem;           m = 0;          mul = 128; d = 1; off = 0;   am = 16; qoff = 0;  sub = 0; }
        else if (rem < 320) { int x = rem - 128; o = x / 3; m = x - o * 3; mul = 64;  d = 3; off = 128; am = 8;  qoff = 16; sub = 16384; }
        else                { int x = rem - 320; o = x / 5; m = x - o * 5; mul = 32;  d = 5; off = 320; am = 4;  qoff = 40; sub = 20480; }
        const float* base = (kind == 0) ? WtQ : (kind == 1) ? WtK : WtV;
        const float4* W4 = reinterpret_cast<const float4*>(base + sub + o * mul);
        const float* nf0 = nfs + off + m;
        float ax = 0.f, ay = 0.f, az = 0.f, aw = 0.f;
        const int n4 = mul >> 2;
        for (int i4 = 0; i4 < n4; ++i4) {
            float4 w = W4[i4];
            int ib = 4 * i4 * d;
            ax += nf0[ib]         * w.x;
            ay += nf0[ib + d]     * w.y;
            az += nf0[ib + 2 * d] * w.z;
            aw += nf0[ib + 3 * d] * w.w;
        }
        float acc = (ax + ay) + (az + aw);
        int hh = o / am, a = o - hh * am;
        int j = qoff + a * d + m;
        if (kind == 2) {
            // v bf16 transposed: [h][j][s=n]
            vT[((size_t)(hh * 64 + j)) * 512 + n] = f2bf(acc);
        } else {
            // bf16 pre-swizzled tile write: [rt][hh][row][chunk^(row&7)][j&7]
            const int row = n & 15, rt = n >> 4;
            const int cc = (j >> 3) ^ (n & 7);
            uint16_t* dst = (uint16_t*)(kind == 0 ? qG : kG);
            dst[((((size_t)rt * 8 + hh) * 16 + row) * 8 + cc) * 8 + (j & 7)] = f2bf(acc);
        }
    }

    if (t < 128) {
        const int src = t >> 6, o = t & 63;
        float a[9];
        #pragma unroll
        for (int mi = 0; mi < 9; ++mi) {
            const int l = (mi == 0) ? 0 : (mi < 4 ? 1 : 2);
            const int m = (mi == 0) ? 0 : (mi < 4 ? mi - 1 : mi - 4);
            const int mul = (l == 0 ? 128 : l == 1 ? 64 : 32);
            const int d = 2 * l + 1;
            const int off = (l == 0 ? 0 : l == 1 ? 128 : 320);
            const int base = (src == 0) ? (l == 0 ? 32 : l == 1 ? 160 : 224)
                                        : (l == 0 ? 256 : l == 1 ? 384 : 448);
            const float4* W4 = reinterpret_cast<const float4*>(W1T + o * 480 + base);
            const float* nf0 = nfs + off + m;
            float ax = 0.f, ay = 0.f, az = 0.f, aw = 0.f;
            const int n4 = mul >> 2;
            for (int i4 = 0; i4 < n4; ++i4) {
                float4 w = W4[i4];
                int ib = 4 * i4 * d;
                ax += nf0[ib]         * w.x;
                ay += nf0[ib + d]     * w.y;
                az += nf0[ib + 2 * d] * w.z;
                aw += nf0[ib + 3 * d] * w.w;
            }
            a[mi] = (ax + ay) + (az + aw);
        }
        float b[9];
        #pragma unroll
        for (int mi = 0; mi < 9; ++mi) b[mi] = __shfl_xor(a[mi], 1, 64);
        if ((o & 1) == 0) {
            uint32_t* dst = (src ? AsndG : ArecG) + (size_t)n * 288 + (o >> 1);
            #pragma unroll
            for (int mi = 0; mi < 9; ++mi)
                dst[mi * 32] = ((uint32_t)f2bf(b[mi]) << 16) | (uint32_t)f2bf(a[mi]);
        }
    }
}

// ------------------------------------------------- edge MLP + logits (full grid)
// Phase 1 (VALU, per-thread = per-edge): h = tanh(b1 + sh.(Arec+Asnd) + ea@W1a)
// Phase 2 (MFMA, per-mm fused): h2 = tanh(b2 + h@W2) ; ew = b3 + h2@W3 -> ewS (LDS)
// Phase 0 (MFMA, LAST): copy prebuilt q/k bf16 tiles -> logits = q.k ;
//                       L = logits + ew (ONE write)
__global__ __launch_bounds__(256, 4) void kB(
    const void* __restrict__ eaG, const void* __restrict__ shG,
    const uint32_t* __restrict__ ArecG, const uint32_t* __restrict__ AsndG,
    const uint32_t* __restrict__ qG, const uint32_t* __restrict__ kG,
    const uint32_t* __restrict__ W2B, const uint32_t* __restrict__ W3B,
    const float* __restrict__ Wf, float* __restrict__ L,
    const int* __restrict__ flagp)
{
    // words [0,4672)   ArecS        (phase 1)
    // words [4672,9344) AsndS       (phase 1)
    // words [0,8192)   h-tile / q,k tiles (phases 2 / 0)
    // words [8192,10240) ewS: [h(8)][e2(256)^ (h<<2)] f32  (written ph2, read ph0)
    __shared__ __align__(16) uint32_t smem[10240];   // 40960 B = 160KB / 4
    uint32_t* ArecS = smem;
    uint32_t* AsndS = smem + 4672;
    float* ewS = (float*)(smem + 8192);
    const int f32 = flagp[0];
    const int t = threadIdx.x;
    const int s0 = blockIdx.x * 16, r0 = blockIdx.y * 16;
    const int lane = t & 63, wv = t >> 6;
    const int g = lane >> 4, nl = lane & 15;

    const int rl = t >> 4, sl = t & 15;
    const int r = r0 + rl, s = s0 + sl;
    const size_t eidx = (((size_t)r) << 9) + s;

    // ---- per-edge ea / sh loads early (registers; independent of LDS) ----
    uint32_t eaR[16];
    if (f32) {
        const float4* ep = reinterpret_cast<const float4*>((const float*)eaG + eidx * 32);
        #pragma unroll
        for (int i = 0; i < 8; ++i) {
            float4 v = ep[i];
            eaR[2 * i]     = ((uint32_t)f2bf(v.y) << 16) | (uint32_t)f2bf(v.x);
            eaR[2 * i + 1] = ((uint32_t)f2bf(v.w) << 16) | (uint32_t)f2bf(v.z);
        }
    } else {
        const uint4* ep = reinterpret_cast<const uint4*>((const uint32_t*)eaG + eidx * 16);
        #pragma unroll
        for (int i = 0; i < 4; ++i) {
            uint4 v = ep[i];
            eaR[4 * i] = v.x; eaR[4 * i + 1] = v.y; eaR[4 * i + 2] = v.z; eaR[4 * i + 3] = v.w;
        }
    }

    float sh0, sh1, sh2, sh3, sh4, sh5, sh6, sh7, sh8;
    {
        const size_t sb = eidx * 9;
        if (f32) {
            const float* shp = (const float*)shG + sb;
            sh0 = shp[0]; sh1 = shp[1]; sh2 = shp[2]; sh3 = shp[3]; sh4 = shp[4];
            sh5 = shp[5]; sh6 = shp[6]; sh7 = shp[7]; sh8 = shp[8];
        } else {
            const uint16_t* shp = (const uint16_t*)shG + sb;
            sh0 = bf2f(shp[0]); sh1 = bf2f(shp[1]); sh2 = bf2f(shp[2]);
            sh3 = bf2f(shp[3]); sh4 = bf2f(shp[4]); sh5 = bf2f(shp[5]);
            sh6 = bf2f(shp[6]); sh7 = bf2f(shp[7]); sh8 = bf2f(shp[8]);
        }
    }

    // ---- stage Arec/Asnd ----
    for (int i = t; i < 16 * 288; i += 256) {
        int row = i / 288, c = i - row * 288;
        ArecS[row * 292 + c] = ArecG[(size_t)(r0 + row) * 288 + c];
        AsndS[row * 292 + c] = AsndG[(size_t)(s0 + row) * 288 + c];
    }

    float h[64];
    #pragma unroll
    for (int o = 0; o < 64; ++o) h[o] = Wf[6656 + o];   // b1

    __syncthreads();

    // ---- phase 1: sh.(Arec+Asnd) ----
    {
        const int rb = rl * 292, sb = sl * 292;
        #pragma unroll 1
        for (int mi = 0; mi < 9; ++mi) {
            float shv = sh0;
            shv = (mi == 1) ? sh1 : shv;  shv = (mi == 2) ? sh2 : shv;
            shv = (mi == 3) ? sh3 : shv;  shv = (mi == 4) ? sh4 : shv;
            shv = (mi == 5) ? sh5 : shv;  shv = (mi == 6) ? sh6 : shv;
            shv = (mi == 7) ? sh7 : shv;  shv = (mi == 8) ? sh8 : shv;
            const int ro = rb + mi * 32, so = sb + mi * 32;
            #pragma unroll
            for (int oc = 0; oc < 32; ++oc) {
                uint32_t pa = ArecS[ro + oc];
                uint32_t pb = AsndS[so + oc];
                float a0 = __uint_as_float(pa << 16);
                float b0 = __uint_as_float(pb << 16);
                float a1 = __uint_as_float(pa & 0xffff0000u);
                float b1 = __uint_as_float(pb & 0xffff0000u);
                h[2 * oc]     += shv * (a0 + b0);
                h[2 * oc + 1] += shv * (a1 + b1);
            }
        }
    }

    // ---- phase 1b: ea @ W1a ----
    {
        #pragma unroll 1
        for (int cd = 0; cd < 16; ++cd) {
            uint32_t p = eaR[cd];
            float e0 = __uint_as_float(p << 16);
            float e1 = __uint_as_float(p & 0xffff0000u);
            const float* w0 = Wf + (2 * cd) * 64;
            #pragma unroll
            for (int o = 0; o < 64; ++o) h[o] += e0 * w0[o];
            #pragma unroll
            for (int o = 0; o < 64; ++o) h[o] += e1 * w0[64 + o];
        }
    }

    #pragma unroll
    for (int o = 0; o < 64; ++o) h[o] = ftanh(h[o]);

    // ---- pack h -> bf16, write swizzled LDS tile (row e = t, stride 32 u32;
    //      16B chunk c stored at c ^ (row&7)) ----
    __syncthreads();   // all ArecS/AsndS reads complete before overwrite
    #pragma unroll
    for (int c = 0; c < 8; ++c) {
        const int cc = c ^ (t & 7);
        *(uint4*)&smem[t * 32 + cc * 4] =
            make_uint4(packbf(h[c * 8 + 0], h[c * 8 + 1]),
                       packbf(h[c * 8 + 2], h[c * 8 + 3]),
                       packbf(h[c * 8 + 4], h[c * 8 + 5]),
                       packbf(h[c * 8 + 6], h[c * 8 + 7]));
    }
    // Pin: nothing below (W-fragment loads) may be hoisted above this point —
    // keeping phase-1 peak pressure low is the point (R14).
    __builtin_amdgcn_sched_barrier(0);

    // ---- W2/W3 B-fragments: direct 16B loads of prebuilt per-lane images ----
    s16x8 w2f[4][2];
    #pragma unroll
    for (int nt = 0; nt < 4; ++nt) {
        #pragma unroll
        for (int ks = 0; ks < 2; ++ks)
            w2f[nt][ks] = ((const s16x8*)W2B)[(nt * 2 + ks) * 64 + lane];
    }
    s16x8 w3f[2];
    w3f[0] = ((const s16x8*)W3B)[lane];
    w3f[1] = ((const s16x8*)W3B)[64 + lane];
    float b2v[4];
    #pragma unroll
    for (int nt = 0; nt < 4; ++nt) b2v[nt] = Wf[6720 + nt * 16 + nl];
    const float b3v = (nl < 8) ? Wf[6784 + nl] : 0.f;

    // From here on every h-tile LDS row this wave touches is in
    // [wv*64, wv*64+64): written by this wave's own threads -> no barriers
    // needed inside phase 2 (per-wave LDS ordering + compiler lgkmcnt).

    // ---- phase 2 fused per-mm: layer2 -> tanh -> h2 pack -> layer3 -> ewS ----
    uint16_t* sm16 = (uint16_t*)smem;
    #pragma unroll 1
    for (int mm = 0; mm < 4; ++mm) {
        const int mt = wv * 4 + mm;
        const int row = mt * 16 + nl;
        const int sw0 = ((g    ) ^ (row & 7)) * 4;
        const int sw1 = ((4 + g) ^ (row & 7)) * 4;
        // layer 2: A-frag row = mt*16 + (l&15), k = ks*32 + (l>>4)*8 + j
        const s16x8 a0 = *(const s16x8*)&smem[row * 32 + sw0];
        const s16x8 a1 = *(const s16x8*)&smem[row * 32 + sw1];
        f32x4 acc[4];
        #pragma unroll
        for (int nt = 0; nt < 4; ++nt) {
            f32x4 a = {b2v[nt], b2v[nt], b2v[nt], b2v[nt]};
            a = __builtin_amdgcn_mfma_f32_16x16x32_bf16(a0, w2f[nt][0], a, 0, 0, 0);
            a = __builtin_amdgcn_mfma_f32_16x16x32_bf16(a1, w2f[nt][1], a, 0, 0, 0);
            acc[nt] = a;
        }
        // tanh + h2 write (bf16, same swizzle; C layout: col=l&15, row=g*4+reg)
        const int e2base = mt * 16 + g * 4;
        #pragma unroll
        for (int nt = 0; nt < 4; ++nt) {
            const int n = nt * 16 + nl;
            #pragma unroll
            for (int rg = 0; rg < 4; ++rg) {
                const int e2 = e2base + rg;
                const int cc = (n >> 3) ^ (e2 & 7);
                sm16[e2 * 64 + cc * 8 + (n & 7)] = f2bf(ftanh(acc[nt][rg]));
            }
        }
        // layer 3: re-read same rows (now h2) — in-wave LDS ordering guarantees
        // the writes above are observed.
        const s16x8 c0 = *(const s16x8*)&smem[row * 32 + sw0];
        const s16x8 c1 = *(const s16x8*)&smem[row * 32 + sw1];
        f32x4 a3 = {b3v, b3v, b3v, b3v};
        a3 = __builtin_amdgcn_mfma_f32_16x16x32_bf16(c0, w3f[0], a3, 0, 0, 0);
        a3 = __builtin_amdgcn_mfma_f32_16x16x32_bf16(c1, w3f[1], a3, 0, 0, 0);
        if (nl < 8) {
            // ew -> LDS scratch (read back in phase 0b); XOR swizzle -> 4-way
            #pragma unroll
            for (int rg = 0; rg < 4; ++rg) {
                const int e2 = mt * 16 + g * 4 + rg;
                ewS[nl * 256 + (e2 ^ (nl << 2))] = a3[rg];
            }
        }
    }

    __syncthreads();   // phase-2 h-tile reads + ewS writes complete

    // ---- phase 0a: copy prebuilt q/k bf16 tiles -> LDS (pure uint4 copy) ----
    {
        const uint4* qg4 = (const uint4*)qG + (size_t)blockIdx.y * 1024;
        const uint4* kg4 = (const uint4*)kG + (size_t)blockIdx.x * 1024;
        uint4* sm4 = (uint4*)smem;
        for (int i = t; i < 2048; i += 256)
            sm4[i] = (i < 1024) ? qg4[i] : kg4[i - 1024];
    }
    __syncthreads();

    // ---- phase 0b: logits = q.k via MFMA; L = logits + ew (single write) ----
    {
        const int sw0 = ((g    ) ^ (nl & 7)) << 2;
        const int sw1 = ((4 + g) ^ (nl & 7)) << 2;
        #pragma unroll
        for (int hh2 = 0; hh2 < 2; ++hh2) {
            const int h = wv * 2 + hh2;
            const uint32_t* qb = smem + h * 512;
            const uint32_t* kb = smem + 4096 + h * 512;
            const s16x8 qa0 = *(const s16x8*)&qb[nl * 32 + sw0];
            const s16x8 qa1 = *(const s16x8*)&qb[nl * 32 + sw1];
            const s16x8 ka0 = *(const s16x8*)&kb[nl * 32 + sw0];
            const s16x8 ka1 = *(const s16x8*)&kb[nl * 32 + sw1];
            f32x4 a = {0.f, 0.f, 0.f, 0.f};
            a = __builtin_amdgcn_mfma_f32_16x16x32_bf16(qa0, ka0, a, 0, 0, 0);
            a = __builtin_amdgcn_mfma_f32_16x16x32_bf16(qa1, ka1, a, 0, 0, 0);
            float* Lp = L + (((size_t)h) << 18) + (((size_t)(r0 + g * 4)) << 9) + s0 + nl;
            #pragma unroll
            for (int rg = 0; rg < 4; ++rg) {
                const int e2 = (g * 4 + rg) * 16 + nl;
                Lp[(size_t)rg << 9] = a[rg] + ewS[h * 256 + (e2 ^ (h << 2))];
            }
        }
    }
}

// ------------------------------------------------- softmax + aggregation (MFMA)
// Block = (16-row r-tile, head h).  out_h[16 x 60] = softmax(L_h)[16x512] @ V_h.
// Softmax: 16-lane groups per row; bf16 A-tile in 16KB swizzled LDS.
// GEMM: wave = one 16-col n-tile; B-frags are 16B contiguous vT global loads.
__global__ __launch_bounds__(256) void kAgg(
    const float* __restrict__ L, const uint16_t* __restrict__ vT,
    const void* __restrict__ nfu, void* __restrict__ out,
    const int* __restrict__ flagp)
{
    __shared__ __align__(16) uint32_t Ws[4096];   // [row(16)][chunk(64)^swz][4 u32]
    const int f32 = flagp[0];
    const int t = threadIdx.x;
    const int lane = t & 63, wv = t >> 6;
    const int g = lane >> 4, nl = lane & 15;
    const int r0 = blockIdx.x * 16;
    const int h  = blockIdx.y;

    // ---- softmax: row = wv*4+g, 16 lanes/row; lane owns 4 blocks of 8 cols ----
    {
        const int row = wv * 4 + g;
        const float* Lg = L + (((size_t)h) << 18) + (((size_t)(r0 + row)) << 9);
        float v[32];
        #pragma unroll
        for (int cw = 0; cw < 4; ++cw) {
            const float4* p = reinterpret_cast<const float4*>(Lg + nl * 8 + cw * 128);
            float4 x = p[0], y = p[1];
            v[cw * 8 + 0] = x.x; v[cw * 8 + 1] = x.y; v[cw * 8 + 2] = x.z; v[cw * 8 + 3] = x.w;
            v[cw * 8 + 4] = y.x; v[cw * 8 + 5] = y.y; v[cw * 8 + 6] = y.z; v[cw * 8 + 7] = y.w;
        }
        float mx = -3.402823466e38f;
        #pragma unroll
        for (int i = 0; i < 32; ++i) mx = fmaxf(mx, v[i]);
        #pragma unroll
        for (int off = 8; off >= 1; off >>= 1) mx = fmaxf(mx, __shfl_xor(mx, off, 16));
        const float C = 1.4426950408889634f;
        float sm = 0.f;
        #pragma unroll
        for (int i = 0; i < 32; ++i) {
            v[i] = __builtin_amdgcn_exp2f((v[i] - mx) * C);
            sm += v[i];
        }
        #pragma unroll
        for (int off = 8; off >= 1; off >>= 1) sm += __shfl_xor(sm, off, 16);
        const float inv = __builtin_amdgcn_rcpf(sm);
        #pragma unroll
        for (int cw = 0; cw < 4; ++cw) {
            const int cc = (nl + cw * 16) ^ (row & 7);
            *(uint4*)&Ws[row * 256 + cc * 4] = make_uint4(
                packbf(v[cw * 8 + 0] * inv, v[cw * 8 + 1] * inv),
                packbf(v[cw * 8 + 2] * inv, v[cw * 8 + 3] * inv),
                packbf(v[cw * 8 + 4] * inv, v[cw * 8 + 5] * inv),
                packbf(v[cw * 8 + 6] * inv, v[cw * 8 + 7] * inv));
        }
    }
    __syncthreads();

    // ---- GEMM: A = Ws (row=nl, k=ks*32+g*8+j), B = vT[h][n][k] contiguous ----
    f32x4 acc = {0.f, 0.f, 0.f, 0.f};
    {
        const uint16_t* vb = vT + ((size_t)(h * 64 + wv * 16 + nl)) * 512 + g * 8;
        #pragma unroll
        for (int ks = 0; ks < 16; ++ks) {
            const s16x8 a = *(const s16x8*)&Ws[nl * 256 + (((ks * 4 + g) ^ (nl & 7)) << 2)];
            const s16x8 b = *(const s16x8*)&vb[ks * 32];
            acc = __builtin_amdgcn_mfma_f32_16x16x32_bf16(a, b, acc, 0, 0, 0);
        }
    }

    // ---- epilogue: local j -> global column (3 contiguous spans per head) ----
    const int n = wv * 16 + nl;
    if (n < 60) {
        int col;
        if (n < 16)      col = h * 16 + n;
        else if (n < 40) col = 128 + h * 24 + (n - 16);
        else             col = 320 + h * 20 + (n - 40);
        #pragma unroll
        for (int rg = 0; rg < 4; ++rg) {
            const size_t o = (size_t)(r0 + g * 4 + rg) * 480 + col;
            float val = ldin(nfu, o, f32) + acc[rg];
            if (f32) ((float*)out)[o] = val;
            else     ((uint16_t*)out)[o] = f2bf(val);
        }
    }
}

extern "C" void kernel_launch(void* const* d_in, const int* in_sizes, int n_in,
                              void* d_out, int out_size, void* d_ws, size_t ws_size,
                              hipStream_t stream)
{
    (void)in_sizes; (void)n_in; (void)out_size; (void)ws_size;
    const void* nf  = d_in[0];
    const void* eaG = d_in[1];
    const void* shG = d_in[2];

    float* ws = (float*)d_ws;
    uint32_t* qG = (uint32_t*)(ws + QG_OFF);
    uint32_t* kG = (uint32_t*)(ws + KG_OFF);
    uint32_t* W2B = (uint32_t*)(ws + W2B_OFF);
    uint32_t* W3B = (uint32_t*)(ws + W3B_OFF);
    uint16_t* vT = (uint16_t*)(ws + VT_OFF);
    uint32_t* ArecG = (uint32_t*)(ws + ARE_OFF);
    uint32_t* AsndG = (uint32_t*)(ws + ASN_OFF);
    float* Wf  = ws + WF_OFF;
    int* flag  = (int*)(ws + FLAG_OFF);
    float* L   = ws + L_OFF;
    float* WtQ = ws + WTQ_OFF;
    float* WtK = ws + WTK_OFF;
    float* WtV = ws + WTV_OFF;
    float* W1T = ws + W1T_OFF;

    kW<<<64, 256, 0, stream>>>(d_in[12], d_in[13], d_in[14], d_in[15], d_in[16], d_in[17],
                               d_in[3], d_in[4], d_in[5], d_in[6], d_in[7], d_in[8],
                               d_in[9], d_in[10], d_in[11], ws, nf, flag);
    kA<<<512, 256, 0, stream>>>(nf, WtQ, WtK, WtV, W1T, qG, kG, vT, ArecG, AsndG, flag);
    kB<<<dim3(32, 32), 256, 0, stream>>>(eaG, shG, ArecG, AsndG, qG, kG, W2B, W3B, Wf, L, flag);
    kAgg<<<dim3(32, 8), 256, 0, stream>>>(L, vT, nf, d_out, flag);
}

// Round 8
// 188.762 us; speedup vs baseline: 1.5903x; 1.0523x over previous
//
#include <hip/hip_runtime.h>
#include <hip/hip_bf16.h>
#include <stdint.h>

// ---------------------------------------------------------------------------
// EquivariantAttention on MI355X.  Dtype-adaptive (bf16 or fp32 inputs).
// R15: kQK fused into kB (logits via MFMA).  kB 82, tot 253.
// R16: single-L-write kB + softmax fused into kAgg; kSM deleted.  kB 70, tot 231.
// R17: pre-converted bf16 q/k tiles + prebuilt W2/W3 fragment images.  kB 58.6.
// R18: kAgg rewritten as per-(r-tile, head) MFMA GEMM.  tot 198.6 (kAgg ~30 -> ~8).
// R19: kB phase-1 ea@W1a (2048 VALU FMA/thread, the largest VALU chunk) -> MFMA:
//   - A-frags gathered from eaR registers via 16 compile-time __shfl per mm
//     (edge rows mt*16+nl are owned by lanes of the SAME wave) — no LDS stage,
//     no extra barrier for the gather.
//   - W1a B-frags prebuilt in kW (W1B image, like W2B/W3B).
//   - C written bf16 to the h-tile region (phase-2's proven intra-wave
//     write->read pattern); thread re-reads its own row as h[64] init (+b1).
//   - Arec/Asnd staging moved after the h-init read (+1 barrier).
//   Numerics: ea already bf16; W1a->bf16 adds ~0.002 pre-tanh (tolerated).
// ---------------------------------------------------------------------------

#define NNODES 512
#define NDIM   480

// ws layout (4-byte word offsets)
#define QG_OFF    0u         // q bf16 tiles: [rt(32)][h(8)][row(16)][32 u32] = 131072 u32
#define W2B_OFF   131072u    // W2 B-frag bf16 per-lane image: 2048 u32
#define W3B_OFF   133120u    // W3 B-frag bf16 per-lane image: 512 u32
#define W1B_OFF   133632u    // W1a B-frag bf16 per-lane image: 1024 u32
#define KG_OFF    245760u    // k bf16 tiles, same layout as qG
#define VT_OFF    491520u    // v bf16 transposed: [h(8)][j(64)][s(512)] u16 = 512KB
#define ARE_OFF   737280u    // 512*288 u32 (bf16 pairs over o): [n][mi(9)][oc(32)]
#define ASN_OFF   884736u    // 512*288 u32
#define WF_OFF    1032192u   // W1a[32][64]@0, b1@6656, b2@6720, b3@6784
#define FLAG_OFF  1040384u   // flag[0] = 1 if inputs fp32, 0 if bf16
#define L_OFF     1040448u   // L SoA: [h(8)][r(512)][s(512)] f32 (8MB)
#define WTQ_OFF   3137600u   // q weights transposed [o][i] f32 + folds
#define WTK_OFF   3159104u
#define WTV_OFF   3180608u
#define W1T_OFF   3202112u   // mW1 transposed [o(64)][row(480)] f32, cg folded

typedef float f32x4 __attribute__((ext_vector_type(4)));
typedef short s16x8 __attribute__((ext_vector_type(8)));

__device__ __forceinline__ float bf2f(uint16_t u) {
    return __uint_as_float(((uint32_t)u) << 16);
}
__device__ __forceinline__ uint16_t f2bf(float f) {
    union { __hip_bfloat16 h; uint16_t u; } cv;
    cv.h = __float2bfloat16(f);
    return cv.u;
}
__device__ __forceinline__ uint32_t packbf(float lo, float hi) {
    return ((uint32_t)f2bf(hi) << 16) | (uint32_t)f2bf(lo);
}
__device__ __forceinline__ float ldin(const void* p, size_t i, int f32) {
    return f32 ? ((const float*)p)[i] : bf2f(((const uint16_t*)p)[i]);
}
// tanh(x) = 1 - 2/(exp(2x)+1)
__device__ __forceinline__ float ftanh(float x) {
    float e = __builtin_amdgcn_exp2f(x * 2.885390081777927f);
    return 1.0f - 2.0f * __builtin_amdgcn_rcpf(e + 1.0f);
}

// ---------------------------------------------------------------- weights prep
// (kDet fused: every block self-detects dtype from nf; block 0 publishes flag.)
#define NS 16384
__global__ __launch_bounds__(256) void kW(
    const void* __restrict__ mW1, const void* __restrict__ mb1,
    const void* __restrict__ mW2, const void* __restrict__ mb2,
    const void* __restrict__ mW3, const void* __restrict__ mb3,
    const void* __restrict__ Wq0, const void* __restrict__ Wq1, const void* __restrict__ Wq2,
    const void* __restrict__ Wk0, const void* __restrict__ Wk1, const void* __restrict__ Wk2,
    const void* __restrict__ Wv0, const void* __restrict__ Wv1, const void* __restrict__ Wv2,
    float* __restrict__ ws, const void* __restrict__ nfu, int* __restrict__ flagp)
{
    __shared__ int sflag;
    const int t = threadIdx.x;
    if (t < 64) {
        uint32_t x = ((const uint32_t*)nfu)[64 + t];
        int e = (x >> 7) & 0xff;
        int good = (x != 0u) && (e >= 100) && (e <= 140);
        unsigned long long m = __ballot(good);
        if (t == 0) sflag = (__popcll(m) < 32) ? 1 : 0;
    }
    __syncthreads();
    const int f32 = sflag;
    if (blockIdx.x == 0 && t == 0) flagp[0] = f32;

    const int gt = blockIdx.x * 256 + t;
    float* Wf = ws + WF_OFF;

    for (int i = gt; i < 2048; i += NS) Wf[i] = ldin(mW1, i, f32);   // W1a
    for (int i = gt; i < 64; i += NS) Wf[6656 + i] = ldin(mb1, i, f32);
    for (int i = gt; i < 64; i += NS) Wf[6720 + i] = ldin(mb2, i, f32);
    for (int i = gt; i < 8; i += NS)  Wf[6784 + i] = ldin(mb3, i, f32);

    // W2 B-fragment per-lane image: idx = ((nt*2+ks)*64 + lane)*4 + w
    // value = pack(W2[kb][n], W2[kb+1][n]), n = nt*16+(lane&15), kb = ks*32+(lane>>4)*8+2w
    {
        uint32_t* W2B = (uint32_t*)(ws + W2B_OFF);
        for (int i = gt; i < 2048; i += NS) {
            int f = i >> 8, lane = (i >> 2) & 63, w = i & 3;
            int nt = f >> 1, ks = f & 1, nl2 = lane & 15, gg = lane >> 4;
            int n = nt * 16 + nl2, kb = ks * 32 + gg * 8 + 2 * w;
            float lo = ldin(mW2, (size_t)kb * 64 + n, f32);
            float hi = ldin(mW2, (size_t)(kb + 1) * 64 + n, f32);
            W2B[i] = packbf(lo, hi);
        }
        uint32_t* W3B = (uint32_t*)(ws + W3B_OFF);
        for (int i = gt; i < 512; i += NS) {
            int ks = i >> 8, lane = (i >> 2) & 63, w = i & 3;
            int nl2 = lane & 15, gg = lane >> 4;
            int kb = ks * 32 + gg * 8 + 2 * w;
            float lo = (nl2 < 8) ? ldin(mW3, (size_t)kb * 8 + nl2, f32) : 0.f;
            float hi = (nl2 < 8) ? ldin(mW3, (size_t)(kb + 1) * 8 + nl2, f32) : 0.f;
            W3B[i] = packbf(lo, hi);
        }
        // W1a B-fragment: idx = nt*256 + lane*4 + w;
        // value = pack(W1a[k0][n], W1a[k0+1][n]), n = nt*16+(lane&15), k0 = (lane>>4)*8+2w
        uint32_t* W1B = (uint32_t*)(ws + W1B_OFF);
        for (int i = gt; i < 1024; i += NS) {
            int nt = i >> 8, lane = (i >> 2) & 63, w = i & 3;
            int nl2 = lane & 15, gg = lane >> 4;
            int n = nt * 16 + nl2, k0 = gg * 8 + 2 * w;
            W1B[i] = packbf(ldin(mW1, (size_t)k0 * 64 + n, f32),
                            ldin(mW1, (size_t)(k0 + 1) * 64 + n, f32));
        }
    }

    const float e3n0 = 0.08838834764831845f, e3n1 = 0.125f, e3n2 = 0.17677669529663687f;
    const float cg1 = 0.5773502691896258f, cg2 = 0.4472135954999579f;
    const float attn = 0.1889822365046136f;

    const void* Wsrc[9] = {Wq0, Wq1, Wq2, Wk0, Wk1, Wk2, Wv0, Wv1, Wv2};
    float* Wdst[3] = {ws + WTQ_OFF, ws + WTK_OFF, ws + WTV_OFF};
    for (int kind = 0; kind < 3; ++kind) {
        const float f0 = (kind == 0) ? e3n0 * attn : e3n0;
        const float f1 = (kind == 0) ? e3n1 * cg1 * attn : e3n1;
        const float f2 = (kind == 0) ? e3n2 * cg2 * attn : e3n2;
        for (int i = gt; i < 16384; i += NS) {
            int o = i >> 7, ii = i & 127;
            Wdst[kind][i] = ldin(Wsrc[kind * 3], (size_t)ii * 128 + o, f32) * f0;
        }
        for (int i = gt; i < 4096; i += NS) {
            int o = i >> 6, ii = i & 63;
            Wdst[kind][16384 + i] = ldin(Wsrc[kind * 3 + 1], (size_t)ii * 64 + o, f32) * f1;
        }
        for (int i = gt; i < 1024; i += NS) {
            int o = i >> 5, ii = i & 31;
            Wdst[kind][20480 + i] = ldin(Wsrc[kind * 3 + 2], (size_t)ii * 32 + o, f32) * f2;
        }
    }
    float* W1T = ws + W1T_OFF;
    for (int i = gt; i < 30720; i += NS) {
        int o = i / 480, row = i - o * 480;
        float cgv;
        if (row < 160)      cgv = 1.0f;
        else if (row < 224) cgv = cg1;
        else if (row < 256) cgv = cg2;
        else if (row < 384) cgv = 1.0f;
        else if (row < 448) cgv = cg1;
        else                cgv = cg2;
        W1T[i] = ldin(mW1, (size_t)row * 64 + o, f32) * cgv;
    }
}

// ------------------------------------------------- per-node precompute
__global__ __launch_bounds__(256) void kA(
    const void* __restrict__ nfu,
    const float* __restrict__ WtQ, const float* __restrict__ WtK,
    const float* __restrict__ WtV, const float* __restrict__ W1T,
    uint32_t* __restrict__ qG, uint32_t* __restrict__ kG, uint16_t* __restrict__ vT,
    uint32_t* __restrict__ ArecG, uint32_t* __restrict__ AsndG,
    const int* __restrict__ flagp)
{
    const int f32 = flagp[0];
    const int n = blockIdx.x, t = threadIdx.x;
    __shared__ float nfs[480];
    for (int i = t; i < 480; i += 256) nfs[i] = ldin(nfu, (size_t)n * 480 + i, f32);

    // zero-fill tile pad (j = 60..63): {q,k,v} x 8 heads x 4 j = 96 tasks
    if (t < 96) {
        const int kind3 = t >> 5, hh = (t >> 2) & 7, j = 60 + (t & 3);
        if (kind3 < 2) {
            const int row = n & 15, rt = n >> 4;
            const int cc = (j >> 3) ^ (n & 7);
            uint16_t* dst = (uint16_t*)(kind3 == 0 ? qG : kG);
            dst[((((size_t)rt * 8 + hh) * 16 + row) * 8 + cc) * 8 + (j & 7)] = 0;
        } else {
            vT[((size_t)(hh * 64 + j)) * 512 + n] = 0;
        }
    }
    __syncthreads();

    for (int idx = t; idx < 1440; idx += 256) {
        int kind = idx / 480, rem = idx - kind * 480;
        int o, m, mul, d, off, am, qoff, sub;
        if (rem < 128)      { o = rem;           m = 0;          mul = 128; d = 1; off = 0;   am = 16; qoff = 0;  sub = 0; }
        else if (rem < 320) { int x = rem - 128; o = x / 3; m = x - o * 3; mul = 64;  d = 3; off = 128; am = 8;  qoff = 16; sub = 16384; }
        else                { int x = rem - 320; o = x / 5; m = x - o * 5; mul = 32;  d = 5; off = 320; am = 4;  qoff = 40; sub = 20480; }
        const float* base = (kind == 0) ? WtQ : (kind == 1) ? WtK : WtV;
        const float4* W4 = reinterpret_cast<const float4*>(base + sub + o * mul);
        const float* nf0 = nfs + off + m;
        float ax = 0.f, ay = 0.f, az = 0.f, aw = 0.f;
        const int n4 = mul >> 2;
        for (int i4 = 0; i4 < n4; ++i4) {
            float4 w = W4[i4];
            int ib = 4 * i4 * d;
            ax += nf0[ib]         * w.x;
            ay += nf0[ib + d]     * w.y;
            az += nf0[ib + 2 * d] * w.z;
            aw += nf0[ib + 3 * d] * w.w;
        }
        float acc = (ax + ay) + (az + aw);
        int hh = o / am, a = o - hh * am;
        int j = qoff + a * d + m;
        if (kind == 2) {
            // v bf16 transposed: [h][j][s=n]
            vT[((size_t)(hh * 64 + j)) * 512 + n] = f2bf(acc);
        } else {
            // bf16 pre-swizzled tile write: [rt][hh][row][chunk^(row&7)][j&7]
            const int row = n & 15, rt = n >> 4;
            const int cc = (j >> 3) ^ (n & 7);
            uint16_t* dst = (uint16_t*)(kind == 0 ? qG : kG);
            dst[((((size_t)rt * 8 + hh) * 16 + row) * 8 + cc) * 8 + (j & 7)] = f2bf(acc);
        }
    }

    if (t < 128) {
        const int src = t >> 6, o = t & 63;
        float a[9];
        #pragma unroll
        for (int mi = 0; mi < 9; ++mi) {
            const int l = (mi == 0) ? 0 : (mi < 4 ? 1 : 2);
            const int m = (mi == 0) ? 0 : (mi < 4 ? mi - 1 : mi - 4);
            const int mul = (l == 0 ? 128 : l == 1 ? 64 : 32);
            const int d = 2 * l + 1;
            const int off = (l == 0 ? 0 : l == 1 ? 128 : 320);
            const int base = (src == 0) ? (l == 0 ? 32 : l == 1 ? 160 : 224)
                                        : (l == 0 ? 256 : l == 1 ? 384 : 448);
            const float4* W4 = reinterpret_cast<const float4*>(W1T + o * 480 + base);
            const float* nf0 = nfs + off + m;
            float ax = 0.f, ay = 0.f, az = 0.f, aw = 0.f;
            const int n4 = mul >> 2;
            for (int i4 = 0; i4 < n4; ++i4) {
                float4 w = W4[i4];
                int ib = 4 * i4 * d;
                ax += nf0[ib]         * w.x;
                ay += nf0[ib + d]     * w.y;
                az += nf0[ib + 2 * d] * w.z;
                aw += nf0[ib + 3 * d] * w.w;
            }
            a[mi] = (ax + ay) + (az + aw);
        }
        float b[9];
        #pragma unroll
        for (int mi = 0; mi < 9; ++mi) b[mi] = __shfl_xor(a[mi], 1, 64);
        if ((o & 1) == 0) {
            uint32_t* dst = (src ? AsndG : ArecG) + (size_t)n * 288 + (o >> 1);
            #pragma unroll
            for (int mi = 0; mi < 9; ++mi)
                dst[mi * 32] = ((uint32_t)f2bf(b[mi]) << 16) | (uint32_t)f2bf(a[mi]);
        }
    }
}

// ------------------------------------------------- edge MLP + logits (full grid)
// Phase 1a (MFMA): eaPart = ea @ W1a -> bf16 h-tile (A-frags via in-wave shfl)
// Phase 1b (VALU): h = eaPart + b1 + sh.(Arec+Asnd) ; tanh
// Phase 2 (MFMA, per-mm fused): h2 = tanh(b2 + h@W2) ; ew = b3 + h2@W3 -> ewS (LDS)
// Phase 0 (MFMA, LAST): copy prebuilt q/k bf16 tiles -> logits = q.k ;
//                       L = logits + ew (ONE write)
__global__ __launch_bounds__(256, 4) void kB(
    const void* __restrict__ eaG, const void* __restrict__ shG,
    const uint32_t* __restrict__ ArecG, const uint32_t* __restrict__ AsndG,
    const uint32_t* __restrict__ qG, const uint32_t* __restrict__ kG,
    const uint32_t* __restrict__ W2B, const uint32_t* __restrict__ W3B,
    const uint32_t* __restrict__ W1B,
    const float* __restrict__ Wf, float* __restrict__ L,
    const int* __restrict__ flagp)
{
    // words [0,8192)   ea-partial tile / Arec+Asnd / h-tile / q,k tiles (time-shared)
    // words [0,4672)   ArecS        (phase 1b)
    // words [4672,9344) AsndS       (phase 1b)
    // words [8192,10240) ewS: [h(8)][e2(256)^ (h<<2)] f32  (written ph2, read ph0)
    __shared__ __align__(16) uint32_t smem[10240];   // 40960 B = 160KB / 4
    uint32_t* ArecS = smem;
    uint32_t* AsndS = smem + 4672;
    float* ewS = (float*)(smem + 8192);
    const int f32 = flagp[0];
    const int t = threadIdx.x;
    const int s0 = blockIdx.x * 16, r0 = blockIdx.y * 16;
    const int lane = t & 63, wv = t >> 6;
    const int g = lane >> 4, nl = lane & 15;

    const int rl = t >> 4, sl = t & 15;
    const int r = r0 + rl, s = s0 + sl;
    const size_t eidx = (((size_t)r) << 9) + s;

    // ---- per-edge ea / sh loads early (registers; independent of LDS) ----
    uint32_t eaR[16];
    if (f32) {
        const float4* ep = reinterpret_cast<const float4*>((const float*)eaG + eidx * 32);
        #pragma unroll
        for (int i = 0; i < 8; ++i) {
            float4 v = ep[i];
            eaR[2 * i]     = ((uint32_t)f2bf(v.y) << 16) | (uint32_t)f2bf(v.x);
            eaR[2 * i + 1] = ((uint32_t)f2bf(v.w) << 16) | (uint32_t)f2bf(v.z);
        }
    } else {
        const uint4* ep = reinterpret_cast<const uint4*>((const uint32_t*)eaG + eidx * 16);
        #pragma unroll
        for (int i = 0; i < 4; ++i) {
            uint4 v = ep[i];
            eaR[4 * i] = v.x; eaR[4 * i + 1] = v.y; eaR[4 * i + 2] = v.z; eaR[4 * i + 3] = v.w;
        }
    }

    float sh0, sh1, sh2, sh3, sh4, sh5, sh6, sh7, sh8;
    {
        const size_t sb = eidx * 9;
        if (f32) {
            const float* shp = (const float*)shG + sb;
            sh0 = shp[0]; sh1 = shp[1]; sh2 = shp[2]; sh3 = shp[3]; sh4 = shp[4];
            sh5 = shp[5]; sh6 = shp[6]; sh7 = shp[7]; sh8 = shp[8];
        } else {
            const uint16_t* shp = (const uint16_t*)shG + sb;
            sh0 = bf2f(shp[0]); sh1 = bf2f(shp[1]); sh2 = bf2f(shp[2]);
            sh3 = bf2f(shp[3]); sh4 = bf2f(shp[4]); sh5 = bf2f(shp[5]);
            sh6 = bf2f(shp[6]); sh7 = bf2f(shp[7]); sh8 = bf2f(shp[8]);
        }
    }

    // ---- phase 1a: eaPart = ea @ W1a via MFMA (K=32, one MFMA per n-tile) ----
    // A-frag rows (edges mt*16+nl) are owned by lanes mm*16+nl of THIS wave ->
    // gather via compile-time-indexed shuffles.  C written bf16 into the h-tile
    // region (rows [wv*64,wv*64+64) only -> intra-wave, no barrier needed before
    // this wave's own-row read below).
    {
        s16x8 w1f[4];
        #pragma unroll
        for (int nt = 0; nt < 4; ++nt) w1f[nt] = ((const s16x8*)W1B)[nt * 64 + lane];
        uint16_t* sm16 = (uint16_t*)smem;
        #pragma unroll
        for (int mm = 0; mm < 4; ++mm) {
            const int srcl = mm * 16 + nl;
            uint32_t af0 = 0, af1 = 0, af2 = 0, af3 = 0;
            #pragma unroll
            for (int c = 0; c < 16; ++c) {
                const uint32_t tmp = (uint32_t)__shfl((int)eaR[c], srcl, 64);
                if ((c >> 2) == g) {
                    if ((c & 3) == 0)      af0 = tmp;
                    else if ((c & 3) == 1) af1 = tmp;
                    else if ((c & 3) == 2) af2 = tmp;
                    else                   af3 = tmp;
                }
            }
            union { uint32_t u[4]; s16x8 v; } afc;
            afc.u[0] = af0; afc.u[1] = af1; afc.u[2] = af2; afc.u[3] = af3;
            const s16x8 afrag = afc.v;
            const int mt = wv * 4 + mm;
            #pragma unroll
            for (int nt = 0; nt < 4; ++nt) {
                f32x4 a = {0.f, 0.f, 0.f, 0.f};
                a = __builtin_amdgcn_mfma_f32_16x16x32_bf16(afrag, w1f[nt], a, 0, 0, 0);
                #pragma unroll
                for (int rg = 0; rg < 4; ++rg) {
                    const int e = mt * 16 + g * 4 + rg;
                    const int o = nt * 16 + nl;
                    sm16[e * 64 + (((o >> 3) ^ (e & 7)) << 3) + (o & 7)] = f2bf(a[rg]);
                }
            }
        }
    }

    // ---- h init: own row's ea-partial (intra-wave LDS dep) + b1 ----
    float h[64];
    #pragma unroll
    for (int c = 0; c < 8; ++c) {
        const int cc = c ^ (t & 7);
        const uint4 p = *(const uint4*)&smem[t * 32 + cc * 4];
        h[c * 8 + 0] = __uint_as_float(p.x << 16);
        h[c * 8 + 1] = __uint_as_float(p.x & 0xffff0000u);
        h[c * 8 + 2] = __uint_as_float(p.y << 16);
        h[c * 8 + 3] = __uint_as_float(p.y & 0xffff0000u);
        h[c * 8 + 4] = __uint_as_float(p.z << 16);
        h[c * 8 + 5] = __uint_as_float(p.z & 0xffff0000u);
        h[c * 8 + 6] = __uint_as_float(p.w << 16);
        h[c * 8 + 7] = __uint_as_float(p.w & 0xffff0000u);
    }
    #pragma unroll
    for (int o = 0; o < 64; ++o) h[o] += Wf[6656 + o];   // b1

    __syncthreads();   // all waves done reading ea-partial before restage

    // ---- stage Arec/Asnd (overwrites ea-partial region) ----
    for (int i = t; i < 16 * 288; i += 256) {
        int row = i / 288, c = i - row * 288;
        ArecS[row * 292 + c] = ArecG[(size_t)(r0 + row) * 288 + c];
        AsndS[row * 292 + c] = AsndG[(size_t)(s0 + row) * 288 + c];
    }
    __syncthreads();

    // ---- phase 1b: sh.(Arec+Asnd) ----
    {
        const int rb = rl * 292, sb = sl * 292;
        #pragma unroll 1
        for (int mi = 0; mi < 9; ++mi) {
            float shv = sh0;
            shv = (mi == 1) ? sh1 : shv;  shv = (mi == 2) ? sh2 : shv;
            shv = (mi == 3) ? sh3 : shv;  shv = (mi == 4) ? sh4 : shv;
            shv = (mi == 5) ? sh5 : shv;  shv = (mi == 6) ? sh6 : shv;
            shv = (mi == 7) ? sh7 : shv;  shv = (mi == 8) ? sh8 : shv;
            const int ro = rb + mi * 32, so = sb + mi * 32;
            #pragma unroll
            for (int oc = 0; oc < 32; ++oc) {
                uint32_t pa = ArecS[ro + oc];
                uint32_t pb = AsndS[so + oc];
                float a0 = __uint_as_float(pa << 16);
                float b0 = __uint_as_float(pb << 16);
                float a1 = __uint_as_float(pa & 0xffff0000u);
                float b1 = __uint_as_float(pb & 0xffff0000u);
                h[2 * oc]     += shv * (a0 + b0);
                h[2 * oc + 1] += shv * (a1 + b1);
            }
        }
    }

    #pragma unroll
    for (int o = 0; o < 64; ++o) h[o] = ftanh(h[o]);

    // ---- pack h -> bf16, write swizzled LDS tile (row e = t, stride 32 u32;
    //      16B chunk c stored at c ^ (row&7)) ----
    __syncthreads();   // all ArecS/AsndS reads complete before overwrite
    #pragma unroll
    for (int c = 0; c < 8; ++c) {
        const int cc = c ^ (t & 7);
        *(uint4*)&smem[t * 32 + cc * 4] =
            make_uint4(packbf(h[c * 8 + 0], h[c * 8 + 1]),
                       packbf(h[c * 8 + 2], h[c * 8 + 3]),
                       packbf(h[c * 8 + 4], h[c * 8 + 5]),
                       packbf(h[c * 8 + 6], h[c * 8 + 7]));
    }
    // Pin: nothing below (W-fragment loads) may be hoisted above this point —
    // keeping phase-1 peak pressure low is the point (R14).
    __builtin_amdgcn_sched_barrier(0);

    // ---- W2/W3 B-fragments: direct 16B loads of prebuilt per-lane images ----
    s16x8 w2f[4][2];
    #pragma unroll
    for (int nt = 0; nt < 4; ++nt) {
        #pragma unroll
        for (int ks = 0; ks < 2; ++ks)
            w2f[nt][ks] = ((const s16x8*)W2B)[(nt * 2 + ks) * 64 + lane];
    }
    s16x8 w3f[2];
    w3f[0] = ((const s16x8*)W3B)[lane];
    w3f[1] = ((const s16x8*)W3B)[64 + lane];
    float b2v[4];
    #pragma unroll
    for (int nt = 0; nt < 4; ++nt) b2v[nt] = Wf[6720 + nt * 16 + nl];
    const float b3v = (nl < 8) ? Wf[6784 + nl] : 0.f;

    // From here on every h-tile LDS row this wave touches is in
    // [wv*64, wv*64+64): written by this wave's own threads -> no barriers
    // needed inside phase 2 (per-wave LDS ordering + compiler lgkmcnt).

    // ---- phase 2 fused per-mm: layer2 -> tanh -> h2 pack -> layer3 -> ewS ----
    uint16_t* sm16 = (uint16_t*)smem;
    #pragma unroll 1
    for (int mm = 0; mm < 4; ++mm) {
        const int mt = wv * 4 + mm;
        const int row = mt * 16 + nl;
        const int sw0 = ((g    ) ^ (row & 7)) * 4;
        const int sw1 = ((4 + g) ^ (row & 7)) * 4;
        // layer 2: A-frag row = mt*16 + (l&15), k = ks*32 + (l>>4)*8 + j
        const s16x8 a0 = *(const s16x8*)&smem[row * 32 + sw0];
        const s16x8 a1 = *(const s16x8*)&smem[row * 32 + sw1];
        f32x4 acc[4];
        #pragma unroll
        for (int nt = 0; nt < 4; ++nt) {
            f32x4 a = {b2v[nt], b2v[nt], b2v[nt], b2v[nt]};
            a = __builtin_amdgcn_mfma_f32_16x16x32_bf16(a0, w2f[nt][0], a, 0, 0, 0);
            a = __builtin_amdgcn_mfma_f32_16x16x32_bf16(a1, w2f[nt][1], a, 0, 0, 0);
            acc[nt] = a;
        }
        // tanh + h2 write (bf16, same swizzle; C layout: col=l&15, row=g*4+reg)
        const int e2base = mt * 16 + g * 4;
        #pragma unroll
        for (int nt = 0; nt < 4; ++nt) {
            const int n = nt * 16 + nl;
            #pragma unroll
            for (int rg = 0; rg < 4; ++rg) {
                const int e2 = e2base + rg;
                const int cc = (n >> 3) ^ (e2 & 7);
                sm16[e2 * 64 + cc * 8 + (n & 7)] = f2bf(ftanh(acc[nt][rg]));
            }
        }
        // layer 3: re-read same rows (now h2) — in-wave LDS ordering guarantees
        // the writes above are observed.
        const s16x8 c0 = *(const s16x8*)&smem[row * 32 + sw0];
        const s16x8 c1 = *(const s16x8*)&smem[row * 32 + sw1];
        f32x4 a3 = {b3v, b3v, b3v, b3v};
        a3 = __builtin_amdgcn_mfma_f32_16x16x32_bf16(c0, w3f[0], a3, 0, 0, 0);
        a3 = __builtin_amdgcn_mfma_f32_16x16x32_bf16(c1, w3f[1], a3, 0, 0, 0);
        if (nl < 8) {
            // ew -> LDS scratch (read back in phase 0b); XOR swizzle -> 4-way
            #pragma unroll
            for (int rg = 0; rg < 4; ++rg) {
                const int e2 = mt * 16 + g * 4 + rg;
                ewS[nl * 256 + (e2 ^ (nl << 2))] = a3[rg];
            }
        }
    }

    __syncthreads();   // phase-2 h-tile reads + ewS writes complete

    // ---- phase 0a: copy prebuilt q/k bf16 tiles -> LDS (pure uint4 copy) ----
    {
        const uint4* qg4 = (const uint4*)qG + (size_t)blockIdx.y * 1024;
        const uint4* kg4 = (const uint4*)kG + (size_t)blockIdx.x * 1024;
        uint4* sm4 = (uint4*)smem;
        for (int i = t; i < 2048; i += 256)
            sm4[i] = (i < 1024) ? qg4[i] : kg4[i - 1024];
    }
    __syncthreads();

    // ---- phase 0b: logits = q.k via MFMA; L = logits + ew (single write) ----
    {
        const int sw0 = ((g    ) ^ (nl & 7)) << 2;
        const int sw1 = ((4 + g) ^ (nl & 7)) << 2;
        #pragma unroll
        for (int hh2 = 0; hh2 < 2; ++hh2) {
            const int h2 = wv * 2 + hh2;
            const uint32_t* qb = smem + h2 * 512;
            const uint32_t* kb = smem + 4096 + h2 * 512;
            const s16x8 qa0 = *(const s16x8*)&qb[nl * 32 + sw0];
            const s16x8 qa1 = *(const s16x8*)&qb[nl * 32 + sw1];
            const s16x8 ka0 = *(const s16x8*)&kb[nl * 32 + sw0];
            const s16x8 ka1 = *(const s16x8*)&kb[nl * 32 + sw1];
            f32x4 a = {0.f, 0.f, 0.f, 0.f};
            a = __builtin_amdgcn_mfma_f32_16x16x32_bf16(qa0, ka0, a, 0, 0, 0);
            a = __builtin_amdgcn_mfma_f32_16x16x32_bf16(qa1, ka1, a, 0, 0, 0);
            float* Lp = L + (((size_t)h2) << 18) + (((size_t)(r0 + g * 4)) << 9) + s0 + nl;
            #pragma unroll
            for (int rg = 0; rg < 4; ++rg) {
                const int e2 = (g * 4 + rg) * 16 + nl;
                Lp[(size_t)rg << 9] = a[rg] + ewS[h2 * 256 + (e2 ^ (h2 << 2))];
            }
        }
    }
}

// ------------------------------------------------- softmax + aggregation (MFMA)
// Block = (16-row r-tile, head h).  out_h[16 x 60] = softmax(L_h)[16x512] @ V_h.
// Softmax: 16-lane groups per row; bf16 A-tile in 16KB swizzled LDS.
// GEMM: wave = one 16-col n-tile; B-frags are 16B contiguous vT global loads.
__global__ __launch_bounds__(256) void kAgg(
    const float* __restrict__ L, const uint16_t* __restrict__ vT,
    const void* __restrict__ nfu, void* __restrict__ out,
    const int* __restrict__ flagp)
{
    __shared__ __align__(16) uint32_t Ws[4096];   // [row(16)][chunk(64)^swz][4 u32]
    const int f32 = flagp[0];
    const int t = threadIdx.x;
    const int lane = t & 63, wv = t >> 6;
    const int g = lane >> 4, nl = lane & 15;
    const int r0 = blockIdx.x * 16;
    const int h  = blockIdx.y;

    // ---- softmax: row = wv*4+g, 16 lanes/row; lane owns 4 blocks of 8 cols ----
    {
        const int row = wv * 4 + g;
        const float* Lg = L + (((size_t)h) << 18) + (((size_t)(r0 + row)) << 9);
        float v[32];
        #pragma unroll
        for (int cw = 0; cw < 4; ++cw) {
            const float4* p = reinterpret_cast<const float4*>(Lg + nl * 8 + cw * 128);
            float4 x = p[0], y = p[1];
            v[cw * 8 + 0] = x.x; v[cw * 8 + 1] = x.y; v[cw * 8 + 2] = x.z; v[cw * 8 + 3] = x.w;
            v[cw * 8 + 4] = y.x; v[cw * 8 + 5] = y.y; v[cw * 8 + 6] = y.z; v[cw * 8 + 7] = y.w;
        }
        float mx = -3.402823466e38f;
        #pragma unroll
        for (int i = 0; i < 32; ++i) mx = fmaxf(mx, v[i]);
        #pragma unroll
        for (int off = 8; off >= 1; off >>= 1) mx = fmaxf(mx, __shfl_xor(mx, off, 16));
        const float C = 1.4426950408889634f;
        float sm = 0.f;
        #pragma unroll
        for (int i = 0; i < 32; ++i) {
            v[i] = __builtin_amdgcn_exp2f((v[i] - mx) * C);
            sm += v[i];
        }
        #pragma unroll
        for (int off = 8; off >= 1; off >>= 1) sm += __shfl_xor(sm, off, 16);
        const float inv = __builtin_amdgcn_rcpf(sm);
        #pragma unroll
        for (int cw = 0; cw < 4; ++cw) {
            const int cc = (nl + cw * 16) ^ (row & 7);
            *(uint4*)&Ws[row * 256 + cc * 4] = make_uint4(
                packbf(v[cw * 8 + 0] * inv, v[cw * 8 + 1] * inv),
                packbf(v[cw * 8 + 2] * inv, v[cw * 8 + 3] * inv),
                packbf(v[cw * 8 + 4] * inv, v[cw * 8 + 5] * inv),
                packbf(v[cw * 8 + 6] * inv, v[cw * 8 + 7] * inv));
        }
    }
    __syncthreads();

    // ---- GEMM: A = Ws (row=nl, k=ks*32+g*8+j), B = vT[h][n][k] contiguous ----
    f32x4 acc = {0.f, 0.f, 0.f, 0.f};
    {
        const uint16_t* vb = vT + ((size_t)(h * 64 + wv * 16 + nl)) * 512 + g * 8;
        #pragma unroll
        for (int ks = 0; ks < 16; ++ks) {
            const s16x8 a = *(const s16x8*)&Ws[nl * 256 + (((ks * 4 + g) ^ (nl & 7)) << 2)];
            const s16x8 b = *(const s16x8*)&vb[ks * 32];
            acc = __builtin_amdgcn_mfma_f32_16x16x32_bf16(a, b, acc, 0, 0, 0);
        }
    }

    // ---- epilogue: local j -> global column (3 contiguous spans per head) ----
    const int n = wv * 16 + nl;
    if (n < 60) {
        int col;
        if (n < 16)      col = h * 16 + n;
        else if (n < 40) col = 128 + h * 24 + (n - 16);
        else             col = 320 + h * 20 + (n - 40);
        #pragma unroll
        for (int rg = 0; rg < 4; ++rg) {
            const size_t o = (size_t)(r0 + g * 4 + rg) * 480 + col;
            float val = ldin(nfu, o, f32) + acc[rg];
            if (f32) ((float*)out)[o] = val;
            else     ((uint16_t*)out)[o] = f2bf(val);
        }
    }
}

extern "C" void kernel_launch(void* const* d_in, const int* in_sizes, int n_in,
                              void* d_out, int out_size, void* d_ws, size_t ws_size,
                              hipStream_t stream)
{
    (void)in_sizes; (void)n_in; (void)out_size; (void)ws_size;
    const void* nf  = d_in[0];
    const void* eaG = d_in[1];
    const void* shG = d_in[2];

    float* ws = (float*)d_ws;
    uint32_t* qG = (uint32_t*)(ws + QG_OFF);
    uint32_t* kG = (uint32_t*)(ws + KG_OFF);
    uint32_t* W2B = (uint32_t*)(ws + W2B_OFF);
    uint32_t* W3B = (uint32_t*)(ws + W3B_OFF);
    uint32_t* W1B = (uint32_t*)(ws + W1B_OFF);
    uint16_t* vT = (uint16_t*)(ws + VT_OFF);
    uint32_t* ArecG = (uint32_t*)(ws + ARE_OFF);
    uint32_t* AsndG = (uint32_t*)(ws + ASN_OFF);
    float* Wf  = ws + WF_OFF;
    int* flag  = (int*)(ws + FLAG_OFF);
    float* L   = ws + L_OFF;
    float* WtQ = ws + WTQ_OFF;
    float* WtK = ws + WTK_OFF;
    float* WtV = ws + WTV_OFF;
    float* W1T = ws + W1T_OFF;

    kW<<<64, 256, 0, stream>>>(d_in[12], d_in[13], d_in[14], d_in[15], d_in[16], d_in[17],
                               d_in[3], d_in[4], d_in[5], d_in[6], d_in[7], d_in[8],
                               d_in[9], d_in[10], d_in[11], ws, nf, flag);
    kA<<<512, 256, 0, stream>>>(nf, WtQ, WtK, WtV, W1T, qG, kG, vT, ArecG, AsndG, flag);
    kB<<<dim3(32, 32), 256, 0, stream>>>(eaG, shG, ArecG, AsndG, qG, kG, W2B, W3B, W1B, Wf, L, flag);
    kAgg<<<dim3(32, 8), 256, 0, stream>>>(L, vT, nf, d_out, flag);
}